// Round 2
// baseline (3415.128 us; speedup 1.0000x reference)
//
#include <hip/hip_runtime.h>
#include <hip/hip_bf16.h>
#include <math.h>
#include <stdint.h>

#define B_    8
#define N_    16384
#define F_    1024
#define D_    512
#define S_    64
#define H_    8
#define DH_   64
#define LMAX_ 1024
#define M2_   512
#define WIN_  32
#define NTOK_ (B_ * N_)   // 131072

// ---------------------------------------------------------------- utilities
static __device__ __forceinline__ float wred_sum(float v) {
    #pragma unroll
    for (int d = 1; d < 64; d <<= 1) v += __shfl_xor(v, d, 64);
    return v;
}

static __device__ __forceinline__ void bf8_to_f32(uint4 q, float* a) {
    a[0] = __uint_as_float(q.x << 16); a[1] = __uint_as_float(q.x & 0xffff0000u);
    a[2] = __uint_as_float(q.y << 16); a[3] = __uint_as_float(q.y & 0xffff0000u);
    a[4] = __uint_as_float(q.z << 16); a[5] = __uint_as_float(q.z & 0xffff0000u);
    a[6] = __uint_as_float(q.w << 16); a[7] = __uint_as_float(q.w & 0xffff0000u);
}

// ------------------------------------------------- mask layout detection
// If key_padding_mask is raw bool bytes, padded rows contain 1-bytes at
// offsets not divisible by 4. If it is int32 {0,1}, those offsets are all 0.
__global__ void k_detect(const unsigned char* mb, int nbytes, int* flag) {
    if (threadIdx.x == 0) *flag = 0;
    __syncthreads();
    int found = 0;
    for (int i = threadIdx.x; i < nbytes; i += blockDim.x)
        if ((i & 3) && mb[i]) found = 1;
    if (found) atomicOr(flag, 1);
}

__global__ void k_valid(const void* maskp, const int* flag, unsigned char* v) {
    int i = blockIdx.x * 256 + threadIdx.x;
    if (i >= NTOK_) return;
    int pad;
    if (*flag) pad = (((const unsigned char*)maskp)[i] != 0);
    else       pad = (((const int*)maskp)[i] != 0);
    v[i] = pad ? 0 : 1;
}

// ------------------------------------------------- text feature (masked mean)
__global__ void k_text_feat(const float* emb, const int* ids, const int* am, float* tf) {
    int b = blockIdx.x;
    __shared__ int   sid[S_];
    __shared__ float sam[S_];
    int t = threadIdx.x;
    if (t < S_) { sid[t] = ids[b * S_ + t]; sam[t] = (float)am[b * S_ + t]; }
    __syncthreads();
    float asum = 0.f;
    for (int s = 0; s < S_; s++) asum += sam[s];
    float denom = fmaxf(asum, 1.0f);
    for (int d = t; d < 768; d += blockDim.x) {
        float acc = 0.f;
        for (int s = 0; s < S_; s++) acc += emb[(long)sid[s] * 768 + d] * sam[s];
        tf[b * 768 + d] = acc / denom;
    }
}

// out[b][d] = bias[d] + sum_e in[b][e] * W[e*Nn + d]   (blockDim == Nn == 512)
__global__ void k_rowmm(const float* in, const float* W, const float* bias,
                        float* out, int E, int Nn) {
    int b = blockIdx.x, d = threadIdx.x;
    __shared__ float sin[768];
    for (int e = d; e < E; e += blockDim.x) sin[e] = in[b * E + e];
    __syncthreads();
    float acc = bias[d];
    for (int e = 0; e < E; e++) acc = fmaf(sin[e], W[(long)e * Nn + d], acc);
    out[b * Nn + d] = acc;
}

// ------------------------------------------------- tiled f32 GEMM  C = A*B + bias
#define BM 128
#define BN 64
#define BK 32
#define ASTR 136   // 136*4B = 544B rows: 16B-aligned vector reads
__global__ __launch_bounds__(256) void k_gemm(const float* __restrict__ A, int lda,
                                              const float* __restrict__ Bw, int ldb,
                                              const float* __restrict__ bias,
                                              float* __restrict__ C, int ldc, int K) {
    __shared__ float As[BK][ASTR];   // k-major
    __shared__ float Bs[BK][BN];
    int bm = blockIdx.x, bn = blockIdx.y;
    int tid = threadIdx.x;
    int trow = tid >> 4, tcol = tid & 15;
    float acc[8][4] = {};
    const float* Ab = A + (long)bm * BM * lda;
    const float* Bb = Bw + bn * BN;
    for (int kt = 0; kt < K; kt += BK) {
        #pragma unroll
        for (int i = 0; i < 4; i++) {
            int f = tid + 256 * i;              // 0..1023
            int row = f >> 3, c4 = (f & 7) << 2;
            float4 v = *(const float4*)(Ab + (long)row * lda + kt + c4);
            As[c4 + 0][row] = v.x; As[c4 + 1][row] = v.y;
            As[c4 + 2][row] = v.z; As[c4 + 3][row] = v.w;
        }
        #pragma unroll
        for (int i = 0; i < 2; i++) {
            int f = tid + 256 * i;              // 0..511
            int row = f >> 4, c4 = (f & 15) << 2;
            *(float4*)&Bs[row][c4] = *(const float4*)(Bb + (long)(kt + row) * ldb + c4);
        }
        __syncthreads();
        #pragma unroll 8
        for (int kk = 0; kk < BK; kk++) {
            float a[8], bv[4];
            #pragma unroll
            for (int i = 0; i < 8; i++) a[i] = As[kk][trow * 8 + i];
            #pragma unroll
            for (int j = 0; j < 4; j++) bv[j] = Bs[kk][tcol * 4 + j];
            #pragma unroll
            for (int i = 0; i < 8; i++)
                #pragma unroll
                for (int j = 0; j < 4; j++)
                    acc[i][j] = fmaf(a[i], bv[j], acc[i][j]);
        }
        __syncthreads();
    }
    int c = bn * BN + tcol * 4;
    #pragma unroll
    for (int i = 0; i < 8; i++) {
        long r = (long)bm * BM + trow * 8 + i;
        float4 v;
        v.x = acc[i][0] + bias[c + 0]; v.y = acc[i][1] + bias[c + 1];
        v.z = acc[i][2] + bias[c + 2]; v.w = acc[i][3] + bias[c + 3];
        *(float4*)(C + r * ldc + c) = v;
    }
}

// ------------------------------------------------- LayerNorm+ReLU (in place) + rnorm + rel
__global__ __launch_bounds__(256) void k_ln(float* h, const float* g, const float* bb,
                                            const float* temb, float* rnorm, float* rel) {
    int wid = threadIdx.x >> 6, lane = threadIdx.x & 63;
    long row = (long)blockIdx.x * 4 + wid;
    int b = (int)(row >> 14);
    float* hp = h + row * (long)D_;
    int c0 = lane * 4, c1 = 256 + lane * 4;
    float4 x0 = *(float4*)(hp + c0);
    float4 x1 = *(float4*)(hp + c1);
    float x[8] = { x0.x, x0.y, x0.z, x0.w, x1.x, x1.y, x1.z, x1.w };
    float s = 0.f;
    #pragma unroll
    for (int i = 0; i < 8; i++) s += x[i];
    s = wred_sum(s);
    float mu = s * (1.0f / 512.0f);
    float var = 0.f;
    #pragma unroll
    for (int i = 0; i < 8; i++) { float d = x[i] - mu; var += d * d; }
    var = wred_sum(var) * (1.0f / 512.0f);
    float inv = 1.0f / sqrtf(var + 1e-5f);
    float4 g0 = *(const float4*)(g + c0), g1 = *(const float4*)(g + c1);
    float4 b0 = *(const float4*)(bb + c0), b1 = *(const float4*)(bb + c1);
    float gg[8] = { g0.x, g0.y, g0.z, g0.w, g1.x, g1.y, g1.z, g1.w };
    float bbv[8] = { b0.x, b0.y, b0.z, b0.w, b1.x, b1.y, b1.z, b1.w };
    float y[8], sq = 0.f;
    #pragma unroll
    for (int i = 0; i < 8; i++) {
        y[i] = fmaxf(gg[i] * (x[i] - mu) * inv + bbv[i], 0.0f);
        sq += y[i] * y[i];
    }
    float4 o0 = { y[0], y[1], y[2], y[3] }, o1 = { y[4], y[5], y[6], y[7] };
    *(float4*)(hp + c0) = o0;
    *(float4*)(hp + c1) = o1;
    sq = wred_sum(sq);
    float rn = 1.0f / (sqrtf(sq) + 1e-8f);
    const float* tp = temb + (long)b * D_;
    float4 t0 = *(const float4*)(tp + c0), t1 = *(const float4*)(tp + c1);
    float tt[8] = { t0.x, t0.y, t0.z, t0.w, t1.x, t1.y, t1.z, t1.w };
    float rl = 0.f;
    #pragma unroll
    for (int i = 0; i < 8; i++) rl = fmaf(y[i], tt[i], rl);
    rl = wred_sum(rl);
    if (lane == 0) { rnorm[row] = rn; rel[row] = rl; }
}

// ------------------------------------------------- sliding-window cosine pruning
#define CHUNK 28
#define KROWS 60   // 32 overlap + 28 new; 60*512*2B = 61440 B LDS
__global__ __launch_bounds__(256) void k_sim(const float* img, const float* rnorm,
                                             const unsigned char* vld, int* keep) {
    __shared__ __hip_bfloat16 fnb[KROWS][D_];
    long c0 = (long)blockIdx.x * CHUNK;
    int tid = threadIdx.x;
    for (int idx = tid; idx < KROWS * (D_ / 8); idx += 256) {
        int rr = idx / (D_ / 8);
        int cc = (idx % (D_ / 8)) * 8;
        long grow = c0 - WIN_ + rr;
        if (grow < 0) grow = 0;
        if (grow >= NTOK_) grow = NTOK_ - 1;
        float rn = rnorm[grow];
        const float* p = img + grow * (long)D_ + cc;
        float4 u = *(const float4*)p, w = *(const float4*)(p + 4);
        fnb[rr][cc + 0] = __float2bfloat16(u.x * rn);
        fnb[rr][cc + 1] = __float2bfloat16(u.y * rn);
        fnb[rr][cc + 2] = __float2bfloat16(u.z * rn);
        fnb[rr][cc + 3] = __float2bfloat16(u.w * rn);
        fnb[rr][cc + 4] = __float2bfloat16(w.x * rn);
        fnb[rr][cc + 5] = __float2bfloat16(w.y * rn);
        fnb[rr][cc + 6] = __float2bfloat16(w.z * rn);
        fnb[rr][cc + 7] = __float2bfloat16(w.w * rn);
    }
    __syncthreads();
    int wid = tid >> 6, lane = tid & 63;
    for (int ti = 0; ti < 7; ti++) {
        int tloc = wid * 7 + ti;            // 0..27
        long t = c0 + tloc;
        if (t >= NTOK_) continue;
        int lr = WIN_ + tloc;
        int tl = (int)(t & (N_ - 1));       // position within batch
        float a[8];
        bf8_to_f32(*(const uint4*)&fnb[lr][lane * 8], a);
        int wmax = tl < WIN_ ? tl : WIN_;
        float msim = -INFINITY;
        for (int w = 1; w <= wmax; w++) {
            if (!vld[t - w]) continue;      // wave-uniform branch
            float bvv[8];
            bf8_to_f32(*(const uint4*)&fnb[lr - w][lane * 8], bvv);
            float p = 0.f;
            #pragma unroll
            for (int i = 0; i < 8; i++) p = fmaf(a[i], bvv[i], p);
            p = wred_sum(p);
            msim = fmaxf(msim, p);
        }
        int kp = (vld[t] && (msim < 0.7f)) ? 1 : 0;
        if (lane == 0) keep[t] = kp;
    }
}

// ------------------------------------------------- per-batch exact top-k (radix select)
static __device__ void scan1024(int* tot, int tid) {   // exclusive, in place, wave 0
    if (tid < 64) {
        int vals[16], s = 0;
        #pragma unroll
        for (int i = 0; i < 16; i++) vals[i] = tot[tid * 16 + i];
        #pragma unroll
        for (int i = 0; i < 16; i++) { int t = vals[i]; vals[i] = s; s += t; }
        int inc = s;
        #pragma unroll
        for (int d = 1; d < 64; d <<= 1) {
            int v = __shfl_up(inc, d, 64);
            if ((tid & 63) >= d) inc += v;
        }
        int excl = inc - s;
        #pragma unroll
        for (int i = 0; i < 16; i++) tot[tid * 16 + i] = vals[i] + excl;
    }
}

__global__ __launch_bounds__(1024) void k_topk(const float* rel, const int* keep, int* idxo) {
    int b = blockIdx.x, tid = threadIdx.x;
    const float* relb = rel + (long)b * N_;
    const int* keepb  = keep + (long)b * N_;
    __shared__ unsigned int hist[256];
    __shared__ int toti[1024];
    __shared__ unsigned int s_prefix;
    __shared__ int s_rem, s_k;

    unsigned int key[16];
    int base = tid * 16, nk_local = 0;
    #pragma unroll
    for (int j = 0; j < 16; j++) {
        int i = base + j;
        float r = relb[i];
        int kp = keepb[i];
        unsigned int bits = __float_as_uint(r);
        unsigned int kk = (bits & 0x80000000u) ? ~bits : (bits | 0x80000000u);
        key[j] = kp ? kk : 0u;
        nk_local += kp;
    }
    toti[tid] = nk_local; __syncthreads();
    for (int o = 512; o > 0; o >>= 1) { if (tid < o) toti[tid] += toti[tid + o]; __syncthreads(); }
    if (tid == 0) {
        int n_kept = toti[0];
        int k = (int)(0.8f * (float)n_kept);
        if (k < 1) k = 1; if (k > LMAX_) k = LMAX_;
        s_k = k; s_rem = k; s_prefix = 0u;
    }
    __syncthreads();

    for (int pass = 0; pass < 4; pass++) {
        int shift = 24 - pass * 8;
        unsigned int himask = (pass == 0) ? 0u : (0xFFFFFFFFu << (shift + 8));
        if (tid < 256) hist[tid] = 0u;
        __syncthreads();
        unsigned int pfx = s_prefix;
        #pragma unroll
        for (int j = 0; j < 16; j++) {
            unsigned int kk = key[j];
            if ((kk & himask) == (pfx & himask))
                atomicAdd(&hist[(kk >> shift) & 255], 1u);
        }
        __syncthreads();
        if (tid == 0) {
            int rem = s_rem;
            unsigned int cum = 0;
            for (int d = 255; d >= 0; d--) {
                unsigned int h = hist[d];
                if (cum + h >= (unsigned int)rem) {
                    s_rem = rem - (int)cum;
                    s_prefix = pfx | ((unsigned int)d << shift);
                    break;
                }
                cum += h;
            }
        }
        __syncthreads();
    }
    unsigned int T = s_prefix;
    int tie_need = s_rem, k = s_k;

    int eq[16], gt[16], eqpre[16];
    int locEq = 0;
    #pragma unroll
    for (int j = 0; j < 16; j++) {
        eq[j] = (key[j] == T); gt[j] = (key[j] > T);
        eqpre[j] = locEq; locEq += eq[j];
    }
    toti[tid] = locEq; __syncthreads();
    scan1024(toti, tid); __syncthreads();
    int eqoff = toti[tid];

    int sel[16], spre[16];
    int locS = 0;
    #pragma unroll
    for (int j = 0; j < 16; j++) {
        int rank = eqoff + eqpre[j];
        sel[j] = gt[j] || (eq[j] && rank < tie_need);
        spre[j] = locS; locS += sel[j];
    }
    __syncthreads();
    toti[tid] = locS; __syncthreads();
    scan1024(toti, tid); __syncthreads();
    int soff = toti[tid];
    #pragma unroll
    for (int j = 0; j < 16; j++)
        if (sel[j]) idxo[b * LMAX_ + soff + spre[j]] = base + j;
    for (int p = k + tid; p < LMAX_; p += 1024) idxo[b * LMAX_ + p] = N_;
}

// ------------------------------------------------- feat2 gather + pair pooling
__global__ void k_feat3(const float* img, const int* idxo, float* f3) {
    int bm = blockIdx.x;                 // b*512 + m
    int b = bm >> 9, m = bm & 511;
    int i0 = idxo[b * LMAX_ + 2 * m], i1 = idxo[b * LMAX_ + 2 * m + 1];
    int c0 = i0 < N_, c1 = i1 < N_;
    float dn = 1.0f / fmaxf((float)(c0 + c1), 1.0f);
    const float* p0 = img + ((long)b * N_ + (c0 ? i0 : 0)) * D_;
    const float* p1 = img + ((long)b * N_ + (c1 ? i1 : 0)) * D_;
    int d = threadIdx.x * 4;
    float4 v0 = c0 ? *(const float4*)(p0 + d) : make_float4(0.f, 0.f, 0.f, 0.f);
    float4 v1 = c1 ? *(const float4*)(p1 + d) : make_float4(0.f, 0.f, 0.f, 0.f);
    float4 o;
    o.x = (v0.x + v1.x) * dn; o.y = (v0.y + v1.y) * dn;
    o.z = (v0.z + v1.z) * dn; o.w = (v0.w + v1.w) * dn;
    *(float4*)(f3 + (long)bm * D_ + d) = o;
}

// ------------------------------------------------- cross-modal attention
__global__ __launch_bounds__(512) void k_attn(const float* qv, const float* kk,
                                              const float* vv, float* ctx) {
    int bh = blockIdx.x;
    int b = bh >> 3, h = bh & 7;
    __shared__ float qs[DH_];
    __shared__ float sc[M2_];
    __shared__ float red[M2_];
    int m = threadIdx.x;
    if (m < DH_) qs[m] = qv[b * D_ + h * DH_ + m];
    __syncthreads();
    const float* kp = kk + (long)b * M2_ * D_ + h * DH_;
    float acc = 0.f;
    #pragma unroll
    for (int d = 0; d < DH_; d += 4) {
        float4 kv = *(const float4*)(kp + (long)m * D_ + d);
        acc += qs[d] * kv.x + qs[d + 1] * kv.y + qs[d + 2] * kv.z + qs[d + 3] * kv.w;
    }
    acc *= 0.125f;                        // 1/sqrt(64)
    red[m] = acc; __syncthreads();
    for (int o = 256; o > 0; o >>= 1) { if (m < o) red[m] = fmaxf(red[m], red[m + o]); __syncthreads(); }
    float mx = red[0]; __syncthreads();
    float e = expf(acc - mx);
    sc[m] = e; red[m] = e; __syncthreads();
    for (int o = 256; o > 0; o >>= 1) { if (m < o) red[m] += red[m + o]; __syncthreads(); }
    float inv = 1.0f / red[0];
    if (m < DH_) {
        float a2 = 0.f;
        const float* vp = vv + (long)b * M2_ * D_ + h * DH_ + m;
        for (int mm = 0; mm < M2_; mm++) a2 = fmaf(sc[mm], vp[(long)mm * D_], a2);
        ctx[b * D_ + h * DH_ + m] = a2 * inv;
    }
}

// ------------------------------------------------- output head (Wo then W_cls), f32 out
__global__ __launch_bounds__(512) void k_head(const float* ctx, const float* Wo, const float* bo,
                                              const float* Wc, const float* bc,
                                              float* out) {
    int b = blockIdx.x, d = threadIdx.x;
    __shared__ float cl[D_], ol[D_];
    cl[d] = ctx[b * D_ + d]; __syncthreads();
    float acc = bo[d];
    for (int e = 0; e < D_; e++) acc = fmaf(cl[e], Wo[(long)e * D_ + d], acc);
    ol[d] = acc; __syncthreads();
    if (d < 4) {
        float a2 = bc[d];
        for (int e = 0; e < D_; e++) a2 = fmaf(ol[e], Wc[e * 4 + d], a2);
        out[b * 4 + d] = a2;
    }
}

// ---------------------------------------------------------------- launcher
extern "C" void kernel_launch(void* const* d_in, const int* in_sizes, int n_in,
                              void* d_out, int out_size, void* d_ws, size_t ws_size,
                              hipStream_t stream) {
    const float* bags = (const float*)d_in[0];
    const void*  kpm  = d_in[1];
    const int*   ids  = (const int*)d_in[2];
    const int*   am   = (const int*)d_in[3];
    const float* emb  = (const float*)d_in[4];
    const float* Wtp  = (const float*)d_in[5];
    const float* btp  = (const float*)d_in[6];
    const float* Wen  = (const float*)d_in[7];
    const float* ben  = (const float*)d_in[8];
    const float* lng  = (const float*)d_in[9];
    const float* lnb  = (const float*)d_in[10];
    const float* Wq   = (const float*)d_in[11];
    const float* bq   = (const float*)d_in[12];
    const float* Wk   = (const float*)d_in[13];
    const float* bk   = (const float*)d_in[14];
    const float* Wv   = (const float*)d_in[15];
    const float* bv   = (const float*)d_in[16];
    const float* Wo   = (const float*)d_in[17];
    const float* bo   = (const float*)d_in[18];
    const float* Wc   = (const float*)d_in[19];
    const float* bc   = (const float*)d_in[20];

    char* ws = (char*)d_ws;
    size_t o = 0;
    auto alloc = [&](size_t bytes) -> void* {
        void* p = ws + o; o += (bytes + 255) & ~(size_t)255; return p;
    };
    float* img  = (float*)alloc((size_t)NTOK_ * D_ * 4);   // 256 MiB (h, then img in place)
    float* rno  = (float*)alloc((size_t)NTOK_ * 4);
    float* rel  = (float*)alloc((size_t)NTOK_ * 4);
    int*   keep = (int*)alloc((size_t)NTOK_ * 4);
    unsigned char* vld = (unsigned char*)alloc(NTOK_);
    float* tf   = (float*)alloc(B_ * 768 * 4);
    float* te   = (float*)alloc(B_ * D_ * 4);
    float* qv   = (float*)alloc(B_ * D_ * 4);
    int*   idxo = (int*)alloc(B_ * LMAX_ * 4);
    float* f3   = (float*)alloc((size_t)B_ * M2_ * D_ * 4);
    float* kkb  = (float*)alloc((size_t)B_ * M2_ * D_ * 4);
    float* vvb  = (float*)alloc((size_t)B_ * M2_ * D_ * 4);
    float* ctx  = (float*)alloc(B_ * D_ * 4);
    int*   flag = (int*)alloc(256);

    k_detect<<<1, 256, 0, stream>>>((const unsigned char*)kpm, NTOK_, flag);
    k_valid<<<(NTOK_ + 255) / 256, 256, 0, stream>>>(kpm, flag, vld);
    k_text_feat<<<B_, 256, 0, stream>>>(emb, ids, am, tf);
    k_rowmm<<<B_, 512, 0, stream>>>(tf, Wtp, btp, te, 768, 512);
    k_rowmm<<<B_, 512, 0, stream>>>(te, Wq, bq, qv, 512, 512);

    dim3 g3(NTOK_ / BM, D_ / BN);
    k_gemm<<<g3, 256, 0, stream>>>(bags, F_, Wen, D_, ben, img, D_, F_);
    k_ln<<<NTOK_ / 4, 256, 0, stream>>>(img, lng, lnb, te, rno, rel);
    k_sim<<<(NTOK_ + CHUNK - 1) / CHUNK, 256, 0, stream>>>(img, rno, vld, keep);
    k_topk<<<B_, 1024, 0, stream>>>(rel, keep, idxo);
    k_feat3<<<B_ * M2_, 128, 0, stream>>>(img, idxo, f3);

    dim3 g8(B_ * M2_ / BM, D_ / BN);
    k_gemm<<<g8, 256, 0, stream>>>(f3, D_, Wk, D_, bk, kkb, D_, D_);
    k_gemm<<<g8, 256, 0, stream>>>(f3, D_, Wv, D_, bv, vvb, D_, D_);

    k_attn<<<B_ * H_, 512, 0, stream>>>(qv, kkb, vvb, ctx);
    k_head<<<B_, 512, 0, stream>>>(ctx, Wo, bo, Wc, bc, (float*)d_out);
}

// Round 3
// 2111.487 us; speedup vs baseline: 1.6174x; 1.6174x over previous
//
#include <hip/hip_runtime.h>
#include <hip/hip_bf16.h>
#include <math.h>
#include <stdint.h>

#define B_    8
#define N_    16384
#define F_    1024
#define D_    512
#define S_    64
#define H_    8
#define DH_   64
#define LMAX_ 1024
#define M2_   512
#define WIN_  32
#define NTOK_ (B_ * N_)   // 131072

typedef __attribute__((ext_vector_type(8)))  short bf16x8;
typedef __attribute__((ext_vector_type(16))) float f32x16;

// ---------------------------------------------------------------- utilities
static __device__ __forceinline__ float wred_sum(float v) {
    #pragma unroll
    for (int d = 1; d < 64; d <<= 1) v += __shfl_xor(v, d, 64);
    return v;
}

static __device__ __forceinline__ void bf8_to_f32(uint4 q, float* a) {
    a[0] = __uint_as_float(q.x << 16); a[1] = __uint_as_float(q.x & 0xffff0000u);
    a[2] = __uint_as_float(q.y << 16); a[3] = __uint_as_float(q.y & 0xffff0000u);
    a[4] = __uint_as_float(q.z << 16); a[5] = __uint_as_float(q.z & 0xffff0000u);
    a[6] = __uint_as_float(q.w << 16); a[7] = __uint_as_float(q.w & 0xffff0000u);
}

// RNE split: x ~= hi + lo (both bf16), dropped residual ~2^-17 |x|
static __device__ __forceinline__ void split_bf(float x, unsigned short& h, unsigned short& l) {
    unsigned int b = __float_as_uint(x);
    unsigned int hb = (b + 0x7FFFu + ((b >> 16) & 1u)) >> 16;
    h = (unsigned short)hb;
    float r = x - __uint_as_float(hb << 16);
    unsigned int rb = __float_as_uint(r);
    unsigned int lb = (rb + 0x7FFFu + ((rb >> 16) & 1u)) >> 16;
    l = (unsigned short)lb;
}

// ------------------------------------------------- mask layout detection
__global__ void k_detect(const unsigned char* mb, int nbytes, int* flag) {
    if (threadIdx.x == 0) *flag = 0;
    __syncthreads();
    int found = 0;
    for (int i = threadIdx.x; i < nbytes; i += blockDim.x)
        if ((i & 3) && mb[i]) found = 1;
    if (found) atomicOr(flag, 1);
}

__global__ void k_valid(const void* maskp, const int* flag, unsigned char* v) {
    int i = blockIdx.x * 256 + threadIdx.x;
    if (i >= NTOK_) return;
    int pad;
    if (*flag) pad = (((const unsigned char*)maskp)[i] != 0);
    else       pad = (((const int*)maskp)[i] != 0);
    v[i] = pad ? 0 : 1;
}

// ------------------------------------------------- text feature (masked mean)
__global__ void k_text_feat(const float* emb, const int* ids, const int* am, float* tf) {
    int b = blockIdx.x;
    __shared__ int   sid[S_];
    __shared__ float sam[S_];
    int t = threadIdx.x;
    if (t < S_) { sid[t] = ids[b * S_ + t]; sam[t] = (float)am[b * S_ + t]; }
    __syncthreads();
    float asum = 0.f;
    for (int s = 0; s < S_; s++) asum += sam[s];
    float denom = fmaxf(asum, 1.0f);
    for (int d = t; d < 768; d += blockDim.x) {
        float acc = 0.f;
        for (int s = 0; s < S_; s++) acc += emb[(long)sid[s] * 768 + d] * sam[s];
        tf[b * 768 + d] = acc / denom;
    }
}

__global__ void k_rowmm(const float* in, const float* W, const float* bias,
                        float* out, int E, int Nn) {
    int b = blockIdx.x, d = threadIdx.x;
    __shared__ float sin[768];
    for (int e = d; e < E; e += blockDim.x) sin[e] = in[b * E + e];
    __syncthreads();
    float acc = bias[d];
    for (int e = 0; e < E; e++) acc = fmaf(sin[e], W[(long)e * Nn + d], acc);
    out[b * Nn + d] = acc;
}

// ------------------------------------------------- W_enc transpose + bf16 split (one-time, 2 MiB)
// W [1024][512] f32  ->  Bt_hi/Bt_lo [512][1024] bf16
__global__ __launch_bounds__(256) void k_bsplit(const float* __restrict__ W,
                                                unsigned short* __restrict__ bh,
                                                unsigned short* __restrict__ bl) {
    __shared__ float tile[32][33];
    int e0 = blockIdx.x * 32;     // K rows of W
    int d0 = blockIdx.y * 32;     // N cols of W
    int t = threadIdx.x;
    int r = t >> 3;               // 0..31
    int c = (t & 7) * 4;          // 0..28
    float4 v = *(const float4*)(W + (long)(e0 + r) * D_ + d0 + c);
    tile[r][c] = v.x; tile[r][c + 1] = v.y; tile[r][c + 2] = v.z; tile[r][c + 3] = v.w;
    __syncthreads();
    ushort4 h4, l4;
    unsigned short hh, ll;
    float x0 = tile[c + 0][r], x1 = tile[c + 1][r], x2 = tile[c + 2][r], x3 = tile[c + 3][r];
    split_bf(x0, hh, ll); h4.x = hh; l4.x = ll;
    split_bf(x1, hh, ll); h4.y = hh; l4.y = ll;
    split_bf(x2, hh, ll); h4.z = hh; l4.z = ll;
    split_bf(x3, hh, ll); h4.w = hh; l4.w = ll;
    *(ushort4*)(bh + (long)(d0 + r) * 1024 + e0 + c) = h4;
    *(ushort4*)(bl + (long)(d0 + r) * 1024 + e0 + c) = l4;
}

// ------------------------------------------------- split-bf16 MFMA GEMM (the big one)
// C[131072][512] = A[131072][1024] @ W[1024][512] + bias
// A f32 (split in-kernel), W pre-split/transposed: Bt[512][1024] bf16 hi/lo.
// Block: 256 thr (4 waves), tile BM=64 x BN=256, BK=32. Wave w: cols [w*64,w*64+64).
#define GPAD 40   // LDS row stride in bf16 (80 B): 2-way bank conflicts only, 16B-aligned
__global__ __launch_bounds__(256, 3) void k_gemm_mfma(const float* __restrict__ A,
                                                      const unsigned short* __restrict__ Bth,
                                                      const unsigned short* __restrict__ Btl,
                                                      const float* __restrict__ bias,
                                                      float* __restrict__ C) {
    __shared__ __align__(16) unsigned short As[2][64][GPAD];
    __shared__ __align__(16) unsigned short Bs[2][256][GPAD];
    int bm = blockIdx.x, bn = blockIdx.y;
    int tid = threadIdx.x;
    int w = tid >> 6, lane = tid & 63;
    int r32 = lane & 31, kg = lane >> 5;

    f32x16 acc[2][2];
    #pragma unroll
    for (int i = 0; i < 2; i++)
        #pragma unroll
        for (int j = 0; j < 2; j++)
            #pragma unroll
            for (int r = 0; r < 16; r++) acc[i][j][r] = 0.f;

    int arow = tid >> 2, aq = tid & 3;            // A stage: 64 rows x 4 quads
    const float* abase = A + (long)(bm * 64 + arow) * 1024 + aq * 8;
    const unsigned short* bhbase = Bth + (long)(bn * 256 + tid) * 1024;
    const unsigned short* blbase = Btl + (long)(bn * 256 + tid) * 1024;

    for (int kt = 0; kt < 1024; kt += 32) {
        // ---- stage A (f32 -> split bf16 hi/lo) ----
        {
            const float* ap = abase + kt;
            float4 v0 = *(const float4*)ap;
            float4 v1 = *(const float4*)(ap + 4);
            float xs[8] = { v0.x, v0.y, v0.z, v0.w, v1.x, v1.y, v1.z, v1.w };
            unsigned short h[8], l[8];
            #pragma unroll
            for (int i = 0; i < 8; i++) split_bf(xs[i], h[i], l[i]);
            uint4 ph, pl;
            ph.x = h[0] | ((unsigned)h[1] << 16); ph.y = h[2] | ((unsigned)h[3] << 16);
            ph.z = h[4] | ((unsigned)h[5] << 16); ph.w = h[6] | ((unsigned)h[7] << 16);
            pl.x = l[0] | ((unsigned)l[1] << 16); pl.y = l[2] | ((unsigned)l[3] << 16);
            pl.z = l[4] | ((unsigned)l[5] << 16); pl.w = l[6] | ((unsigned)l[7] << 16);
            *(uint4*)&As[0][arow][aq * 8] = ph;
            *(uint4*)&As[1][arow][aq * 8] = pl;
        }
        // ---- stage B (pre-split bf16, contiguous 64 B per col) ----
        {
            const uint4* ph = (const uint4*)(bhbase + kt);
            const uint4* pl = (const uint4*)(blbase + kt);
            uint4 h0 = ph[0], h1 = ph[1], h2 = ph[2], h3 = ph[3];
            uint4 l0 = pl[0], l1 = pl[1], l2 = pl[2], l3 = pl[3];
            *(uint4*)&Bs[0][tid][0]  = h0; *(uint4*)&Bs[0][tid][8]  = h1;
            *(uint4*)&Bs[0][tid][16] = h2; *(uint4*)&Bs[0][tid][24] = h3;
            *(uint4*)&Bs[1][tid][0]  = l0; *(uint4*)&Bs[1][tid][8]  = l1;
            *(uint4*)&Bs[1][tid][16] = l2; *(uint4*)&Bs[1][tid][24] = l3;
        }
        __syncthreads();
        // ---- compute: 2 k-halves x (2 rf x 2 cf) x 3 split terms ----
        #pragma unroll
        for (int k2 = 0; k2 < 2; k2++) {
            int ko = k2 * 16 + kg * 8;
            bf16x8 ah[2], al[2], bh[2], blv[2];
            #pragma unroll
            for (int rf = 0; rf < 2; rf++) {
                ah[rf] = *(const bf16x8*)&As[0][rf * 32 + r32][ko];
                al[rf] = *(const bf16x8*)&As[1][rf * 32 + r32][ko];
            }
            #pragma unroll
            for (int cf = 0; cf < 2; cf++) {
                bh[cf]  = *(const bf16x8*)&Bs[0][w * 64 + cf * 32 + r32][ko];
                blv[cf] = *(const bf16x8*)&Bs[1][w * 64 + cf * 32 + r32][ko];
            }
            #pragma unroll
            for (int rf = 0; rf < 2; rf++)
                #pragma unroll
                for (int cf = 0; cf < 2; cf++) {
                    acc[rf][cf] = __builtin_amdgcn_mfma_f32_32x32x16_bf16(ah[rf], bh[cf],  acc[rf][cf], 0, 0, 0);
                    acc[rf][cf] = __builtin_amdgcn_mfma_f32_32x32x16_bf16(ah[rf], blv[cf], acc[rf][cf], 0, 0, 0);
                    acc[rf][cf] = __builtin_amdgcn_mfma_f32_32x32x16_bf16(al[rf], bh[cf],  acc[rf][cf], 0, 0, 0);
                }
        }
        __syncthreads();
    }
    // ---- epilogue: D layout col=lane&31, row=(reg&3)+8*(reg>>2)+4*(lane>>5) ----
    #pragma unroll
    for (int rf = 0; rf < 2; rf++)
        #pragma unroll
        for (int cf = 0; cf < 2; cf++) {
            int col = bn * 256 + w * 64 + cf * 32 + r32;
            float bv = bias[col];
            #pragma unroll
            for (int r = 0; r < 16; r++) {
                int row = bm * 64 + rf * 32 + (r & 3) + 8 * (r >> 2) + 4 * kg;
                C[(long)row * D_ + col] = acc[rf][cf][r] + bv;
            }
        }
}

// ------------------------------------------------- tiled f32 GEMM (small k/v projections)
#define BM 128
#define BN 64
#define BK 32
#define ASTR 136
__global__ __launch_bounds__(256) void k_gemm(const float* __restrict__ A, int lda,
                                              const float* __restrict__ Bw, int ldb,
                                              const float* __restrict__ bias,
                                              float* __restrict__ C, int ldc, int K) {
    __shared__ float As[BK][ASTR];
    __shared__ float Bsf[BK][BN];
    int bm = blockIdx.x, bn = blockIdx.y;
    int tid = threadIdx.x;
    int trow = tid >> 4, tcol = tid & 15;
    float acc[8][4] = {};
    const float* Ab = A + (long)bm * BM * lda;
    const float* Bb = Bw + bn * BN;
    for (int kt = 0; kt < K; kt += BK) {
        #pragma unroll
        for (int i = 0; i < 4; i++) {
            int f = tid + 256 * i;
            int row = f >> 3, c4 = (f & 7) << 2;
            float4 v = *(const float4*)(Ab + (long)row * lda + kt + c4);
            As[c4 + 0][row] = v.x; As[c4 + 1][row] = v.y;
            As[c4 + 2][row] = v.z; As[c4 + 3][row] = v.w;
        }
        #pragma unroll
        for (int i = 0; i < 2; i++) {
            int f = tid + 256 * i;
            int row = f >> 4, c4 = (f & 15) << 2;
            *(float4*)&Bsf[row][c4] = *(const float4*)(Bb + (long)(kt + row) * ldb + c4);
        }
        __syncthreads();
        #pragma unroll 8
        for (int kk = 0; kk < BK; kk++) {
            float a[8], bv[4];
            #pragma unroll
            for (int i = 0; i < 8; i++) a[i] = As[kk][trow * 8 + i];
            #pragma unroll
            for (int j = 0; j < 4; j++) bv[j] = Bsf[kk][tcol * 4 + j];
            #pragma unroll
            for (int i = 0; i < 8; i++)
                #pragma unroll
                for (int j = 0; j < 4; j++)
                    acc[i][j] = fmaf(a[i], bv[j], acc[i][j]);
        }
        __syncthreads();
    }
    int c = bn * BN + tcol * 4;
    #pragma unroll
    for (int i = 0; i < 8; i++) {
        long r = (long)bm * BM + trow * 8 + i;
        float4 v;
        v.x = acc[i][0] + bias[c + 0]; v.y = acc[i][1] + bias[c + 1];
        v.z = acc[i][2] + bias[c + 2]; v.w = acc[i][3] + bias[c + 3];
        *(float4*)(C + r * ldc + c) = v;
    }
}

// ------------------------------------------------- LayerNorm+ReLU (in place) + rnorm + rel
__global__ __launch_bounds__(256) void k_ln(float* h, const float* g, const float* bb,
                                            const float* temb, float* rnorm, float* rel) {
    int wid = threadIdx.x >> 6, lane = threadIdx.x & 63;
    long row = (long)blockIdx.x * 4 + wid;
    int b = (int)(row >> 14);
    float* hp = h + row * (long)D_;
    int c0 = lane * 4, c1 = 256 + lane * 4;
    float4 x0 = *(float4*)(hp + c0);
    float4 x1 = *(float4*)(hp + c1);
    float x[8] = { x0.x, x0.y, x0.z, x0.w, x1.x, x1.y, x1.z, x1.w };
    float s = 0.f;
    #pragma unroll
    for (int i = 0; i < 8; i++) s += x[i];
    s = wred_sum(s);
    float mu = s * (1.0f / 512.0f);
    float var = 0.f;
    #pragma unroll
    for (int i = 0; i < 8; i++) { float d = x[i] - mu; var += d * d; }
    var = wred_sum(var) * (1.0f / 512.0f);
    float inv = 1.0f / sqrtf(var + 1e-5f);
    float4 g0 = *(const float4*)(g + c0), g1 = *(const float4*)(g + c1);
    float4 b0 = *(const float4*)(bb + c0), b1 = *(const float4*)(bb + c1);
    float gg[8] = { g0.x, g0.y, g0.z, g0.w, g1.x, g1.y, g1.z, g1.w };
    float bbv[8] = { b0.x, b0.y, b0.z, b0.w, b1.x, b1.y, b1.z, b1.w };
    float y[8], sq = 0.f;
    #pragma unroll
    for (int i = 0; i < 8; i++) {
        y[i] = fmaxf(gg[i] * (x[i] - mu) * inv + bbv[i], 0.0f);
        sq += y[i] * y[i];
    }
    float4 o0 = { y[0], y[1], y[2], y[3] }, o1 = { y[4], y[5], y[6], y[7] };
    *(float4*)(hp + c0) = o0;
    *(float4*)(hp + c1) = o1;
    sq = wred_sum(sq);
    float rn = 1.0f / (sqrtf(sq) + 1e-8f);
    const float* tp = temb + (long)b * D_;
    float4 t0 = *(const float4*)(tp + c0), t1 = *(const float4*)(tp + c1);
    float tt[8] = { t0.x, t0.y, t0.z, t0.w, t1.x, t1.y, t1.z, t1.w };
    float rl = 0.f;
    #pragma unroll
    for (int i = 0; i < 8; i++) rl = fmaf(y[i], tt[i], rl);
    rl = wred_sum(rl);
    if (lane == 0) { rnorm[row] = rn; rel[row] = rl; }
}

// ------------------------------------------------- sliding-window cosine pruning
#define CHUNK 28
#define KROWS 60
__global__ __launch_bounds__(256) void k_sim(const float* img, const float* rnorm,
                                             const unsigned char* vld, int* keep) {
    __shared__ __hip_bfloat16 fnb[KROWS][D_];
    long c0 = (long)blockIdx.x * CHUNK;
    int tid = threadIdx.x;
    for (int idx = tid; idx < KROWS * (D_ / 8); idx += 256) {
        int rr = idx / (D_ / 8);
        int cc = (idx % (D_ / 8)) * 8;
        long grow = c0 - WIN_ + rr;
        if (grow < 0) grow = 0;
        if (grow >= NTOK_) grow = NTOK_ - 1;
        float rn = rnorm[grow];
        const float* p = img + grow * (long)D_ + cc;
        float4 u = *(const float4*)p, w = *(const float4*)(p + 4);
        fnb[rr][cc + 0] = __float2bfloat16(u.x * rn);
        fnb[rr][cc + 1] = __float2bfloat16(u.y * rn);
        fnb[rr][cc + 2] = __float2bfloat16(u.z * rn);
        fnb[rr][cc + 3] = __float2bfloat16(u.w * rn);
        fnb[rr][cc + 4] = __float2bfloat16(w.x * rn);
        fnb[rr][cc + 5] = __float2bfloat16(w.y * rn);
        fnb[rr][cc + 6] = __float2bfloat16(w.z * rn);
        fnb[rr][cc + 7] = __float2bfloat16(w.w * rn);
    }
    __syncthreads();
    int wid = tid >> 6, lane = tid & 63;
    for (int ti = 0; ti < 7; ti++) {
        int tloc = wid * 7 + ti;
        long t = c0 + tloc;
        if (t >= NTOK_) continue;
        int lr = WIN_ + tloc;
        int tl = (int)(t & (N_ - 1));
        float a[8];
        bf8_to_f32(*(const uint4*)&fnb[lr][lane * 8], a);
        int wmax = tl < WIN_ ? tl : WIN_;
        float msim = -INFINITY;
        for (int w = 1; w <= wmax; w++) {
            if (!vld[t - w]) continue;
            float bvv[8];
            bf8_to_f32(*(const uint4*)&fnb[lr - w][lane * 8], bvv);
            float p = 0.f;
            #pragma unroll
            for (int i = 0; i < 8; i++) p = fmaf(a[i], bvv[i], p);
            p = wred_sum(p);
            msim = fmaxf(msim, p);
        }
        int kp = (vld[t] && (msim < 0.7f)) ? 1 : 0;
        if (lane == 0) keep[t] = kp;
    }
}

// ------------------------------------------------- per-batch exact top-k (radix select)
static __device__ void scan1024(int* tot, int tid) {
    if (tid < 64) {
        int vals[16], s = 0;
        #pragma unroll
        for (int i = 0; i < 16; i++) vals[i] = tot[tid * 16 + i];
        #pragma unroll
        for (int i = 0; i < 16; i++) { int t = vals[i]; vals[i] = s; s += t; }
        int inc = s;
        #pragma unroll
        for (int d = 1; d < 64; d <<= 1) {
            int v = __shfl_up(inc, d, 64);
            if ((tid & 63) >= d) inc += v;
        }
        int excl = inc - s;
        #pragma unroll
        for (int i = 0; i < 16; i++) tot[tid * 16 + i] = vals[i] + excl;
    }
}

__global__ __launch_bounds__(1024) void k_topk(const float* rel, const int* keep, int* idxo) {
    int b = blockIdx.x, tid = threadIdx.x;
    const float* relb = rel + (long)b * N_;
    const int* keepb  = keep + (long)b * N_;
    __shared__ unsigned int hist[256];
    __shared__ int toti[1024];
    __shared__ unsigned int s_prefix;
    __shared__ int s_rem, s_k;

    unsigned int key[16];
    int base = tid * 16, nk_local = 0;
    #pragma unroll
    for (int j = 0; j < 16; j++) {
        int i = base + j;
        float r = relb[i];
        int kp = keepb[i];
        unsigned int bits = __float_as_uint(r);
        unsigned int kk = (bits & 0x80000000u) ? ~bits : (bits | 0x80000000u);
        key[j] = kp ? kk : 0u;
        nk_local += kp;
    }
    toti[tid] = nk_local; __syncthreads();
    for (int o = 512; o > 0; o >>= 1) { if (tid < o) toti[tid] += toti[tid + o]; __syncthreads(); }
    if (tid == 0) {
        int n_kept = toti[0];
        int k = (int)(0.8f * (float)n_kept);
        if (k < 1) k = 1; if (k > LMAX_) k = LMAX_;
        s_k = k; s_rem = k; s_prefix = 0u;
    }
    __syncthreads();

    for (int pass = 0; pass < 4; pass++) {
        int shift = 24 - pass * 8;
        unsigned int himask = (pass == 0) ? 0u : (0xFFFFFFFFu << (shift + 8));
        if (tid < 256) hist[tid] = 0u;
        __syncthreads();
        unsigned int pfx = s_prefix;
        #pragma unroll
        for (int j = 0; j < 16; j++) {
            unsigned int kk = key[j];
            if ((kk & himask) == (pfx & himask))
                atomicAdd(&hist[(kk >> shift) & 255], 1u);
        }
        __syncthreads();
        if (tid == 0) {
            int rem = s_rem;
            unsigned int cum = 0;
            for (int d = 255; d >= 0; d--) {
                unsigned int h = hist[d];
                if (cum + h >= (unsigned int)rem) {
                    s_rem = rem - (int)cum;
                    s_prefix = pfx | ((unsigned int)d << shift);
                    break;
                }
                cum += h;
            }
        }
        __syncthreads();
    }
    unsigned int T = s_prefix;
    int tie_need = s_rem, k = s_k;

    int eq[16], gt[16], eqpre[16];
    int locEq = 0;
    #pragma unroll
    for (int j = 0; j < 16; j++) {
        eq[j] = (key[j] == T); gt[j] = (key[j] > T);
        eqpre[j] = locEq; locEq += eq[j];
    }
    toti[tid] = locEq; __syncthreads();
    scan1024(toti, tid); __syncthreads();
    int eqoff = toti[tid];

    int sel[16], spre[16];
    int locS = 0;
    #pragma unroll
    for (int j = 0; j < 16; j++) {
        int rank = eqoff + eqpre[j];
        sel[j] = gt[j] || (eq[j] && rank < tie_need);
        spre[j] = locS; locS += sel[j];
    }
    __syncthreads();
    toti[tid] = locS; __syncthreads();
    scan1024(toti, tid); __syncthreads();
    int soff = toti[tid];
    #pragma unroll
    for (int j = 0; j < 16; j++)
        if (sel[j]) idxo[b * LMAX_ + soff + spre[j]] = base + j;
    for (int p = k + tid; p < LMAX_; p += 1024) idxo[b * LMAX_ + p] = N_;
}

// ------------------------------------------------- feat2 gather + pair pooling
__global__ void k_feat3(const float* img, const int* idxo, float* f3) {
    int bm = blockIdx.x;
    int b = bm >> 9, m = bm & 511;
    int i0 = idxo[b * LMAX_ + 2 * m], i1 = idxo[b * LMAX_ + 2 * m + 1];
    int c0 = i0 < N_, c1 = i1 < N_;
    float dn = 1.0f / fmaxf((float)(c0 + c1), 1.0f);
    const float* p0 = img + ((long)b * N_ + (c0 ? i0 : 0)) * D_;
    const float* p1 = img + ((long)b * N_ + (c1 ? i1 : 0)) * D_;
    int d = threadIdx.x * 4;
    float4 v0 = c0 ? *(const float4*)(p0 + d) : make_float4(0.f, 0.f, 0.f, 0.f);
    float4 v1 = c1 ? *(const float4*)(p1 + d) : make_float4(0.f, 0.f, 0.f, 0.f);
    float4 o;
    o.x = (v0.x + v1.x) * dn; o.y = (v0.y + v1.y) * dn;
    o.z = (v0.z + v1.z) * dn; o.w = (v0.w + v1.w) * dn;
    *(float4*)(f3 + (long)bm * D_ + d) = o;
}

// ------------------------------------------------- cross-modal attention
__global__ __launch_bounds__(512) void k_attn(const float* qv, const float* kk,
                                              const float* vv, float* ctx) {
    int bh = blockIdx.x;
    int b = bh >> 3, h = bh & 7;
    __shared__ float qs[DH_];
    __shared__ float sc[M2_];
    __shared__ float red[M2_];
    int m = threadIdx.x;
    if (m < DH_) qs[m] = qv[b * D_ + h * DH_ + m];
    __syncthreads();
    const float* kp = kk + (long)b * M2_ * D_ + h * DH_;
    float acc = 0.f;
    #pragma unroll
    for (int d = 0; d < DH_; d += 4) {
        float4 kv = *(const float4*)(kp + (long)m * D_ + d);
        acc += qs[d] * kv.x + qs[d + 1] * kv.y + qs[d + 2] * kv.z + qs[d + 3] * kv.w;
    }
    acc *= 0.125f;
    red[m] = acc; __syncthreads();
    for (int o = 256; o > 0; o >>= 1) { if (m < o) red[m] = fmaxf(red[m], red[m + o]); __syncthreads(); }
    float mx = red[0]; __syncthreads();
    float e = expf(acc - mx);
    sc[m] = e; red[m] = e; __syncthreads();
    for (int o = 256; o > 0; o >>= 1) { if (m < o) red[m] += red[m + o]; __syncthreads(); }
    float inv = 1.0f / red[0];
    if (m < DH_) {
        float a2 = 0.f;
        const float* vp = vv + (long)b * M2_ * D_ + h * DH_ + m;
        for (int mm = 0; mm < M2_; mm++) a2 = fmaf(sc[mm], vp[(long)mm * D_], a2);
        ctx[b * D_ + h * DH_ + m] = a2 * inv;
    }
}

// ------------------------------------------------- output head (Wo then W_cls), f32 out
__global__ __launch_bounds__(512) void k_head(const float* ctx, const float* Wo, const float* bo,
                                              const float* Wc, const float* bc,
                                              float* out) {
    int b = blockIdx.x, d = threadIdx.x;
    __shared__ float cl[D_], ol[D_];
    cl[d] = ctx[b * D_ + d]; __syncthreads();
    float acc = bo[d];
    for (int e = 0; e < D_; e++) acc = fmaf(cl[e], Wo[(long)e * D_ + d], acc);
    ol[d] = acc; __syncthreads();
    if (d < 4) {
        float a2 = bc[d];
        for (int e = 0; e < D_; e++) a2 = fmaf(ol[e], Wc[e * 4 + d], a2);
        out[b * 4 + d] = a2;
    }
}

// ---------------------------------------------------------------- launcher
extern "C" void kernel_launch(void* const* d_in, const int* in_sizes, int n_in,
                              void* d_out, int out_size, void* d_ws, size_t ws_size,
                              hipStream_t stream) {
    const float* bags = (const float*)d_in[0];
    const void*  kpm  = d_in[1];
    const int*   ids  = (const int*)d_in[2];
    const int*   am   = (const int*)d_in[3];
    const float* emb  = (const float*)d_in[4];
    const float* Wtp  = (const float*)d_in[5];
    const float* btp  = (const float*)d_in[6];
    const float* Wen  = (const float*)d_in[7];
    const float* ben  = (const float*)d_in[8];
    const float* lng  = (const float*)d_in[9];
    const float* lnb  = (const float*)d_in[10];
    const float* Wq   = (const float*)d_in[11];
    const float* bq   = (const float*)d_in[12];
    const float* Wk   = (const float*)d_in[13];
    const float* bk   = (const float*)d_in[14];
    const float* Wv   = (const float*)d_in[15];
    const float* bv   = (const float*)d_in[16];
    const float* Wo   = (const float*)d_in[17];
    const float* bo   = (const float*)d_in[18];
    const float* Wc   = (const float*)d_in[19];
    const float* bc   = (const float*)d_in[20];

    char* ws = (char*)d_ws;
    size_t o = 0;
    auto alloc = [&](size_t bytes) -> void* {
        void* p = ws + o; o += (bytes + 255) & ~(size_t)255; return p;
    };
    float* img  = (float*)alloc((size_t)NTOK_ * D_ * 4);
    float* rno  = (float*)alloc((size_t)NTOK_ * 4);
    float* rel  = (float*)alloc((size_t)NTOK_ * 4);
    int*   keep = (int*)alloc((size_t)NTOK_ * 4);
    unsigned char* vld = (unsigned char*)alloc(NTOK_);
    float* tf   = (float*)alloc(B_ * 768 * 4);
    float* te   = (float*)alloc(B_ * D_ * 4);
    float* qv   = (float*)alloc(B_ * D_ * 4);
    int*   idxo = (int*)alloc(B_ * LMAX_ * 4);
    float* f3   = (float*)alloc((size_t)B_ * M2_ * D_ * 4);
    float* kkb  = (float*)alloc((size_t)B_ * M2_ * D_ * 4);
    float* vvb  = (float*)alloc((size_t)B_ * M2_ * D_ * 4);
    float* ctx  = (float*)alloc(B_ * D_ * 4);
    int*   flag = (int*)alloc(256);
    unsigned short* bth = (unsigned short*)alloc((size_t)D_ * F_ * 2);
    unsigned short* btl = (unsigned short*)alloc((size_t)D_ * F_ * 2);

    k_detect<<<1, 256, 0, stream>>>((const unsigned char*)kpm, NTOK_, flag);
    k_valid<<<(NTOK_ + 255) / 256, 256, 0, stream>>>(kpm, flag, vld);
    k_text_feat<<<B_, 256, 0, stream>>>(emb, ids, am, tf);
    k_rowmm<<<B_, 512, 0, stream>>>(tf, Wtp, btp, te, 768, 512);
    k_rowmm<<<B_, 512, 0, stream>>>(te, Wq, bq, qv, 512, 512);

    dim3 gsplit(F_ / 32, D_ / 32);
    k_bsplit<<<gsplit, 256, 0, stream>>>(Wen, bth, btl);
    dim3 g3(NTOK_ / 64, 2);
    k_gemm_mfma<<<g3, 256, 0, stream>>>(bags, bth, btl, ben, img);

    k_ln<<<NTOK_ / 4, 256, 0, stream>>>(img, lng, lnb, te, rno, rel);
    k_sim<<<(NTOK_ + CHUNK - 1) / CHUNK, 256, 0, stream>>>(img, rno, vld, keep);
    k_topk<<<B_, 1024, 0, stream>>>(rel, keep, idxo);
    k_feat3<<<B_ * M2_, 128, 0, stream>>>(img, idxo, f3);

    dim3 g8(B_ * M2_ / BM, D_ / BN);
    k_gemm<<<g8, 256, 0, stream>>>(f3, D_, Wk, D_, bk, kkb, D_, D_);
    k_gemm<<<g8, 256, 0, stream>>>(f3, D_, Wv, D_, bv, vvb, D_, D_);

    k_attn<<<B_ * H_, 512, 0, stream>>>(qv, kkb, vvb, ctx);
    k_head<<<B_, 512, 0, stream>>>(ctx, Wo, bo, Wc, bc, (float*)d_out);
}

// Round 4
// 1363.865 us; speedup vs baseline: 2.5040x; 1.5482x over previous
//
#include <hip/hip_runtime.h>
#include <hip/hip_bf16.h>
#include <math.h>
#include <stdint.h>

#define B_    8
#define N_    16384
#define F_    1024
#define D_    512
#define S_    64
#define H_    8
#define DH_   64
#define LMAX_ 1024
#define M2_   512
#define WIN_  32
#define NTOK_ (B_ * N_)   // 131072

typedef __attribute__((ext_vector_type(8)))  short bf16x8;
typedef __attribute__((ext_vector_type(16))) float f32x16;

// ---------------------------------------------------------------- utilities
static __device__ __forceinline__ float wred_sum(float v) {
    #pragma unroll
    for (int d = 1; d < 64; d <<= 1) v += __shfl_xor(v, d, 64);
    return v;
}

static __device__ __forceinline__ void bf8_to_f32(uint4 q, float* a) {
    a[0] = __uint_as_float(q.x << 16); a[1] = __uint_as_float(q.x & 0xffff0000u);
    a[2] = __uint_as_float(q.y << 16); a[3] = __uint_as_float(q.y & 0xffff0000u);
    a[4] = __uint_as_float(q.z << 16); a[5] = __uint_as_float(q.z & 0xffff0000u);
    a[6] = __uint_as_float(q.w << 16); a[7] = __uint_as_float(q.w & 0xffff0000u);
}

static __device__ __forceinline__ unsigned short bf16r(float x) {   // RNE f32->bf16
    unsigned int b = __float_as_uint(x);
    return (unsigned short)((b + 0x7FFFu + ((b >> 16) & 1u)) >> 16);
}

// RNE split: x ~= hi + lo (both bf16), dropped residual ~2^-17 |x|
static __device__ __forceinline__ void split_bf(float x, unsigned short& h, unsigned short& l) {
    unsigned int b = __float_as_uint(x);
    unsigned int hb = (b + 0x7FFFu + ((b >> 16) & 1u)) >> 16;
    h = (unsigned short)hb;
    float r = x - __uint_as_float(hb << 16);
    l = bf16r(r);
}

// ------------------------------------------------- mask layout detection
__global__ void k_detect(const unsigned char* mb, int nbytes, int* flag) {
    int found = 0;
    for (int i = blockIdx.x * blockDim.x + threadIdx.x; i < nbytes; i += gridDim.x * blockDim.x)
        if ((i & 3) && mb[i]) found = 1;
    if (found) atomicOr(flag, 1);
}

__global__ void k_valid(const void* maskp, const int* flag, unsigned char* v) {
    int i = blockIdx.x * 256 + threadIdx.x;
    if (i >= NTOK_) return;
    int pad;
    if (*flag) pad = (((const unsigned char*)maskp)[i] != 0);
    else       pad = (((const int*)maskp)[i] != 0);
    v[i] = pad ? 0 : 1;
}

// ------------------------------------------------- text feature (masked mean)
__global__ void k_text_feat(const float* emb, const int* ids, const int* am, float* tf) {
    int b = blockIdx.x;
    __shared__ int   sid[S_];
    __shared__ float sam[S_];
    int t = threadIdx.x;
    if (t < S_) { sid[t] = ids[b * S_ + t]; sam[t] = (float)am[b * S_ + t]; }
    __syncthreads();
    float asum = 0.f;
    for (int s = 0; s < S_; s++) asum += sam[s];
    float denom = fmaxf(asum, 1.0f);
    for (int d = t; d < 768; d += blockDim.x) {
        float acc = 0.f;
        for (int s = 0; s < S_; s++) acc += emb[(long)sid[s] * 768 + d] * sam[s];
        tf[b * 768 + d] = acc / denom;
    }
}

__global__ void k_rowmm(const float* in, const float* W, const float* bias,
                        float* out, int E, int Nn) {
    int b = blockIdx.x, d = threadIdx.x;
    __shared__ float sin[768];
    for (int e = d; e < E; e += blockDim.x) sin[e] = in[b * E + e];
    __syncthreads();
    float acc = bias[d];
    for (int e = 0; e < E; e++) acc = fmaf(sin[e], W[(long)e * Nn + d], acc);
    out[b * Nn + d] = acc;
}

// ------------------------------------------------- W_enc transpose + bf16 split (one-time)
__global__ __launch_bounds__(256) void k_bsplit(const float* __restrict__ W,
                                                unsigned short* __restrict__ bh,
                                                unsigned short* __restrict__ bl) {
    __shared__ float tile[32][33];
    int e0 = blockIdx.x * 32;
    int d0 = blockIdx.y * 32;
    int t = threadIdx.x;
    int r = t >> 3;
    int c = (t & 7) * 4;
    float4 v = *(const float4*)(W + (long)(e0 + r) * D_ + d0 + c);
    tile[r][c] = v.x; tile[r][c + 1] = v.y; tile[r][c + 2] = v.z; tile[r][c + 3] = v.w;
    __syncthreads();
    ushort4 h4, l4;
    unsigned short hh, ll;
    float x0 = tile[c + 0][r], x1 = tile[c + 1][r], x2 = tile[c + 2][r], x3 = tile[c + 3][r];
    split_bf(x0, hh, ll); h4.x = hh; l4.x = ll;
    split_bf(x1, hh, ll); h4.y = hh; l4.y = ll;
    split_bf(x2, hh, ll); h4.z = hh; l4.z = ll;
    split_bf(x3, hh, ll); h4.w = hh; l4.w = ll;
    *(ushort4*)(bh + (long)(d0 + r) * 1024 + e0 + c) = h4;
    *(ushort4*)(bl + (long)(d0 + r) * 1024 + e0 + c) = l4;
}

// ------------------------------------------------- split-bf16 MFMA GEMM (the big one)
// C[131072][512] = A[131072][1024] @ W[1024][512] + bias
// A-prefetch (issue-early, T14): next K-step's HBM loads overlap current MFMA phase.
#define GPAD 40
__global__ __launch_bounds__(256, 3) void k_gemm_mfma(const float* __restrict__ A,
                                                      const unsigned short* __restrict__ Bth,
                                                      const unsigned short* __restrict__ Btl,
                                                      const float* __restrict__ bias,
                                                      float* __restrict__ C) {
    __shared__ __align__(16) unsigned short As[2][64][GPAD];
    __shared__ __align__(16) unsigned short Bs[2][256][GPAD];
    int bm = blockIdx.x, bn = blockIdx.y;
    int tid = threadIdx.x;
    int w = tid >> 6, lane = tid & 63;
    int r32 = lane & 31, kg = lane >> 5;

    f32x16 acc[2][2];
    #pragma unroll
    for (int i = 0; i < 2; i++)
        #pragma unroll
        for (int j = 0; j < 2; j++)
            #pragma unroll
            for (int r = 0; r < 16; r++) acc[i][j][r] = 0.f;

    int arow = tid >> 2, aq = tid & 3;
    const float* abase = A + (long)(bm * 64 + arow) * 1024 + aq * 8;
    const unsigned short* bhbase = Bth + (long)(bn * 256 + tid) * 1024;
    const unsigned short* blbase = Btl + (long)(bn * 256 + tid) * 1024;

    float4 pa0 = *(const float4*)abase;          // prefetch kt=0
    float4 pa1 = *(const float4*)(abase + 4);

    for (int kt = 0; kt < 1024; kt += 32) {
        // ---- store phase: A regs -> split -> LDS; B (L2-hot) -> LDS ----
        {
            float xs[8] = { pa0.x, pa0.y, pa0.z, pa0.w, pa1.x, pa1.y, pa1.z, pa1.w };
            unsigned short h[8], l[8];
            #pragma unroll
            for (int i = 0; i < 8; i++) split_bf(xs[i], h[i], l[i]);
            uint4 ph, pl;
            ph.x = h[0] | ((unsigned)h[1] << 16); ph.y = h[2] | ((unsigned)h[3] << 16);
            ph.z = h[4] | ((unsigned)h[5] << 16); ph.w = h[6] | ((unsigned)h[7] << 16);
            pl.x = l[0] | ((unsigned)l[1] << 16); pl.y = l[2] | ((unsigned)l[3] << 16);
            pl.z = l[4] | ((unsigned)l[5] << 16); pl.w = l[6] | ((unsigned)l[7] << 16);
            *(uint4*)&As[0][arow][aq * 8] = ph;
            *(uint4*)&As[1][arow][aq * 8] = pl;
        }
        {
            const uint4* ph = (const uint4*)(bhbase + kt);
            const uint4* pl = (const uint4*)(blbase + kt);
            #pragma unroll
            for (int q = 0; q < 4; q++) {
                *(uint4*)&Bs[0][tid][q * 8] = ph[q];
                *(uint4*)&Bs[1][tid][q * 8] = pl[q];
            }
        }
        __syncthreads();
        // ---- issue next A prefetch (overlaps MFMA phase) ----
        if (kt + 32 < 1024) {
            const float* ap = abase + kt + 32;
            pa0 = *(const float4*)ap;
            pa1 = *(const float4*)(ap + 4);
        }
        // ---- compute ----
        #pragma unroll
        for (int k2 = 0; k2 < 2; k2++) {
            int ko = k2 * 16 + kg * 8;
            bf16x8 ah[2], al[2], bh[2], blv[2];
            #pragma unroll
            for (int rf = 0; rf < 2; rf++) {
                ah[rf] = *(const bf16x8*)&As[0][rf * 32 + r32][ko];
                al[rf] = *(const bf16x8*)&As[1][rf * 32 + r32][ko];
            }
            #pragma unroll
            for (int cf = 0; cf < 2; cf++) {
                bh[cf]  = *(const bf16x8*)&Bs[0][w * 64 + cf * 32 + r32][ko];
                blv[cf] = *(const bf16x8*)&Bs[1][w * 64 + cf * 32 + r32][ko];
            }
            #pragma unroll
            for (int rf = 0; rf < 2; rf++)
                #pragma unroll
                for (int cf = 0; cf < 2; cf++) {
                    acc[rf][cf] = __builtin_amdgcn_mfma_f32_32x32x16_bf16(ah[rf], bh[cf],  acc[rf][cf], 0, 0, 0);
                    acc[rf][cf] = __builtin_amdgcn_mfma_f32_32x32x16_bf16(ah[rf], blv[cf], acc[rf][cf], 0, 0, 0);
                    acc[rf][cf] = __builtin_amdgcn_mfma_f32_32x32x16_bf16(al[rf], bh[cf],  acc[rf][cf], 0, 0, 0);
                }
        }
        __syncthreads();
    }
    #pragma unroll
    for (int rf = 0; rf < 2; rf++)
        #pragma unroll
        for (int cf = 0; cf < 2; cf++) {
            int col = bn * 256 + w * 64 + cf * 32 + r32;
            float bv = bias[col];
            #pragma unroll
            for (int r = 0; r < 16; r++) {
                int row = bm * 64 + rf * 32 + (r & 3) + 8 * (r >> 2) + 4 * kg;
                C[(long)row * D_ + col] = acc[rf][cf][r] + bv;
            }
        }
}

// ------------------------------------------------- tiled f32 GEMM (small k/v projections)
#define BM 128
#define BN 64
#define BK 32
#define ASTR 136
__global__ __launch_bounds__(256) void k_gemm(const float* __restrict__ A, int lda,
                                              const float* __restrict__ Bw, int ldb,
                                              const float* __restrict__ bias,
                                              float* __restrict__ C, int ldc, int K) {
    __shared__ float As[BK][ASTR];
    __shared__ float Bsf[BK][BN];
    int bm = blockIdx.x, bn = blockIdx.y;
    int tid = threadIdx.x;
    int trow = tid >> 4, tcol = tid & 15;
    float acc[8][4] = {};
    const float* Ab = A + (long)bm * BM * lda;
    const float* Bb = Bw + bn * BN;
    for (int kt = 0; kt < K; kt += BK) {
        #pragma unroll
        for (int i = 0; i < 4; i++) {
            int f = tid + 256 * i;
            int row = f >> 3, c4 = (f & 7) << 2;
            float4 v = *(const float4*)(Ab + (long)row * lda + kt + c4);
            As[c4 + 0][row] = v.x; As[c4 + 1][row] = v.y;
            As[c4 + 2][row] = v.z; As[c4 + 3][row] = v.w;
        }
        #pragma unroll
        for (int i = 0; i < 2; i++) {
            int f = tid + 256 * i;
            int row = f >> 4, c4 = (f & 15) << 2;
            *(float4*)&Bsf[row][c4] = *(const float4*)(Bb + (long)(kt + row) * ldb + c4);
        }
        __syncthreads();
        #pragma unroll 8
        for (int kk = 0; kk < BK; kk++) {
            float a[8], bv[4];
            #pragma unroll
            for (int i = 0; i < 8; i++) a[i] = As[kk][trow * 8 + i];
            #pragma unroll
            for (int j = 0; j < 4; j++) bv[j] = Bsf[kk][tcol * 4 + j];
            #pragma unroll
            for (int i = 0; i < 8; i++)
                #pragma unroll
                for (int j = 0; j < 4; j++)
                    acc[i][j] = fmaf(a[i], bv[j], acc[i][j]);
        }
        __syncthreads();
    }
    int c = bn * BN + tcol * 4;
    #pragma unroll
    for (int i = 0; i < 8; i++) {
        long r = (long)bm * BM + trow * 8 + i;
        float4 v;
        v.x = acc[i][0] + bias[c + 0]; v.y = acc[i][1] + bias[c + 1];
        v.z = acc[i][2] + bias[c + 2]; v.w = acc[i][3] + bias[c + 3];
        *(float4*)(C + r * ldc + c) = v;
    }
}

// ------------------------------------------------- LayerNorm+ReLU (in place) + rnorm + rel (+fnb)
__global__ __launch_bounds__(256) void k_ln(float* h, const float* g, const float* bb,
                                            const float* temb, float* rnorm, float* rel,
                                            unsigned short* fnb) {
    int wid = threadIdx.x >> 6, lane = threadIdx.x & 63;
    long row = (long)blockIdx.x * 4 + wid;
    int b = (int)(row >> 14);
    float* hp = h + row * (long)D_;
    int c0 = lane * 4, c1 = 256 + lane * 4;
    float4 x0 = *(float4*)(hp + c0);
    float4 x1 = *(float4*)(hp + c1);
    float x[8] = { x0.x, x0.y, x0.z, x0.w, x1.x, x1.y, x1.z, x1.w };
    float s = 0.f;
    #pragma unroll
    for (int i = 0; i < 8; i++) s += x[i];
    s = wred_sum(s);
    float mu = s * (1.0f / 512.0f);
    float var = 0.f;
    #pragma unroll
    for (int i = 0; i < 8; i++) { float d = x[i] - mu; var += d * d; }
    var = wred_sum(var) * (1.0f / 512.0f);
    float inv = 1.0f / sqrtf(var + 1e-5f);
    float4 g0 = *(const float4*)(g + c0), g1 = *(const float4*)(g + c1);
    float4 b0 = *(const float4*)(bb + c0), b1 = *(const float4*)(bb + c1);
    float gg[8] = { g0.x, g0.y, g0.z, g0.w, g1.x, g1.y, g1.z, g1.w };
    float bbv[8] = { b0.x, b0.y, b0.z, b0.w, b1.x, b1.y, b1.z, b1.w };
    float y[8], sq = 0.f;
    #pragma unroll
    for (int i = 0; i < 8; i++) {
        y[i] = fmaxf(gg[i] * (x[i] - mu) * inv + bbv[i], 0.0f);
        sq += y[i] * y[i];
    }
    float4 o0 = { y[0], y[1], y[2], y[3] }, o1 = { y[4], y[5], y[6], y[7] };
    *(float4*)(hp + c0) = o0;
    *(float4*)(hp + c1) = o1;
    sq = wred_sum(sq);
    float rn = 1.0f / (sqrtf(sq) + 1e-8f);
    if (fnb) {
        ushort4 u0, u1;
        u0.x = bf16r(y[0] * rn); u0.y = bf16r(y[1] * rn);
        u0.z = bf16r(y[2] * rn); u0.w = bf16r(y[3] * rn);
        u1.x = bf16r(y[4] * rn); u1.y = bf16r(y[5] * rn);
        u1.z = bf16r(y[6] * rn); u1.w = bf16r(y[7] * rn);
        *(ushort4*)(fnb + row * D_ + c0) = u0;
        *(ushort4*)(fnb + row * D_ + c1) = u1;
    }
    const float* tp = temb + (long)b * D_;
    float4 t0 = *(const float4*)(tp + c0), t1 = *(const float4*)(tp + c1);
    float tt[8] = { t0.x, t0.y, t0.z, t0.w, t1.x, t1.y, t1.z, t1.w };
    float rl = 0.f;
    #pragma unroll
    for (int i = 0; i < 8; i++) rl = fmaf(y[i], tt[i], rl);
    rl = wred_sum(rl);
    if (lane == 0) { rnorm[row] = rn; rel[row] = rl; }
}

// ------------------------------------------------- sliding-window cosine pruning via MFMA band
// One wave per 32 tokens: G0 = Fn[T:T+32) . Fn[T-32:T)^T, G1 = Fn[T:T+32) . Fn[T:T+32)^T.
// Pair (i, j) valid iff j in same batch, vld[j], and 1 <= (T+i)-j <= 32.
__global__ __launch_bounds__(256) void k_simg(const unsigned short* __restrict__ fnb,
                                              const unsigned char* __restrict__ vld,
                                              int* __restrict__ keep) {
    int wid = threadIdx.x >> 6, lane = threadIdx.x & 63;
    int T = (blockIdx.x * 4 + wid) * 32;
    int r32 = lane & 31, kg = lane >> 5;
    int prevok = (T & (N_ - 1)) != 0;
    const unsigned short* arow  = fnb + (long)(T + r32) * D_ + kg * 8;
    const unsigned short* b0row = fnb + (long)((prevok ? T - 32 : T) + r32) * D_ + kg * 8;

    f32x16 g0, g1;
    #pragma unroll
    for (int r = 0; r < 16; r++) { g0[r] = 0.f; g1[r] = 0.f; }
    #pragma unroll 4
    for (int kt = 0; kt < D_; kt += 16) {
        bf16x8 a  = *(const bf16x8*)(arow + kt);
        bf16x8 b0 = *(const bf16x8*)(b0row + kt);
        g0 = __builtin_amdgcn_mfma_f32_32x32x16_bf16(a, b0, g0, 0, 0, 0);
        g1 = __builtin_amdgcn_mfma_f32_32x32x16_bf16(a, a,  g1, 0, 0, 0);
    }
    int okc0 = prevok ? (int)vld[T - 32 + r32] : 0;
    int okc1 = (int)vld[T + r32];
    float ms[16];
    #pragma unroll
    for (int r = 0; r < 16; r++) {
        int i = (r & 3) + 8 * (r >> 2) + 4 * kg;     // output row within tile
        float v = -INFINITY;
        if (okc0 && r32 >= i) v = g0[r];             // w = i+32-col in [1,32]
        if (okc1 && r32 < i)  v = fmaxf(v, g1[r]);   // w = i-col in [1,31]
        #pragma unroll
        for (int d = 1; d < 32; d <<= 1) v = fmaxf(v, __shfl_xor(v, d, 64));
        ms[r] = v;
    }
    if (r32 == 0) {
        #pragma unroll
        for (int r = 0; r < 16; r++) {
            int i = (r & 3) + 8 * (r >> 2) + 4 * kg;
            int t = T + i;
            keep[t] = (vld[t] && ms[r] < 0.7f) ? 1 : 0;
        }
    }
}

// ------------------------------------------------- fallback sliding-window (no fnb space)
#define CHUNK 28
#define KROWS 60
__global__ __launch_bounds__(256) void k_sim(const float* img, const float* rnorm,
                                             const unsigned char* vld, int* keep) {
    __shared__ __hip_bfloat16 fnbs[KROWS][D_];
    long c0 = (long)blockIdx.x * CHUNK;
    int tid = threadIdx.x;
    for (int idx = tid; idx < KROWS * (D_ / 8); idx += 256) {
        int rr = idx / (D_ / 8);
        int cc = (idx % (D_ / 8)) * 8;
        long grow = c0 - WIN_ + rr;
        if (grow < 0) grow = 0;
        if (grow >= NTOK_) grow = NTOK_ - 1;
        float rn = rnorm[grow];
        const float* p = img + grow * (long)D_ + cc;
        float4 u = *(const float4*)p, w = *(const float4*)(p + 4);
        fnbs[rr][cc + 0] = __float2bfloat16(u.x * rn);
        fnbs[rr][cc + 1] = __float2bfloat16(u.y * rn);
        fnbs[rr][cc + 2] = __float2bfloat16(u.z * rn);
        fnbs[rr][cc + 3] = __float2bfloat16(u.w * rn);
        fnbs[rr][cc + 4] = __float2bfloat16(w.x * rn);
        fnbs[rr][cc + 5] = __float2bfloat16(w.y * rn);
        fnbs[rr][cc + 6] = __float2bfloat16(w.z * rn);
        fnbs[rr][cc + 7] = __float2bfloat16(w.w * rn);
    }
    __syncthreads();
    int wid = tid >> 6, lane = tid & 63;
    for (int ti = 0; ti < 7; ti++) {
        int tloc = wid * 7 + ti;
        long t = c0 + tloc;
        if (t >= NTOK_) continue;
        int lr = WIN_ + tloc;
        int tl = (int)(t & (N_ - 1));
        float a[8];
        bf8_to_f32(*(const uint4*)&fnbs[lr][lane * 8], a);
        int wmax = tl < WIN_ ? tl : WIN_;
        float msim = -INFINITY;
        for (int w = 1; w <= wmax; w++) {
            if (!vld[t - w]) continue;
            float bvv[8];
            bf8_to_f32(*(const uint4*)&fnbs[lr - w][lane * 8], bvv);
            float p = 0.f;
            #pragma unroll
            for (int i = 0; i < 8; i++) p = fmaf(a[i], bvv[i], p);
            p = wred_sum(p);
            msim = fmaxf(msim, p);
        }
        int kp = (vld[t] && (msim < 0.7f)) ? 1 : 0;
        if (lane == 0) keep[t] = kp;
    }
}

// ------------------------------------------------- per-batch exact top-k (radix select)
static __device__ void scan1024(int* tot, int tid) {
    if (tid < 64) {
        int vals[16], s = 0;
        #pragma unroll
        for (int i = 0; i < 16; i++) vals[i] = tot[tid * 16 + i];
        #pragma unroll
        for (int i = 0; i < 16; i++) { int t = vals[i]; vals[i] = s; s += t; }
        int inc = s;
        #pragma unroll
        for (int d = 1; d < 64; d <<= 1) {
            int v = __shfl_up(inc, d, 64);
            if ((tid & 63) >= d) inc += v;
        }
        int excl = inc - s;
        #pragma unroll
        for (int i = 0; i < 16; i++) tot[tid * 16 + i] = vals[i] + excl;
    }
}

__global__ __launch_bounds__(1024) void k_topk(const float* rel, const int* keep, int* idxo) {
    int b = blockIdx.x, tid = threadIdx.x;
    const float* relb = rel + (long)b * N_;
    const int* keepb  = keep + (long)b * N_;
    __shared__ unsigned int hist[256];
    __shared__ int toti[1024];
    __shared__ unsigned int s_prefix;
    __shared__ int s_rem, s_k;

    unsigned int key[16];
    int base = tid * 16, nk_local = 0;
    #pragma unroll
    for (int j = 0; j < 16; j++) {
        int i = base + j;
        float r = relb[i];
        int kp = keepb[i];
        unsigned int bits = __float_as_uint(r);
        unsigned int kk = (bits & 0x80000000u) ? ~bits : (bits | 0x80000000u);
        key[j] = kp ? kk : 0u;
        nk_local += kp;
    }
    toti[tid] = nk_local; __syncthreads();
    for (int o = 512; o > 0; o >>= 1) { if (tid < o) toti[tid] += toti[tid + o]; __syncthreads(); }
    if (tid == 0) {
        int n_kept = toti[0];
        int k = (int)(0.8f * (float)n_kept);
        if (k < 1) k = 1; if (k > LMAX_) k = LMAX_;
        s_k = k; s_rem = k; s_prefix = 0u;
    }
    __syncthreads();

    for (int pass = 0; pass < 4; pass++) {
        int shift = 24 - pass * 8;
        unsigned int himask = (pass == 0) ? 0u : (0xFFFFFFFFu << (shift + 8));
        if (tid < 256) hist[tid] = 0u;
        __syncthreads();
        unsigned int pfx = s_prefix;
        #pragma unroll
        for (int j = 0; j < 16; j++) {
            unsigned int kk = key[j];
            if ((kk & himask) == (pfx & himask))
                atomicAdd(&hist[(kk >> shift) & 255], 1u);
        }
        __syncthreads();
        if (tid == 0) {
            int rem = s_rem;
            unsigned int cum = 0;
            for (int d = 255; d >= 0; d--) {
                unsigned int h = hist[d];
                if (cum + h >= (unsigned int)rem) {
                    s_rem = rem - (int)cum;
                    s_prefix = pfx | ((unsigned int)d << shift);
                    break;
                }
                cum += h;
            }
        }
        __syncthreads();
    }
    unsigned int T = s_prefix;
    int tie_need = s_rem, k = s_k;

    int eq[16], gt[16], eqpre[16];
    int locEq = 0;
    #pragma unroll
    for (int j = 0; j < 16; j++) {
        eq[j] = (key[j] == T); gt[j] = (key[j] > T);
        eqpre[j] = locEq; locEq += eq[j];
    }
    toti[tid] = locEq; __syncthreads();
    scan1024(toti, tid); __syncthreads();
    int eqoff = toti[tid];

    int sel[16], spre[16];
    int locS = 0;
    #pragma unroll
    for (int j = 0; j < 16; j++) {
        int rank = eqoff + eqpre[j];
        sel[j] = gt[j] || (eq[j] && rank < tie_need);
        spre[j] = locS; locS += sel[j];
    }
    __syncthreads();
    toti[tid] = locS; __syncthreads();
    scan1024(toti, tid); __syncthreads();
    int soff = toti[tid];
    #pragma unroll
    for (int j = 0; j < 16; j++)
        if (sel[j]) idxo[b * LMAX_ + soff + spre[j]] = base + j;
    for (int p = k + tid; p < LMAX_; p += 1024) idxo[b * LMAX_ + p] = N_;
}

// ------------------------------------------------- feat2 gather + pair pooling
__global__ void k_feat3(const float* img, const int* idxo, float* f3) {
    int bm = blockIdx.x;
    int b = bm >> 9, m = bm & 511;
    int i0 = idxo[b * LMAX_ + 2 * m], i1 = idxo[b * LMAX_ + 2 * m + 1];
    int c0 = i0 < N_, c1 = i1 < N_;
    float dn = 1.0f / fmaxf((float)(c0 + c1), 1.0f);
    const float* p0 = img + ((long)b * N_ + (c0 ? i0 : 0)) * D_;
    const float* p1 = img + ((long)b * N_ + (c1 ? i1 : 0)) * D_;
    int d = threadIdx.x * 4;
    float4 v0 = c0 ? *(const float4*)(p0 + d) : make_float4(0.f, 0.f, 0.f, 0.f);
    float4 v1 = c1 ? *(const float4*)(p1 + d) : make_float4(0.f, 0.f, 0.f, 0.f);
    float4 o;
    o.x = (v0.x + v1.x) * dn; o.y = (v0.y + v1.y) * dn;
    o.z = (v0.z + v1.z) * dn; o.w = (v0.w + v1.w) * dn;
    *(float4*)(f3 + (long)bm * D_ + d) = o;
}

// ------------------------------------------------- cross-modal attention
__global__ __launch_bounds__(512) void k_attn(const float* qv, const float* kk,
                                              const float* vv, float* ctx) {
    int bh = blockIdx.x;
    int b = bh >> 3, h = bh & 7;
    __shared__ float qs[DH_];
    __shared__ float sc[M2_];
    __shared__ float red[M2_];
    int m = threadIdx.x;
    if (m < DH_) qs[m] = qv[b * D_ + h * DH_ + m];
    __syncthreads();
    const float* kp = kk + (long)b * M2_ * D_ + h * DH_;
    float acc = 0.f;
    #pragma unroll
    for (int d = 0; d < DH_; d += 4) {
        float4 kv = *(const float4*)(kp + (long)m * D_ + d);
        acc += qs[d] * kv.x + qs[d + 1] * kv.y + qs[d + 2] * kv.z + qs[d + 3] * kv.w;
    }
    acc *= 0.125f;
    red[m] = acc; __syncthreads();
    for (int o = 256; o > 0; o >>= 1) { if (m < o) red[m] = fmaxf(red[m], red[m + o]); __syncthreads(); }
    float mx = red[0]; __syncthreads();
    float e = expf(acc - mx);
    sc[m] = e; red[m] = e; __syncthreads();
    for (int o = 256; o > 0; o >>= 1) { if (m < o) red[m] += red[m + o]; __syncthreads(); }
    float inv = 1.0f / red[0];
    if (m < DH_) {
        float a2 = 0.f;
        const float* vp = vv + (long)b * M2_ * D_ + h * DH_ + m;
        for (int mm = 0; mm < M2_; mm++) a2 = fmaf(sc[mm], vp[(long)mm * D_], a2);
        ctx[b * D_ + h * DH_ + m] = a2 * inv;
    }
}

// ------------------------------------------------- output head (Wo then W_cls), f32 out
__global__ __launch_bounds__(512) void k_head(const float* ctx, const float* Wo, const float* bo,
                                              const float* Wc, const float* bc,
                                              float* out) {
    int b = blockIdx.x, d = threadIdx.x;
    __shared__ float cl[D_], ol[D_];
    cl[d] = ctx[b * D_ + d]; __syncthreads();
    float acc = bo[d];
    for (int e = 0; e < D_; e++) acc = fmaf(cl[e], Wo[(long)e * D_ + d], acc);
    ol[d] = acc; __syncthreads();
    if (d < 4) {
        float a2 = bc[d];
        for (int e = 0; e < D_; e++) a2 = fmaf(ol[e], Wc[e * 4 + d], a2);
        out[b * 4 + d] = a2;
    }
}

// ---------------------------------------------------------------- launcher
extern "C" void kernel_launch(void* const* d_in, const int* in_sizes, int n_in,
                              void* d_out, int out_size, void* d_ws, size_t ws_size,
                              hipStream_t stream) {
    const float* bags = (const float*)d_in[0];
    const void*  kpm  = d_in[1];
    const int*   ids  = (const int*)d_in[2];
    const int*   am   = (const int*)d_in[3];
    const float* emb  = (const float*)d_in[4];
    const float* Wtp  = (const float*)d_in[5];
    const float* btp  = (const float*)d_in[6];
    const float* Wen  = (const float*)d_in[7];
    const float* ben  = (const float*)d_in[8];
    const float* lng  = (const float*)d_in[9];
    const float* lnb  = (const float*)d_in[10];
    const float* Wq   = (const float*)d_in[11];
    const float* bq   = (const float*)d_in[12];
    const float* Wk   = (const float*)d_in[13];
    const float* bk   = (const float*)d_in[14];
    const float* Wv   = (const float*)d_in[15];
    const float* bv   = (const float*)d_in[16];
    const float* Wo   = (const float*)d_in[17];
    const float* bo   = (const float*)d_in[18];
    const float* Wc   = (const float*)d_in[19];
    const float* bc   = (const float*)d_in[20];

    char* ws = (char*)d_ws;
    size_t o = 0;
    auto alloc = [&](size_t bytes) -> void* {
        void* p = ws + o; o += (bytes + 255) & ~(size_t)255; return p;
    };
    float* img  = (float*)alloc((size_t)NTOK_ * D_ * 4);
    float* rno  = (float*)alloc((size_t)NTOK_ * 4);
    float* rel  = (float*)alloc((size_t)NTOK_ * 4);
    int*   keep = (int*)alloc((size_t)NTOK_ * 4);
    unsigned char* vld = (unsigned char*)alloc(NTOK_);
    float* tf   = (float*)alloc(B_ * 768 * 4);
    float* te   = (float*)alloc(B_ * D_ * 4);
    float* qv   = (float*)alloc(B_ * D_ * 4);
    int*   idxo = (int*)alloc(B_ * LMAX_ * 4);
    float* f3   = (float*)alloc((size_t)B_ * M2_ * D_ * 4);
    float* kkb  = (float*)alloc((size_t)B_ * M2_ * D_ * 4);
    float* vvb  = (float*)alloc((size_t)B_ * M2_ * D_ * 4);
    float* ctx  = (float*)alloc(B_ * D_ * 4);
    int*   flag = (int*)alloc(256);
    unsigned short* bth = (unsigned short*)alloc((size_t)D_ * F_ * 2);
    unsigned short* btl = (unsigned short*)alloc((size_t)D_ * F_ * 2);
    unsigned short* fnb = nullptr;
    {
        size_t need = (size_t)NTOK_ * D_ * 2 + 1024;
        if (ws_size > o && (ws_size - o) >= need)
            fnb = (unsigned short*)alloc((size_t)NTOK_ * D_ * 2);
    }

    hipMemsetAsync(flag, 0, 4, stream);
    k_detect<<<64, 256, 0, stream>>>((const unsigned char*)kpm, NTOK_, flag);
    k_valid<<<(NTOK_ + 255) / 256, 256, 0, stream>>>(kpm, flag, vld);
    k_text_feat<<<B_, 256, 0, stream>>>(emb, ids, am, tf);
    k_rowmm<<<B_, 512, 0, stream>>>(tf, Wtp, btp, te, 768, 512);
    k_rowmm<<<B_, 512, 0, stream>>>(te, Wq, bq, qv, 512, 512);

    dim3 gsplit(F_ / 32, D_ / 32);
    k_bsplit<<<gsplit, 256, 0, stream>>>(Wen, bth, btl);
    dim3 g3(NTOK_ / 64, 2);
    k_gemm_mfma<<<g3, 256, 0, stream>>>(bags, bth, btl, ben, img);

    k_ln<<<NTOK_ / 4, 256, 0, stream>>>(img, lng, lnb, te, rno, rel, fnb);
    if (fnb) k_simg<<<NTOK_ / 128, 256, 0, stream>>>(fnb, vld, keep);
    else     k_sim<<<(NTOK_ + CHUNK - 1) / CHUNK, 256, 0, stream>>>(img, rno, vld, keep);
    k_topk<<<B_, 1024, 0, stream>>>(rel, keep, idxo);
    k_feat3<<<B_ * M2_, 128, 0, stream>>>(img, idxo, f3);

    dim3 g8(B_ * M2_ / BM, D_ / BN);
    k_gemm<<<g8, 256, 0, stream>>>(f3, D_, Wk, D_, bk, kkb, D_, D_);
    k_gemm<<<g8, 256, 0, stream>>>(f3, D_, Wv, D_, bv, vvb, D_, D_);

    k_attn<<<B_ * H_, 512, 0, stream>>>(qv, kkb, vvb, ctx);
    k_head<<<B_, 512, 0, stream>>>(ctx, Wo, bo, Wc, bc, (float*)d_out);
}

// Round 6
// 1243.999 us; speedup vs baseline: 2.7453x; 1.0964x over previous
//
#include <hip/hip_runtime.h>
#include <hip/hip_bf16.h>
#include <math.h>
#include <stdint.h>

#define B_    8
#define N_    16384
#define F_    1024
#define D_    512
#define S_    64
#define H_    8
#define DH_   64
#define LMAX_ 1024
#define M2_   512
#define WIN_  32
#define NTOK_ (B_ * N_)   // 131072

typedef __attribute__((ext_vector_type(8)))  short bf16x8;
typedef __attribute__((ext_vector_type(16))) float f32x16;

// quad-swizzle within each 64B (4x16B) group, keyed by row low bits
#define S_OF(r) (((r) >> 1) & 3)

// ---------------------------------------------------------------- utilities
static __device__ __forceinline__ float wred_sum(float v) {
    #pragma unroll
    for (int d = 1; d < 64; d <<= 1) v += __shfl_xor(v, d, 64);
    return v;
}

static __device__ __forceinline__ void bf8_to_f32(uint4 q, float* a) {
    a[0] = __uint_as_float(q.x << 16); a[1] = __uint_as_float(q.x & 0xffff0000u);
    a[2] = __uint_as_float(q.y << 16); a[3] = __uint_as_float(q.y & 0xffff0000u);
    a[4] = __uint_as_float(q.z << 16); a[5] = __uint_as_float(q.z & 0xffff0000u);
    a[6] = __uint_as_float(q.w << 16); a[7] = __uint_as_float(q.w & 0xffff0000u);
}

static __device__ __forceinline__ unsigned short bf16r(float x) {   // RNE f32->bf16
    unsigned int b = __float_as_uint(x);
    return (unsigned short)((b + 0x7FFFu + ((b >> 16) & 1u)) >> 16);
}

static __device__ __forceinline__ void split_bf(float x, unsigned short& h, unsigned short& l) {
    unsigned int b = __float_as_uint(x);
    unsigned int hb = (b + 0x7FFFu + ((b >> 16) & 1u)) >> 16;
    h = (unsigned short)hb;
    float r = x - __uint_as_float(hb << 16);
    l = bf16r(r);
}

static __device__ __forceinline__ void gll16(const void* g, void* l) {
    __builtin_amdgcn_global_load_lds(
        (const __attribute__((address_space(1))) unsigned int*)g,
        (__attribute__((address_space(3))) unsigned int*)l, 16, 0, 0);
}

// ------------------------------------------------- mask layout detection
__global__ void k_detect(const unsigned char* mb, int nbytes, int* flag) {
    int found = 0;
    for (int i = blockIdx.x * blockDim.x + threadIdx.x; i < nbytes; i += gridDim.x * blockDim.x)
        if ((i & 3) && mb[i]) found = 1;
    if (found) atomicOr(flag, 1);
}

__global__ void k_valid(const void* maskp, const int* flag, unsigned char* v) {
    int i = blockIdx.x * 256 + threadIdx.x;
    if (i >= NTOK_) return;
    int pad;
    if (*flag) pad = (((const unsigned char*)maskp)[i] != 0);
    else       pad = (((const int*)maskp)[i] != 0);
    v[i] = pad ? 0 : 1;
}

// ------------------------------------------------- text feature (masked mean)
__global__ void k_text_feat(const float* emb, const int* ids, const int* am, float* tf) {
    int b = blockIdx.x;
    __shared__ int   sid[S_];
    __shared__ float sam[S_];
    int t = threadIdx.x;
    if (t < S_) { sid[t] = ids[b * S_ + t]; sam[t] = (float)am[b * S_ + t]; }
    __syncthreads();
    float asum = 0.f;
    for (int s = 0; s < S_; s++) asum += sam[s];
    float denom = fmaxf(asum, 1.0f);
    for (int d = t; d < 768; d += blockDim.x) {
        float acc = 0.f;
        for (int s = 0; s < S_; s++) acc += emb[(long)sid[s] * 768 + d] * sam[s];
        tf[b * 768 + d] = acc / denom;
    }
}

__global__ void k_rowmm(const float* in, const float* W, const float* bias,
                        float* out, int E, int Nn) {
    int b = blockIdx.x, d = threadIdx.x;
    __shared__ float sin[768];
    for (int e = d; e < E; e += blockDim.x) sin[e] = in[b * E + e];
    __syncthreads();
    float acc = bias[d];
    for (int e = 0; e < E; e++) acc = fmaf(sin[e], W[(long)e * Nn + d], acc);
    out[b * Nn + d] = acc;
}

// ------------------------------------------------- A split prepass: f32 -> bf16 hi/lo, swizzled
__global__ __launch_bounds__(256) void k_asplit(const float* __restrict__ A,
                                                unsigned short* __restrict__ ah,
                                                unsigned short* __restrict__ al) {
    const long nquads = (long)NTOK_ * 128;
    long idx0 = (long)blockIdx.x * 256 + threadIdx.x;
    long stride = (long)gridDim.x * 256;
    for (long idx = idx0; idx < nquads; idx += stride) {
        long row = idx >> 7;
        int q = (int)(idx & 127);
        int s = S_OF((int)row & 7);
        int qo = (q & ~3) | ((q & 3) ^ s);
        const float* p = A + (row << 10) + q * 8;
        float4 v0 = *(const float4*)p;
        float4 v1 = *(const float4*)(p + 4);
        float xs[8] = { v0.x, v0.y, v0.z, v0.w, v1.x, v1.y, v1.z, v1.w };
        unsigned short h[8], l[8];
        #pragma unroll
        for (int i = 0; i < 8; i++) split_bf(xs[i], h[i], l[i]);
        uint4 ph, pl;
        ph.x = h[0] | ((unsigned)h[1] << 16); ph.y = h[2] | ((unsigned)h[3] << 16);
        ph.z = h[4] | ((unsigned)h[5] << 16); ph.w = h[6] | ((unsigned)h[7] << 16);
        pl.x = l[0] | ((unsigned)l[1] << 16); pl.y = l[2] | ((unsigned)l[3] << 16);
        pl.z = l[4] | ((unsigned)l[5] << 16); pl.w = l[6] | ((unsigned)l[7] << 16);
        *(uint4*)(ah + (row << 10) + qo * 8) = ph;
        *(uint4*)(al + (row << 10) + qo * 8) = pl;
    }
}

// ------------------------------------------------- W_enc transpose + split, swizzled layout
__global__ __launch_bounds__(256) void k_bsplit_sw(const float* __restrict__ W,
                                                   unsigned short* __restrict__ bh,
                                                   unsigned short* __restrict__ bl) {
    __shared__ float tile[32][33];
    int e0 = blockIdx.x * 32;   // k origin
    int d0 = blockIdx.y * 32;   // out-col origin
    int t = threadIdx.x;
    int r = t >> 3, c4 = (t & 7) * 4;
    float4 v = *(const float4*)(W + (long)(e0 + r) * D_ + d0 + c4);
    tile[r][c4] = v.x; tile[r][c4 + 1] = v.y; tile[r][c4 + 2] = v.z; tile[r][c4 + 3] = v.w;
    __syncthreads();
    if (t < 128) {
        int c = t & 31, kq = t >> 5;           // col-in-tile, quad-in-tile (0..3)
        int col = d0 + c;
        float xs[8];
        #pragma unroll
        for (int i = 0; i < 8; i++) xs[i] = tile[kq * 8 + i][c];
        unsigned short h[8], l[8];
        #pragma unroll
        for (int i = 0; i < 8; i++) split_bf(xs[i], h[i], l[i]);
        uint4 ph, pl;
        ph.x = h[0] | ((unsigned)h[1] << 16); ph.y = h[2] | ((unsigned)h[3] << 16);
        ph.z = h[4] | ((unsigned)h[5] << 16); ph.w = h[6] | ((unsigned)h[7] << 16);
        pl.x = l[0] | ((unsigned)l[1] << 16); pl.y = l[2] | ((unsigned)l[3] << 16);
        pl.z = l[4] | ((unsigned)l[5] << 16); pl.w = l[6] | ((unsigned)l[7] << 16);
        int Q = (e0 >> 3) + kq;
        int Qo = (Q & ~3) | ((Q & 3) ^ S_OF(col & 7));
        *(uint4*)(bh + (long)col * 1024 + Qo * 8) = ph;
        *(uint4*)(bl + (long)col * 1024 + Qo * 8) = pl;
    }
}

// ------------------------------------------------- m97-style gll GEMM, 3-term bf16 split
// Tile 128x128, BK=32, 4 waves. Wave w stages plane w via global_load_lds;
// wave w COMPUTES quadrant (wr,wc) = (w>>1, w&1) of the 128x128 output tile.
__global__ __launch_bounds__(256) void k_gemm2(const unsigned short* __restrict__ Ah,
                                               const unsigned short* __restrict__ Al,
                                               const unsigned short* __restrict__ Bh2,
                                               const unsigned short* __restrict__ Bl2,
                                               const float* __restrict__ bias,
                                               float* __restrict__ C) {
    __shared__ __align__(16) unsigned short lds[4][128][32];   // 32 KiB
    int bid = blockIdx.x;
    int wg = (bid & 7) * 512 + (bid >> 3);    // bijective: nwg=4096 % 8 == 0
    int bn = wg & 3, bm = wg >> 2;
    int tid = threadIdx.x;
    int w = tid >> 6, lane = tid & 63;
    int r32 = lane & 31, kg = lane >> 5;
    int lrow = lane >> 2, lq = lane & 3;
    int wr = w >> 1, wc = w & 1;              // wave's output quadrant

    const unsigned short* plane = (w == 0) ? Ah : (w == 1) ? Al : (w == 2) ? Bh2 : Bl2;
    long prow0 = (w < 2) ? ((long)bm * 128) : ((long)bn * 128);
    const unsigned short* gbase = plane + (prow0 + lrow) * 1024 + lq * 8;

    f32x16 acc[2][2];
    #pragma unroll
    for (int i = 0; i < 2; i++)
        #pragma unroll
        for (int j = 0; j < 2; j++)
            #pragma unroll
            for (int r = 0; r < 16; r++) acc[i][j][r] = 0.f;

    for (int kt = 0; kt < 1024; kt += 32) {
        #pragma unroll
        for (int j = 0; j < 8; j++)
            gll16(gbase + (long)j * 16 * 1024 + kt, &lds[w][j * 16][0]);
        __syncthreads();
        #pragma unroll
        for (int k2 = 0; k2 < 2; k2++) {
            int qb = k2 * 2 + kg;
            int q = (qb ^ S_OF(r32)) * 8;     // row&7 == r32&7 for all fragment rows
            bf16x8 a_h[2], a_l[2], b_h[2], b_l[2];
            #pragma unroll
            for (int rf = 0; rf < 2; rf++) {
                int ar = wr * 64 + rf * 32 + r32;
                a_h[rf] = *(const bf16x8*)&lds[0][ar][q];
                a_l[rf] = *(const bf16x8*)&lds[1][ar][q];
            }
            #pragma unroll
            for (int cf = 0; cf < 2; cf++) {
                int bc = wc * 64 + cf * 32 + r32;
                b_h[cf] = *(const bf16x8*)&lds[2][bc][q];
                b_l[cf] = *(const bf16x8*)&lds[3][bc][q];
            }
            #pragma unroll
            for (int rf = 0; rf < 2; rf++)
                #pragma unroll
                for (int cf = 0; cf < 2; cf++) {
                    acc[rf][cf] = __builtin_amdgcn_mfma_f32_32x32x16_bf16(a_h[rf], b_h[cf], acc[rf][cf], 0, 0, 0);
                    acc[rf][cf] = __builtin_amdgcn_mfma_f32_32x32x16_bf16(a_h[rf], b_l[cf], acc[rf][cf], 0, 0, 0);
                    acc[rf][cf] = __builtin_amdgcn_mfma_f32_32x32x16_bf16(a_l[rf], b_h[cf], acc[rf][cf], 0, 0, 0);
                }
        }
        __syncthreads();
    }
    #pragma unroll
    for (int rf = 0; rf < 2; rf++)
        #pragma unroll
        for (int cf = 0; cf < 2; cf++) {
            int col = bn * 128 + wc * 64 + cf * 32 + r32;
            float bv = bias[col];
            #pragma unroll
            for (int r = 0; r < 16; r++) {
                int row = bm * 128 + wr * 64 + rf * 32 + (r & 3) + 8 * (r >> 2) + 4 * kg;
                C[(long)row * D_ + col] = acc[rf][cf][r] + bv;
            }
        }
}

// ------------------------------------------------- fallback fused split GEMM (round-4)
#define GPAD 40
__global__ __launch_bounds__(256, 3) void k_gemm_mfma(const float* __restrict__ A,
                                                      const unsigned short* __restrict__ Bth,
                                                      const unsigned short* __restrict__ Btl,
                                                      const float* __restrict__ bias,
                                                      float* __restrict__ C) {
    __shared__ __align__(16) unsigned short As[2][64][GPAD];
    __shared__ __align__(16) unsigned short Bs[2][256][GPAD];
    int bm = blockIdx.x, bn = blockIdx.y;
    int tid = threadIdx.x;
    int w = tid >> 6, lane = tid & 63;
    int r32 = lane & 31, kg = lane >> 5;
    f32x16 acc[2][2];
    #pragma unroll
    for (int i = 0; i < 2; i++)
        #pragma unroll
        for (int j = 0; j < 2; j++)
            #pragma unroll
            for (int r = 0; r < 16; r++) acc[i][j][r] = 0.f;
    int arow = tid >> 2, aq = tid & 3;
    const float* abase = A + (long)(bm * 64 + arow) * 1024 + aq * 8;
    const unsigned short* bhbase = Bth + (long)(bn * 256 + tid) * 1024;
    const unsigned short* blbase = Btl + (long)(bn * 256 + tid) * 1024;
    float4 pa0 = *(const float4*)abase;
    float4 pa1 = *(const float4*)(abase + 4);
    for (int kt = 0; kt < 1024; kt += 32) {
        {
            float xs[8] = { pa0.x, pa0.y, pa0.z, pa0.w, pa1.x, pa1.y, pa1.z, pa1.w };
            unsigned short h[8], l[8];
            #pragma unroll
            for (int i = 0; i < 8; i++) split_bf(xs[i], h[i], l[i]);
            uint4 ph, pl;
            ph.x = h[0] | ((unsigned)h[1] << 16); ph.y = h[2] | ((unsigned)h[3] << 16);
            ph.z = h[4] | ((unsigned)h[5] << 16); ph.w = h[6] | ((unsigned)h[7] << 16);
            pl.x = l[0] | ((unsigned)l[1] << 16); pl.y = l[2] | ((unsigned)l[3] << 16);
            pl.z = l[4] | ((unsigned)l[5] << 16); pl.w = l[6] | ((unsigned)l[7] << 16);
            *(uint4*)&As[0][arow][aq * 8] = ph;
            *(uint4*)&As[1][arow][aq * 8] = pl;
        }
        {
            const uint4* ph = (const uint4*)(bhbase + kt);
            const uint4* pl = (const uint4*)(blbase + kt);
            #pragma unroll
            for (int q = 0; q < 4; q++) {
                *(uint4*)&Bs[0][tid][q * 8] = ph[q];
                *(uint4*)&Bs[1][tid][q * 8] = pl[q];
            }
        }
        __syncthreads();
        if (kt + 32 < 1024) {
            const float* ap = abase + kt + 32;
            pa0 = *(const float4*)ap;
            pa1 = *(const float4*)(ap + 4);
        }
        #pragma unroll
        for (int k2 = 0; k2 < 2; k2++) {
            int ko = k2 * 16 + kg * 8;
            bf16x8 ah[2], al[2], bh[2], blv[2];
            #pragma unroll
            for (int rf = 0; rf < 2; rf++) {
                ah[rf] = *(const bf16x8*)&As[0][rf * 32 + r32][ko];
                al[rf] = *(const bf16x8*)&As[1][rf * 32 + r32][ko];
            }
            #pragma unroll
            for (int cf = 0; cf < 2; cf++) {
                bh[cf]  = *(const bf16x8*)&Bs[0][w * 64 + cf * 32 + r32][ko];
                blv[cf] = *(const bf16x8*)&Bs[1][w * 64 + cf * 32 + r32][ko];
            }
            #pragma unroll
            for (int rf = 0; rf < 2; rf++)
                #pragma unroll
                for (int cf = 0; cf < 2; cf++) {
                    acc[rf][cf] = __builtin_amdgcn_mfma_f32_32x32x16_bf16(ah[rf], bh[cf],  acc[rf][cf], 0, 0, 0);
                    acc[rf][cf] = __builtin_amdgcn_mfma_f32_32x32x16_bf16(ah[rf], blv[cf], acc[rf][cf], 0, 0, 0);
                    acc[rf][cf] = __builtin_amdgcn_mfma_f32_32x32x16_bf16(al[rf], bh[cf],  acc[rf][cf], 0, 0, 0);
                }
        }
        __syncthreads();
    }
    #pragma unroll
    for (int rf = 0; rf < 2; rf++)
        #pragma unroll
        for (int cf = 0; cf < 2; cf++) {
            int col = bn * 256 + w * 64 + cf * 32 + r32;
            float bv = bias[col];
            #pragma unroll
            for (int r = 0; r < 16; r++) {
                int row = bm * 64 + rf * 32 + (r & 3) + 8 * (r >> 2) + 4 * kg;
                C[(long)row * D_ + col] = acc[rf][cf][r] + bv;
            }
        }
}

// old unswizzled bsplit (fallback path)
__global__ __launch_bounds__(256) void k_bsplit(const float* __restrict__ W,
                                                unsigned short* __restrict__ bh,
                                                unsigned short* __restrict__ bl) {
    __shared__ float tile[32][33];
    int e0 = blockIdx.x * 32;
    int d0 = blockIdx.y * 32;
    int t = threadIdx.x;
    int r = t >> 3;
    int c = (t & 7) * 4;
    float4 v = *(const float4*)(W + (long)(e0 + r) * D_ + d0 + c);
    tile[r][c] = v.x; tile[r][c + 1] = v.y; tile[r][c + 2] = v.z; tile[r][c + 3] = v.w;
    __syncthreads();
    ushort4 h4, l4;
    unsigned short hh, ll;
    float x0 = tile[c + 0][r], x1 = tile[c + 1][r], x2 = tile[c + 2][r], x3 = tile[c + 3][r];
    split_bf(x0, hh, ll); h4.x = hh; l4.x = ll;
    split_bf(x1, hh, ll); h4.y = hh; l4.y = ll;
    split_bf(x2, hh, ll); h4.z = hh; l4.z = ll;
    split_bf(x3, hh, ll); h4.w = hh; l4.w = ll;
    *(ushort4*)(bh + (long)(d0 + r) * 1024 + e0 + c) = h4;
    *(ushort4*)(bl + (long)(d0 + r) * 1024 + e0 + c) = l4;
}

// ------------------------------------------------- LayerNorm+ReLU (in place) + rnorm + rel (+fnb)
__global__ __launch_bounds__(256) void k_ln(float* h, const float* g, const float* bb,
                                            const float* temb, float* rnorm, float* rel,
                                            unsigned short* fnb) {
    int wid = threadIdx.x >> 6, lane = threadIdx.x & 63;
    long row = (long)blockIdx.x * 4 + wid;
    int b = (int)(row >> 14);
    float* hp = h + row * (long)D_;
    int c0 = lane * 4, c1 = 256 + lane * 4;
    float4 x0 = *(float4*)(hp + c0);
    float4 x1 = *(float4*)(hp + c1);
    float x[8] = { x0.x, x0.y, x0.z, x0.w, x1.x, x1.y, x1.z, x1.w };
    float s = 0.f;
    #pragma unroll
    for (int i = 0; i < 8; i++) s += x[i];
    s = wred_sum(s);
    float mu = s * (1.0f / 512.0f);
    float var = 0.f;
    #pragma unroll
    for (int i = 0; i < 8; i++) { float d = x[i] - mu; var += d * d; }
    var = wred_sum(var) * (1.0f / 512.0f);
    float inv = 1.0f / sqrtf(var + 1e-5f);
    float4 g0 = *(const float4*)(g + c0), g1 = *(const float4*)(g + c1);
    float4 b0 = *(const float4*)(bb + c0), b1 = *(const float4*)(bb + c1);
    float gg[8] = { g0.x, g0.y, g0.z, g0.w, g1.x, g1.y, g1.z, g1.w };
    float bbv[8] = { b0.x, b0.y, b0.z, b0.w, b1.x, b1.y, b1.z, b1.w };
    float y[8], sq = 0.f;
    #pragma unroll
    for (int i = 0; i < 8; i++) {
        y[i] = fmaxf(gg[i] * (x[i] - mu) * inv + bbv[i], 0.0f);
        sq += y[i] * y[i];
    }
    float4 o0 = { y[0], y[1], y[2], y[3] }, o1 = { y[4], y[5], y[6], y[7] };
    *(float4*)(hp + c0) = o0;
    *(float4*)(hp + c1) = o1;
    sq = wred_sum(sq);
    float rn = 1.0f / (sqrtf(sq) + 1e-8f);
    if (fnb) {
        ushort4 u0, u1;
        u0.x = bf16r(y[0] * rn); u0.y = bf16r(y[1] * rn);
        u0.z = bf16r(y[2] * rn); u0.w = bf16r(y[3] * rn);
        u1.x = bf16r(y[4] * rn); u1.y = bf16r(y[5] * rn);
        u1.z = bf16r(y[6] * rn); u1.w = bf16r(y[7] * rn);
        *(ushort4*)(fnb + row * D_ + c0) = u0;
        *(ushort4*)(fnb + row * D_ + c1) = u1;
    }
    const float* tp = temb + (long)b * D_;
    float4 t0 = *(const float4*)(tp + c0), t1 = *(const float4*)(tp + c1);
    float tt[8] = { t0.x, t0.y, t0.z, t0.w, t1.x, t1.y, t1.z, t1.w };
    float rl = 0.f;
    #pragma unroll
    for (int i = 0; i < 8; i++) rl = fmaf(y[i], tt[i], rl);
    rl = wred_sum(rl);
    if (lane == 0) { rnorm[row] = rn; rel[row] = rl; }
}

// ------------------------------------------------- sliding-window cosine pruning via MFMA band
__global__ __launch_bounds__(256) void k_simg(const unsigned short* __restrict__ fnb,
                                              const unsigned char* __restrict__ vld,
                                              int* __restrict__ keep) {
    int wid = threadIdx.x >> 6, lane = threadIdx.x & 63;
    int T = (blockIdx.x * 4 + wid) * 32;
    int r32 = lane & 31, kg = lane >> 5;
    int prevok = (T & (N_ - 1)) != 0;
    const unsigned short* arow  = fnb + (long)(T + r32) * D_ + kg * 8;
    const unsigned short* b0row = fnb + (long)((prevok ? T - 32 : T) + r32) * D_ + kg * 8;

    f32x16 g0, g1;
    #pragma unroll
    for (int r = 0; r < 16; r++) { g0[r] = 0.f; g1[r] = 0.f; }
    #pragma unroll 4
    for (int kt = 0; kt < D_; kt += 16) {
        bf16x8 a  = *(const bf16x8*)(arow + kt);
        bf16x8 b0 = *(const bf16x8*)(b0row + kt);
        g0 = __builtin_amdgcn_mfma_f32_32x32x16_bf16(a, b0, g0, 0, 0, 0);
        g1 = __builtin_amdgcn_mfma_f32_32x32x16_bf16(a, a,  g1, 0, 0, 0);
    }
    int okc0 = prevok ? (int)vld[T - 32 + r32] : 0;
    int okc1 = (int)vld[T + r32];
    float ms[16];
    #pragma unroll
    for (int r = 0; r < 16; r++) {
        int i = (r & 3) + 8 * (r >> 2) + 4 * kg;
        float v = -INFINITY;
        if (okc0 && r32 >= i) v = g0[r];
        if (okc1 && r32 < i)  v = fmaxf(v, g1[r]);
        #pragma unroll
        for (int d = 1; d < 32; d <<= 1) v = fmaxf(v, __shfl_xor(v, d, 64));
        ms[r] = v;
    }
    if (r32 == 0) {
        #pragma unroll
        for (int r = 0; r < 16; r++) {
            int i = (r & 3) + 8 * (r >> 2) + 4 * kg;
            int t = T + i;
            keep[t] = (vld[t] && ms[r] < 0.7f) ? 1 : 0;
        }
    }
}

// ------------------------------------------------- fallback sliding-window (no fnb space)
#define CHUNK 28
#define KROWS 60
__global__ __launch_bounds__(256) void k_sim(const float* img, const float* rnorm,
                                             const unsigned char* vld, int* keep) {
    __shared__ __hip_bfloat16 fnbs[KROWS][D_];
    long c0 = (long)blockIdx.x * CHUNK;
    int tid = threadIdx.x;
    for (int idx = tid; idx < KROWS * (D_ / 8); idx += 256) {
        int rr = idx / (D_ / 8);
        int cc = (idx % (D_ / 8)) * 8;
        long grow = c0 - WIN_ + rr;
        if (grow < 0) grow = 0;
        if (grow >= NTOK_) grow = NTOK_ - 1;
        float rn = rnorm[grow];
        const float* p = img + grow * (long)D_ + cc;
        float4 u = *(const float4*)p, w = *(const float4*)(p + 4);
        fnbs[rr][cc + 0] = __float2bfloat16(u.x * rn);
        fnbs[rr][cc + 1] = __float2bfloat16(u.y * rn);
        fnbs[rr][cc + 2] = __float2bfloat16(u.z * rn);
        fnbs[rr][cc + 3] = __float2bfloat16(u.w * rn);
        fnbs[rr][cc + 4] = __float2bfloat16(w.x * rn);
        fnbs[rr][cc + 5] = __float2bfloat16(w.y * rn);
        fnbs[rr][cc + 6] = __float2bfloat16(w.z * rn);
        fnbs[rr][cc + 7] = __float2bfloat16(w.w * rn);
    }
    __syncthreads();
    int wid = tid >> 6, lane = tid & 63;
    for (int ti = 0; ti < 7; ti++) {
        int tloc = wid * 7 + ti;
        long t = c0 + tloc;
        if (t >= NTOK_) continue;
        int lr = WIN_ + tloc;
        int tl = (int)(t & (N_ - 1));
        float a[8];
        bf8_to_f32(*(const uint4*)&fnbs[lr][lane * 8], a);
        int wmax = tl < WIN_ ? tl : WIN_;
        float msim = -INFINITY;
        for (int w = 1; w <= wmax; w++) {
            if (!vld[t - w]) continue;
            float bvv[8];
            bf8_to_f32(*(const uint4*)&fnbs[lr - w][lane * 8], bvv);
            float p = 0.f;
            #pragma unroll
            for (int i = 0; i < 8; i++) p = fmaf(a[i], bvv[i], p);
            p = wred_sum(p);
            msim = fmaxf(msim, p);
        }
        int kp = (vld[t] && (msim < 0.7f)) ? 1 : 0;
        if (lane == 0) keep[t] = kp;
    }
}

// ------------------------------------------------- per-batch exact top-k (radix select)
static __device__ void scan1024(int* tot, int tid) {
    if (tid < 64) {
        int vals[16], s = 0;
        #pragma unroll
        for (int i = 0; i < 16; i++) vals[i] = tot[tid * 16 + i];
        #pragma unroll
        for (int i = 0; i < 16; i++) { int t = vals[i]; vals[i] = s; s += t; }
        int inc = s;
        #pragma unroll
        for (int d = 1; d < 64; d <<= 1) {
            int v = __shfl_up(inc, d, 64);
            if ((tid & 63) >= d) inc += v;
        }
        int excl = inc - s;
        #pragma unroll
        for (int i = 0; i < 16; i++) tot[tid * 16 + i] = vals[i] + excl;
    }
}

__global__ __launch_bounds__(1024) void k_topk(const float* rel, const int* keep, int* idxo) {
    int b = blockIdx.x, tid = threadIdx.x;
    const float* relb = rel + (long)b * N_;
    const int* keepb  = keep + (long)b * N_;
    __shared__ unsigned int hist[256];
    __shared__ int toti[1024];
    __shared__ unsigned int s_prefix;
    __shared__ int s_rem, s_k;

    unsigned int key[16];
    int base = tid * 16, nk_local = 0;
    #pragma unroll
    for (int j = 0; j < 16; j++) {
        int i = base + j;
        float r = relb[i];
        int kp = keepb[i];
        unsigned int bits = __float_as_uint(r);
        unsigned int kk = (bits & 0x80000000u) ? ~bits : (bits | 0x80000000u);
        key[j] = kp ? kk : 0u;
        nk_local += kp;
    }
    toti[tid] = nk_local; __syncthreads();
    for (int o = 512; o > 0; o >>= 1) { if (tid < o) toti[tid] += toti[tid + o]; __syncthreads(); }
    if (tid == 0) {
        int n_kept = toti[0];
        int k = (int)(0.8f * (float)n_kept);
        if (k < 1) k = 1; if (k > LMAX_) k = LMAX_;
        s_k = k; s_rem = k; s_prefix = 0u;
    }
    __syncthreads();

    for (int pass = 0; pass < 4; pass++) {
        int shift = 24 - pass * 8;
        unsigned int himask = (pass == 0) ? 0u : (0xFFFFFFFFu << (shift + 8));
        if (tid < 256) hist[tid] = 0u;
        __syncthreads();
        unsigned int pfx = s_prefix;
        #pragma unroll
        for (int j = 0; j < 16; j++) {
            unsigned int kk = key[j];
            if ((kk & himask) == (pfx & himask))
                atomicAdd(&hist[(kk >> shift) & 255], 1u);
        }
        __syncthreads();
        if (tid == 0) {
            int rem = s_rem;
            unsigned int cum = 0;
            for (int d = 255; d >= 0; d--) {
                unsigned int h = hist[d];
                if (cum + h >= (unsigned int)rem) {
                    s_rem = rem - (int)cum;
                    s_prefix = pfx | ((unsigned int)d << shift);
                    break;
                }
                cum += h;
            }
        }
        __syncthreads();
    }
    unsigned int T = s_prefix;
    int tie_need = s_rem, k = s_k;

    int eq[16], gt[16], eqpre[16];
    int locEq = 0;
    #pragma unroll
    for (int j = 0; j < 16; j++) {
        eq[j] = (key[j] == T); gt[j] = (key[j] > T);
        eqpre[j] = locEq; locEq += eq[j];
    }
    toti[tid] = locEq; __syncthreads();
    scan1024(toti, tid); __syncthreads();
    int eqoff = toti[tid];

    int sel[16], spre[16];
    int locS = 0;
    #pragma unroll
    for (int j = 0; j < 16; j++) {
        int rank = eqoff + eqpre[j];
        sel[j] = gt[j] || (eq[j] && rank < tie_need);
        spre[j] = locS; locS += sel[j];
    }
    __syncthreads();
    toti[tid] = locS; __syncthreads();
    scan1024(toti, tid); __syncthreads();
    int soff = toti[tid];
    #pragma unroll
    for (int j = 0; j < 16; j++)
        if (sel[j]) idxo[b * LMAX_ + soff + spre[j]] = base + j;
    for (int p = k + tid; p < LMAX_; p += 1024) idxo[b * LMAX_ + p] = N_;
}

// ------------------------------------------------- feat2 gather + pair pooling
__global__ void k_feat3(const float* img, const int* idxo, float* f3) {
    int bm = blockIdx.x;
    int b = bm >> 9, m = bm & 511;
    int i0 = idxo[b * LMAX_ + 2 * m], i1 = idxo[b * LMAX_ + 2 * m + 1];
    int c0 = i0 < N_, c1 = i1 < N_;
    float dn = 1.0f / fmaxf((float)(c0 + c1), 1.0f);
    const float* p0 = img + ((long)b * N_ + (c0 ? i0 : 0)) * D_;
    const float* p1 = img + ((long)b * N_ + (c1 ? i1 : 0)) * D_;
    int d = threadIdx.x * 4;
    float4 v0 = c0 ? *(const float4*)(p0 + d) : make_float4(0.f, 0.f, 0.f, 0.f);
    float4 v1 = c1 ? *(const float4*)(p1 + d) : make_float4(0.f, 0.f, 0.f, 0.f);
    float4 o;
    o.x = (v0.x + v1.x) * dn; o.y = (v0.y + v1.y) * dn;
    o.z = (v0.z + v1.z) * dn; o.w = (v0.w + v1.w) * dn;
    *(float4*)(f3 + (long)bm * D_ + d) = o;
}

// ------------------------------------------------- tiled f32 GEMM (small k/v projections)
#define BM 128
#define BN 64
#define BK 32
#define ASTR 136
__global__ __launch_bounds__(256) void k_gemm(const float* __restrict__ A, int lda,
                                              const float* __restrict__ Bw, int ldb,
                                              const float* __restrict__ bias,
                                              float* __restrict__ C, int ldc, int K) {
    __shared__ float As[BK][ASTR];
    __shared__ float Bsf[BK][BN];
    int bm = blockIdx.x, bn = blockIdx.y;
    int tid = threadIdx.x;
    int trow = tid >> 4, tcol = tid & 15;
    float acc[8][4] = {};
    const float* Ab = A + (long)bm * BM * lda;
    const float* Bb = Bw + bn * BN;
    for (int kt = 0; kt < K; kt += BK) {
        #pragma unroll
        for (int i = 0; i < 4; i++) {
            int f = tid + 256 * i;
            int row = f >> 3, c4 = (f & 7) << 2;
            float4 v = *(const float4*)(Ab + (long)row * lda + kt + c4);
            As[c4 + 0][row] = v.x; As[c4 + 1][row] = v.y;
            As[c4 + 2][row] = v.z; As[c4 + 3][row] = v.w;
        }
        #pragma unroll
        for (int i = 0; i < 2; i++) {
            int f = tid + 256 * i;
            int row = f >> 4, c4 = (f & 15) << 2;
            *(float4*)&Bsf[row][c4] = *(const float4*)(Bb + (long)(kt + row) * ldb + c4);
        }
        __syncthreads();
        #pragma unroll 8
        for (int kk = 0; kk < BK; kk++) {
            float a[8], bv[4];
            #pragma unroll
            for (int i = 0; i < 8; i++) a[i] = As[kk][trow * 8 + i];
            #pragma unroll
            for (int j = 0; j < 4; j++) bv[j] = Bsf[kk][tcol * 4 + j];
            #pragma unroll
            for (int i = 0; i < 8; i++)
                #pragma unroll
                for (int j = 0; j < 4; j++)
                    acc[i][j] = fmaf(a[i], bv[j], acc[i][j]);
        }
        __syncthreads();
    }
    int c = bn * BN + tcol * 4;
    #pragma unroll
    for (int i = 0; i < 8; i++) {
        long r = (long)bm * BM + trow * 8 + i;
        float4 v;
        v.x = acc[i][0] + bias[c + 0]; v.y = acc[i][1] + bias[c + 1];
        v.z = acc[i][2] + bias[c + 2]; v.w = acc[i][3] + bias[c + 3];
        *(float4*)(C + r * ldc + c) = v;
    }
}

// ------------------------------------------------- cross-modal attention
__global__ __launch_bounds__(512) void k_attn(const float* qv, const float* kk,
                                              const float* vv, float* ctx) {
    int bh = blockIdx.x;
    int b = bh >> 3, h = bh & 7;
    __shared__ float qs[DH_];
    __shared__ float sc[M2_];
    __shared__ float red[M2_];
    int m = threadIdx.x;
    if (m < DH_) qs[m] = qv[b * D_ + h * DH_ + m];
    __syncthreads();
    const float* kp = kk + (long)b * M2_ * D_ + h * DH_;
    float acc = 0.f;
    #pragma unroll
    for (int d = 0; d < DH_; d += 4) {
        float4 kv = *(const float4*)(kp + (long)m * D_ + d);
        acc += qs[d] * kv.x + qs[d + 1] * kv.y + qs[d + 2] * kv.z + qs[d + 3] * kv.w;
    }
    acc *= 0.125f;
    red[m] = acc; __syncthreads();
    for (int o = 256; o > 0; o >>= 1) { if (m < o) red[m] = fmaxf(red[m], red[m + o]); __syncthreads(); }
    float mx = red[0]; __syncthreads();
    float e = expf(acc - mx);
    sc[m] = e; red[m] = e; __syncthreads();
    for (int o = 256; o > 0; o >>= 1) { if (m < o) red[m] += red[m + o]; __syncthreads(); }
    float inv = 1.0f / red[0];
    if (m < DH_) {
        float a2 = 0.f;
        const float* vp = vv + (long)b * M2_ * D_ + h * DH_ + m;
        for (int mm = 0; mm < M2_; mm++) a2 = fmaf(sc[mm], vp[(long)mm * D_], a2);
        ctx[b * D_ + h * DH_ + m] = a2 * inv;
    }
}

// ------------------------------------------------- output head (Wo then W_cls), f32 out
__global__ __launch_bounds__(512) void k_head(const float* ctx, const float* Wo, const float* bo,
                                              const float* Wc, const float* bc,
                                              float* out) {
    int b = blockIdx.x, d = threadIdx.x;
    __shared__ float cl[D_], ol[D_];
    cl[d] = ctx[b * D_ + d]; __syncthreads();
    float acc = bo[d];
    for (int e = 0; e < D_; e++) acc = fmaf(cl[e], Wo[(long)e * D_ + d], acc);
    ol[d] = acc; __syncthreads();
    if (d < 4) {
        float a2 = bc[d];
        for (int e = 0; e < D_; e++) a2 = fmaf(ol[e], Wc[e * 4 + d], a2);
        out[b * 4 + d] = a2;
    }
}

// ---------------------------------------------------------------- launcher
extern "C" void kernel_launch(void* const* d_in, const int* in_sizes, int n_in,
                              void* d_out, int out_size, void* d_ws, size_t ws_size,
                              hipStream_t stream) {
    const float* bags = (const float*)d_in[0];
    const void*  kpm  = d_in[1];
    const int*   ids  = (const int*)d_in[2];
    const int*   am   = (const int*)d_in[3];
    const float* emb  = (const float*)d_in[4];
    const float* Wtp  = (const float*)d_in[5];
    const float* btp  = (const float*)d_in[6];
    const float* Wen  = (const float*)d_in[7];
    const float* ben  = (const float*)d_in[8];
    const float* lng  = (const float*)d_in[9];
    const float* lnb  = (const float*)d_in[10];
    const float* Wq   = (const float*)d_in[11];
    const float* bq   = (const float*)d_in[12];
    const float* Wk   = (const float*)d_in[13];
    const float* bk   = (const float*)d_in[14];
    const float* Wv   = (const float*)d_in[15];
    const float* bv   = (const float*)d_in[16];
    const float* Wo   = (const float*)d_in[17];
    const float* bo   = (const float*)d_in[18];
    const float* Wc   = (const float*)d_in[19];
    const float* bc   = (const float*)d_in[20];

    char* ws = (char*)d_ws;
    size_t o = 0;
    auto alloc = [&](size_t bytes) -> void* {
        void* p = ws + o; o += (bytes + 255) & ~(size_t)255; return p;
    };
    float* img  = (float*)alloc((size_t)NTOK_ * D_ * 4);
    float* rno  = (float*)alloc((size_t)NTOK_ * 4);
    float* rel  = (float*)alloc((size_t)NTOK_ * 4);
    int*   keep = (int*)alloc((size_t)NTOK_ * 4);
    unsigned char* vld = (unsigned char*)alloc(NTOK_);
    float* tf   = (float*)alloc(B_ * 768 * 4);
    float* te   = (float*)alloc(B_ * D_ * 4);
    float* qv   = (float*)alloc(B_ * D_ * 4);
    int*   idxo = (int*)alloc(B_ * LMAX_ * 4);
    float* f3   = (float*)alloc((size_t)B_ * M2_ * D_ * 4);
    float* kkb  = (float*)alloc((size_t)B_ * M2_ * D_ * 4);
    float* vvb  = (float*)alloc((size_t)B_ * M2_ * D_ * 4);
    float* ctx  = (float*)alloc(B_ * D_ * 4);
    int*   flag = (int*)alloc(256);
    unsigned short* bth = (unsigned short*)alloc((size_t)D_ * F_ * 2);
    unsigned short* btl = (unsigned short*)alloc((size_t)D_ * F_ * 2);

    // new path: A split planes (512 MiB). fnb aliases a_hi (dead after GEMM).
    size_t aplanes = (size_t)NTOK_ * F_ * 2;       // 256 MiB each
    bool newpath = (ws_size > o) && ((ws_size - o) >= 2 * aplanes + 4096);
    unsigned short* a_hi = nullptr;
    unsigned short* a_lo = nullptr;
    unsigned short* fnb  = nullptr;
    if (newpath) {
        a_hi = (unsigned short*)alloc(aplanes);
        a_lo = (unsigned short*)alloc(aplanes);
        fnb  = a_hi;                               // alias: k_ln runs after k_gemm2
    } else {
        size_t need = (size_t)NTOK_ * D_ * 2 + 1024;
        if (ws_size > o && (ws_size - o) >= need)
            fnb = (unsigned short*)alloc((size_t)NTOK_ * D_ * 2);
    }

    hipMemsetAsync(flag, 0, 4, stream);
    k_detect<<<64, 256, 0, stream>>>((const unsigned char*)kpm, NTOK_, flag);
    k_valid<<<(NTOK_ + 255) / 256, 256, 0, stream>>>(kpm, flag, vld);
    k_text_feat<<<B_, 256, 0, stream>>>(emb, ids, am, tf);
    k_rowmm<<<B_, 512, 0, stream>>>(tf, Wtp, btp, te, 768, 512);
    k_rowmm<<<B_, 512, 0, stream>>>(te, Wq, bq, qv, 512, 512);

    dim3 gsplit(F_ / 32, D_ / 32);
    if (newpath) {
        k_bsplit_sw<<<gsplit, 256, 0, stream>>>(Wen, bth, btl);
        k_asplit<<<4096, 256, 0, stream>>>(bags, a_hi, a_lo);
        k_gemm2<<<4096, 256, 0, stream>>>(a_hi, a_lo, bth, btl, ben, img);
    } else {
        k_bsplit<<<gsplit, 256, 0, stream>>>(Wen, bth, btl);
        dim3 g3(NTOK_ / 64, 2);
        k_gemm_mfma<<<g3, 256, 0, stream>>>(bags, bth, btl, ben, img);
    }

    k_ln<<<NTOK_ / 4, 256, 0, stream>>>(img, lng, lnb, te, rno, rel, fnb);
    if (fnb) k_simg<<<NTOK_ / 128, 256, 0, stream>>>(fnb, vld, keep);
    else     k_sim<<<(NTOK_ + CHUNK - 1) / CHUNK, 256, 0, stream>>>(img, rno, vld, keep);
    k_topk<<<B_, 1024, 0, stream>>>(rel, keep, idxo);
    k_feat3<<<B_ * M2_, 128, 0, stream>>>(img, idxo, f3);

    dim3 g8(B_ * M2_ / BM, D_ / BN);
    k_gemm<<<g8, 256, 0, stream>>>(f3, D_, Wk, D_, bk, kkb, D_, D_);
    k_gemm<<<g8, 256, 0, stream>>>(f3, D_, Wv, D_, bv, vvb, D_, D_);

    k_attn<<<B_ * H_, 512, 0, stream>>>(qv, kkb, vvb, ctx);
    k_head<<<B_, 512, 0, stream>>>(ctx, Wo, bo, Wc, bc, (float*)d_out);
}

// Round 7
// 1238.932 us; speedup vs baseline: 2.7565x; 1.0041x over previous
//
#include <hip/hip_runtime.h>
#include <hip/hip_bf16.h>
#include <math.h>
#include <stdint.h>

#define B_    8
#define N_    16384
#define F_    1024
#define D_    512
#define S_    64
#define H_    8
#define DH_   64
#define LMAX_ 1024
#define M2_   512
#define WIN_  32
#define NTOK_ (B_ * N_)   // 131072

typedef __attribute__((ext_vector_type(8)))  short bf16x8;
typedef __attribute__((ext_vector_type(16))) float f32x16;

// quad-swizzle within each 64B (4x16B) group, keyed by row low bits
#define S_OF(r) (((r) >> 1) & 3)

// ---------------------------------------------------------------- utilities
static __device__ __forceinline__ float wred_sum(float v) {
    #pragma unroll
    for (int d = 1; d < 64; d <<= 1) v += __shfl_xor(v, d, 64);
    return v;
}

static __device__ __forceinline__ void bf8_to_f32(uint4 q, float* a) {
    a[0] = __uint_as_float(q.x << 16); a[1] = __uint_as_float(q.x & 0xffff0000u);
    a[2] = __uint_as_float(q.y << 16); a[3] = __uint_as_float(q.y & 0xffff0000u);
    a[4] = __uint_as_float(q.z << 16); a[5] = __uint_as_float(q.z & 0xffff0000u);
    a[6] = __uint_as_float(q.w << 16); a[7] = __uint_as_float(q.w & 0xffff0000u);
}

static __device__ __forceinline__ unsigned short bf16r(float x) {   // RNE f32->bf16
    unsigned int b = __float_as_uint(x);
    return (unsigned short)((b + 0x7FFFu + ((b >> 16) & 1u)) >> 16);
}

static __device__ __forceinline__ void split_bf(float x, unsigned short& h, unsigned short& l) {
    unsigned int b = __float_as_uint(x);
    unsigned int hb = (b + 0x7FFFu + ((b >> 16) & 1u)) >> 16;
    h = (unsigned short)hb;
    float r = x - __uint_as_float(hb << 16);
    l = bf16r(r);
}

static __device__ __forceinline__ void gll16(const void* g, void* l) {
    __builtin_amdgcn_global_load_lds(
        (const __attribute__((address_space(1))) unsigned int*)g,
        (__attribute__((address_space(3))) unsigned int*)l, 16, 0, 0);
}

// ------------------------------------------------- mask layout detection
__global__ void k_detect(const unsigned char* mb, int nbytes, int* flag) {
    int found = 0;
    for (int i = blockIdx.x * blockDim.x + threadIdx.x; i < nbytes; i += gridDim.x * blockDim.x)
        if ((i & 3) && mb[i]) found = 1;
    if (found) atomicOr(flag, 1);
}

__global__ void k_valid(const void* maskp, const int* flag, unsigned char* v) {
    int i = blockIdx.x * 256 + threadIdx.x;
    if (i >= NTOK_) return;
    int pad;
    if (*flag) pad = (((const unsigned char*)maskp)[i] != 0);
    else       pad = (((const int*)maskp)[i] != 0);
    v[i] = pad ? 0 : 1;
}

// ------------------------------------------------- text feature (masked mean)
__global__ void k_text_feat(const float* emb, const int* ids, const int* am, float* tf) {
    int b = blockIdx.x;
    __shared__ int   sid[S_];
    __shared__ float sam[S_];
    int t = threadIdx.x;
    if (t < S_) { sid[t] = ids[b * S_ + t]; sam[t] = (float)am[b * S_ + t]; }
    __syncthreads();
    float asum = 0.f;
    for (int s = 0; s < S_; s++) asum += sam[s];
    float denom = fmaxf(asum, 1.0f);
    for (int d = t; d < 768; d += blockDim.x) {
        float acc = 0.f;
        for (int s = 0; s < S_; s++) acc += emb[(long)sid[s] * 768 + d] * sam[s];
        tf[b * 768 + d] = acc / denom;
    }
}

__global__ void k_rowmm(const float* in, const float* W, const float* bias,
                        float* out, int E, int Nn) {
    int b = blockIdx.x, d = threadIdx.x;
    __shared__ float sin[768];
    for (int e = d; e < E; e += blockDim.x) sin[e] = in[b * E + e];
    __syncthreads();
    float acc = bias[d];
    for (int e = 0; e < E; e++) acc = fmaf(sin[e], W[(long)e * Nn + d], acc);
    out[b * Nn + d] = acc;
}

// ------------------------------------------------- A split prepass: f32 -> bf16 hi/lo, swizzled
__global__ __launch_bounds__(256) void k_asplit(const float* __restrict__ A,
                                                unsigned short* __restrict__ ah,
                                                unsigned short* __restrict__ al) {
    const long nquads = (long)NTOK_ * 128;
    long idx0 = (long)blockIdx.x * 256 + threadIdx.x;
    long stride = (long)gridDim.x * 256;
    for (long idx = idx0; idx < nquads; idx += stride) {
        long row = idx >> 7;
        int q = (int)(idx & 127);
        int s = S_OF((int)row & 7);
        int qo = (q & ~3) | ((q & 3) ^ s);
        const float* p = A + (row << 10) + q * 8;
        float4 v0 = *(const float4*)p;
        float4 v1 = *(const float4*)(p + 4);
        float xs[8] = { v0.x, v0.y, v0.z, v0.w, v1.x, v1.y, v1.z, v1.w };
        unsigned short h[8], l[8];
        #pragma unroll
        for (int i = 0; i < 8; i++) split_bf(xs[i], h[i], l[i]);
        uint4 ph, pl;
        ph.x = h[0] | ((unsigned)h[1] << 16); ph.y = h[2] | ((unsigned)h[3] << 16);
        ph.z = h[4] | ((unsigned)h[5] << 16); ph.w = h[6] | ((unsigned)h[7] << 16);
        pl.x = l[0] | ((unsigned)l[1] << 16); pl.y = l[2] | ((unsigned)l[3] << 16);
        pl.z = l[4] | ((unsigned)l[5] << 16); pl.w = l[6] | ((unsigned)l[7] << 16);
        *(uint4*)(ah + (row << 10) + qo * 8) = ph;
        *(uint4*)(al + (row << 10) + qo * 8) = pl;
    }
}

// ------------------------------------------------- W_enc transpose + split, swizzled layout
__global__ __launch_bounds__(256) void k_bsplit_sw(const float* __restrict__ W,
                                                   unsigned short* __restrict__ bh,
                                                   unsigned short* __restrict__ bl) {
    __shared__ float tile[32][33];
    int e0 = blockIdx.x * 32;   // k origin
    int d0 = blockIdx.y * 32;   // out-col origin
    int t = threadIdx.x;
    int r = t >> 3, c4 = (t & 7) * 4;
    float4 v = *(const float4*)(W + (long)(e0 + r) * D_ + d0 + c4);
    tile[r][c4] = v.x; tile[r][c4 + 1] = v.y; tile[r][c4 + 2] = v.z; tile[r][c4 + 3] = v.w;
    __syncthreads();
    if (t < 128) {
        int c = t & 31, kq = t >> 5;           // col-in-tile, quad-in-tile (0..3)
        int col = d0 + c;
        float xs[8];
        #pragma unroll
        for (int i = 0; i < 8; i++) xs[i] = tile[kq * 8 + i][c];
        unsigned short h[8], l[8];
        #pragma unroll
        for (int i = 0; i < 8; i++) split_bf(xs[i], h[i], l[i]);
        uint4 ph, pl;
        ph.x = h[0] | ((unsigned)h[1] << 16); ph.y = h[2] | ((unsigned)h[3] << 16);
        ph.z = h[4] | ((unsigned)h[5] << 16); ph.w = h[6] | ((unsigned)h[7] << 16);
        pl.x = l[0] | ((unsigned)l[1] << 16); pl.y = l[2] | ((unsigned)l[3] << 16);
        pl.z = l[4] | ((unsigned)l[5] << 16); pl.w = l[6] | ((unsigned)l[7] << 16);
        int Q = (e0 >> 3) + kq;
        int Qo = (Q & ~3) | ((Q & 3) ^ S_OF(col & 7));
        *(uint4*)(bh + (long)col * 1024 + Qo * 8) = ph;
        *(uint4*)(bl + (long)col * 1024 + Qo * 8) = pl;
    }
}

// ------------------------------------------------- counted-vmcnt 2-phase gll GEMM (T3/T4-min)
// Tile 128x128, BK=32, 4 waves, double-buffered LDS. Wave w stages plane w; next
// K-step's 8 gll stay in flight across barriers (s_waitcnt vmcnt(8), never 0 mid-loop).
// Wave w computes quadrant (wr,wc) = (w>>1, w&1).
__global__ __launch_bounds__(256) void k_gemm2(const unsigned short* __restrict__ Ah,
                                               const unsigned short* __restrict__ Al,
                                               const unsigned short* __restrict__ Bh2,
                                               const unsigned short* __restrict__ Bl2,
                                               const float* __restrict__ bias,
                                               float* __restrict__ C) {
    __shared__ __align__(16) unsigned short lds[2][4][128][32];   // 64 KiB (2 bufs)
    int bid = blockIdx.x;
    int wg = (bid & 7) * 512 + (bid >> 3);    // bijective: nwg=4096 % 8 == 0
    int bn = wg & 3, bm = wg >> 2;
    int tid = threadIdx.x;
    int w = tid >> 6, lane = tid & 63;
    int r32 = lane & 31, kg = lane >> 5;
    int lrow = lane >> 2, lq = lane & 3;
    int wr = w >> 1, wc = w & 1;              // wave's output quadrant

    const unsigned short* plane = (w == 0) ? Ah : (w == 1) ? Al : (w == 2) ? Bh2 : Bl2;
    long prow0 = (w < 2) ? ((long)bm * 128) : ((long)bn * 128);
    const unsigned short* gbase = plane + (prow0 + lrow) * 1024 + lq * 8;

    f32x16 acc[2][2];
    #pragma unroll
    for (int i = 0; i < 2; i++)
        #pragma unroll
        for (int j = 0; j < 2; j++)
            #pragma unroll
            for (int r = 0; r < 16; r++) acc[i][j][r] = 0.f;

    // prologue: stage kt=0 into buffer 0 (8 gll in flight)
    #pragma unroll
    for (int j = 0; j < 8; j++)
        gll16(gbase + (long)j * 16 * 1024, &lds[0][w][j * 16][0]);

    #pragma unroll 1
    for (int kt = 0; kt < 1024; kt += 32) {
        int cur = (kt >> 5) & 1;
        if (kt + 32 < 1024) {
            // issue next tile into the other buffer (adds 8 -> <=16 in flight)
            #pragma unroll
            for (int j = 0; j < 8; j++)
                gll16(gbase + (long)j * 16 * 1024 + kt + 32, &lds[cur ^ 1][w][j * 16][0]);
            // wait only for the OLDEST 8 (current tile); next tile stays in flight
            asm volatile("s_waitcnt vmcnt(8)" ::: "memory");
        } else {
            asm volatile("s_waitcnt vmcnt(0)" ::: "memory");
        }
        __builtin_amdgcn_sched_barrier(0);
        __builtin_amdgcn_s_barrier();          // every wave's cur plane landed
        __builtin_amdgcn_sched_barrier(0);

        #pragma unroll
        for (int k2 = 0; k2 < 2; k2++) {
            int qb = k2 * 2 + kg;
            int q = (qb ^ S_OF(r32)) * 8;     // row&7 == r32&7 for all fragment rows
            bf16x8 a_h[2], a_l[2], b_h[2], b_l[2];
            #pragma unroll
            for (int rf = 0; rf < 2; rf++) {
                int ar = wr * 64 + rf * 32 + r32;
                a_h[rf] = *(const bf16x8*)&lds[cur][0][ar][q];
                a_l[rf] = *(const bf16x8*)&lds[cur][1][ar][q];
            }
            #pragma unroll
            for (int cf = 0; cf < 2; cf++) {
                int bc = wc * 64 + cf * 32 + r32;
                b_h[cf] = *(const bf16x8*)&lds[cur][2][bc][q];
                b_l[cf] = *(const bf16x8*)&lds[cur][3][bc][q];
            }
            #pragma unroll
            for (int rf = 0; rf < 2; rf++)
                #pragma unroll
                for (int cf = 0; cf < 2; cf++) {
                    acc[rf][cf] = __builtin_amdgcn_mfma_f32_32x32x16_bf16(a_h[rf], b_h[cf], acc[rf][cf], 0, 0, 0);
                    acc[rf][cf] = __builtin_amdgcn_mfma_f32_32x32x16_bf16(a_h[rf], b_l[cf], acc[rf][cf], 0, 0, 0);
                    acc[rf][cf] = __builtin_amdgcn_mfma_f32_32x32x16_bf16(a_l[rf], b_h[cf], acc[rf][cf], 0, 0, 0);
                }
        }
        __builtin_amdgcn_sched_barrier(0);
        __builtin_amdgcn_s_barrier();          // all reads of buf[cur] retired -> restage OK
        __builtin_amdgcn_sched_barrier(0);
    }
    #pragma unroll
    for (int rf = 0; rf < 2; rf++)
        #pragma unroll
        for (int cf = 0; cf < 2; cf++) {
            int col = bn * 128 + wc * 64 + cf * 32 + r32;
            float bv = bias[col];
            #pragma unroll
            for (int r = 0; r < 16; r++) {
                int row = bm * 128 + wr * 64 + rf * 32 + (r & 3) + 8 * (r >> 2) + 4 * kg;
                C[(long)row * D_ + col] = acc[rf][cf][r] + bv;
            }
        }
}

// ------------------------------------------------- fallback fused split GEMM (round-4)
#define GPAD 40
__global__ __launch_bounds__(256, 3) void k_gemm_mfma(const float* __restrict__ A,
                                                      const unsigned short* __restrict__ Bth,
                                                      const unsigned short* __restrict__ Btl,
                                                      const float* __restrict__ bias,
                                                      float* __restrict__ C) {
    __shared__ __align__(16) unsigned short As[2][64][GPAD];
    __shared__ __align__(16) unsigned short Bs[2][256][GPAD];
    int bm = blockIdx.x, bn = blockIdx.y;
    int tid = threadIdx.x;
    int w = tid >> 6, lane = tid & 63;
    int r32 = lane & 31, kg = lane >> 5;
    f32x16 acc[2][2];
    #pragma unroll
    for (int i = 0; i < 2; i++)
        #pragma unroll
        for (int j = 0; j < 2; j++)
            #pragma unroll
            for (int r = 0; r < 16; r++) acc[i][j][r] = 0.f;
    int arow = tid >> 2, aq = tid & 3;
    const float* abase = A + (long)(bm * 64 + arow) * 1024 + aq * 8;
    const unsigned short* bhbase = Bth + (long)(bn * 256 + tid) * 1024;
    const unsigned short* blbase = Btl + (long)(bn * 256 + tid) * 1024;
    float4 pa0 = *(const float4*)abase;
    float4 pa1 = *(const float4*)(abase + 4);
    for (int kt = 0; kt < 1024; kt += 32) {
        {
            float xs[8] = { pa0.x, pa0.y, pa0.z, pa0.w, pa1.x, pa1.y, pa1.z, pa1.w };
            unsigned short h[8], l[8];
            #pragma unroll
            for (int i = 0; i < 8; i++) split_bf(xs[i], h[i], l[i]);
            uint4 ph, pl;
            ph.x = h[0] | ((unsigned)h[1] << 16); ph.y = h[2] | ((unsigned)h[3] << 16);
            ph.z = h[4] | ((unsigned)h[5] << 16); ph.w = h[6] | ((unsigned)h[7] << 16);
            pl.x = l[0] | ((unsigned)l[1] << 16); pl.y = l[2] | ((unsigned)l[3] << 16);
            pl.z = l[4] | ((unsigned)l[5] << 16); pl.w = l[6] | ((unsigned)l[7] << 16);
            *(uint4*)&As[0][arow][aq * 8] = ph;
            *(uint4*)&As[1][arow][aq * 8] = pl;
        }
        {
            const uint4* ph = (const uint4*)(bhbase + kt);
            const uint4* pl = (const uint4*)(blbase + kt);
            #pragma unroll
            for (int q = 0; q < 4; q++) {
                *(uint4*)&Bs[0][tid][q * 8] = ph[q];
                *(uint4*)&Bs[1][tid][q * 8] = pl[q];
            }
        }
        __syncthreads();
        if (kt + 32 < 1024) {
            const float* ap = abase + kt + 32;
            pa0 = *(const float4*)ap;
            pa1 = *(const float4*)(ap + 4);
        }
        #pragma unroll
        for (int k2 = 0; k2 < 2; k2++) {
            int ko = k2 * 16 + kg * 8;
            bf16x8 ah[2], al[2], bh[2], blv[2];
            #pragma unroll
            for (int rf = 0; rf < 2; rf++) {
                ah[rf] = *(const bf16x8*)&As[0][rf * 32 + r32][ko];
                al[rf] = *(const bf16x8*)&As[1][rf * 32 + r32][ko];
            }
            #pragma unroll
            for (int cf = 0; cf < 2; cf++) {
                bh[cf]  = *(const bf16x8*)&Bs[0][w * 64 + cf * 32 + r32][ko];
                blv[cf] = *(const bf16x8*)&Bs[1][w * 64 + cf * 32 + r32][ko];
            }
            #pragma unroll
            for (int rf = 0; rf < 2; rf++)
                #pragma unroll
                for (int cf = 0; cf < 2; cf++) {
                    acc[rf][cf] = __builtin_amdgcn_mfma_f32_32x32x16_bf16(ah[rf], bh[cf],  acc[rf][cf], 0, 0, 0);
                    acc[rf][cf] = __builtin_amdgcn_mfma_f32_32x32x16_bf16(ah[rf], blv[cf], acc[rf][cf], 0, 0, 0);
                    acc[rf][cf] = __builtin_amdgcn_mfma_f32_32x32x16_bf16(al[rf], bh[cf],  acc[rf][cf], 0, 0, 0);
                }
        }
        __syncthreads();
    }
    #pragma unroll
    for (int rf = 0; rf < 2; rf++)
        #pragma unroll
        for (int cf = 0; cf < 2; cf++) {
            int col = bn * 256 + w * 64 + cf * 32 + r32;
            float bv = bias[col];
            #pragma unroll
            for (int r = 0; r < 16; r++) {
                int row = bm * 64 + rf * 32 + (r & 3) + 8 * (r >> 2) + 4 * kg;
                C[(long)row * D_ + col] = acc[rf][cf][r] + bv;
            }
        }
}

// old unswizzled bsplit (fallback path)
__global__ __launch_bounds__(256) void k_bsplit(const float* __restrict__ W,
                                                unsigned short* __restrict__ bh,
                                                unsigned short* __restrict__ bl) {
    __shared__ float tile[32][33];
    int e0 = blockIdx.x * 32;
    int d0 = blockIdx.y * 32;
    int t = threadIdx.x;
    int r = t >> 3;
    int c = (t & 7) * 4;
    float4 v = *(const float4*)(W + (long)(e0 + r) * D_ + d0 + c);
    tile[r][c] = v.x; tile[r][c + 1] = v.y; tile[r][c + 2] = v.z; tile[r][c + 3] = v.w;
    __syncthreads();
    ushort4 h4, l4;
    unsigned short hh, ll;
    float x0 = tile[c + 0][r], x1 = tile[c + 1][r], x2 = tile[c + 2][r], x3 = tile[c + 3][r];
    split_bf(x0, hh, ll); h4.x = hh; l4.x = ll;
    split_bf(x1, hh, ll); h4.y = hh; l4.y = ll;
    split_bf(x2, hh, ll); h4.z = hh; l4.z = ll;
    split_bf(x3, hh, ll); h4.w = hh; l4.w = ll;
    *(ushort4*)(bh + (long)(d0 + r) * 1024 + e0 + c) = h4;
    *(ushort4*)(bl + (long)(d0 + r) * 1024 + e0 + c) = l4;
}

// ------------------------------------------------- LayerNorm+ReLU (in place) + rnorm + rel (+fnb)
__global__ __launch_bounds__(256) void k_ln(float* h, const float* g, const float* bb,
                                            const float* temb, float* rnorm, float* rel,
                                            unsigned short* fnb) {
    int wid = threadIdx.x >> 6, lane = threadIdx.x & 63;
    long row = (long)blockIdx.x * 4 + wid;
    int b = (int)(row >> 14);
    float* hp = h + row * (long)D_;
    int c0 = lane * 4, c1 = 256 + lane * 4;
    float4 x0 = *(float4*)(hp + c0);
    float4 x1 = *(float4*)(hp + c1);
    float x[8] = { x0.x, x0.y, x0.z, x0.w, x1.x, x1.y, x1.z, x1.w };
    float s = 0.f;
    #pragma unroll
    for (int i = 0; i < 8; i++) s += x[i];
    s = wred_sum(s);
    float mu = s * (1.0f / 512.0f);
    float var = 0.f;
    #pragma unroll
    for (int i = 0; i < 8; i++) { float d = x[i] - mu; var += d * d; }
    var = wred_sum(var) * (1.0f / 512.0f);
    float inv = 1.0f / sqrtf(var + 1e-5f);
    float4 g0 = *(const float4*)(g + c0), g1 = *(const float4*)(g + c1);
    float4 b0 = *(const float4*)(bb + c0), b1 = *(const float4*)(bb + c1);
    float gg[8] = { g0.x, g0.y, g0.z, g0.w, g1.x, g1.y, g1.z, g1.w };
    float bbv[8] = { b0.x, b0.y, b0.z, b0.w, b1.x, b1.y, b1.z, b1.w };
    float y[8], sq = 0.f;
    #pragma unroll
    for (int i = 0; i < 8; i++) {
        y[i] = fmaxf(gg[i] * (x[i] - mu) * inv + bbv[i], 0.0f);
        sq += y[i] * y[i];
    }
    float4 o0 = { y[0], y[1], y[2], y[3] }, o1 = { y[4], y[5], y[6], y[7] };
    *(float4*)(hp + c0) = o0;
    *(float4*)(hp + c1) = o1;
    sq = wred_sum(sq);
    float rn = 1.0f / (sqrtf(sq) + 1e-8f);
    if (fnb) {
        ushort4 u0, u1;
        u0.x = bf16r(y[0] * rn); u0.y = bf16r(y[1] * rn);
        u0.z = bf16r(y[2] * rn); u0.w = bf16r(y[3] * rn);
        u1.x = bf16r(y[4] * rn); u1.y = bf16r(y[5] * rn);
        u1.z = bf16r(y[6] * rn); u1.w = bf16r(y[7] * rn);
        *(ushort4*)(fnb + row * D_ + c0) = u0;
        *(ushort4*)(fnb + row * D_ + c1) = u1;
    }
    const float* tp = temb + (long)b * D_;
    float4 t0 = *(const float4*)(tp + c0), t1 = *(const float4*)(tp + c1);
    float tt[8] = { t0.x, t0.y, t0.z, t0.w, t1.x, t1.y, t1.z, t1.w };
    float rl = 0.f;
    #pragma unroll
    for (int i = 0; i < 8; i++) rl = fmaf(y[i], tt[i], rl);
    rl = wred_sum(rl);
    if (lane == 0) { rnorm[row] = rn; rel[row] = rl; }
}

// ------------------------------------------------- sliding-window cosine pruning via MFMA band
__global__ __launch_bounds__(256) void k_simg(const unsigned short* __restrict__ fnb,
                                              const unsigned char* __restrict__ vld,
                                              int* __restrict__ keep) {
    int wid = threadIdx.x >> 6, lane = threadIdx.x & 63;
    int T = (blockIdx.x * 4 + wid) * 32;
    int r32 = lane & 31, kg = lane >> 5;
    int prevok = (T & (N_ - 1)) != 0;
    const unsigned short* arow  = fnb + (long)(T + r32) * D_ + kg * 8;
    const unsigned short* b0row = fnb + (long)((prevok ? T - 32 : T) + r32) * D_ + kg * 8;

    f32x16 g0, g1;
    #pragma unroll
    for (int r = 0; r < 16; r++) { g0[r] = 0.f; g1[r] = 0.f; }
    #pragma unroll 4
    for (int kt = 0; kt < D_; kt += 16) {
        bf16x8 a  = *(const bf16x8*)(arow + kt);
        bf16x8 b0 = *(const bf16x8*)(b0row + kt);
        g0 = __builtin_amdgcn_mfma_f32_32x32x16_bf16(a, b0, g0, 0, 0, 0);
        g1 = __builtin_amdgcn_mfma_f32_32x32x16_bf16(a, a,  g1, 0, 0, 0);
    }
    int okc0 = prevok ? (int)vld[T - 32 + r32] : 0;
    int okc1 = (int)vld[T + r32];
    float ms[16];
    #pragma unroll
    for (int r = 0; r < 16; r++) {
        int i = (r & 3) + 8 * (r >> 2) + 4 * kg;
        float v = -INFINITY;
        if (okc0 && r32 >= i) v = g0[r];
        if (okc1 && r32 < i)  v = fmaxf(v, g1[r]);
        #pragma unroll
        for (int d = 1; d < 32; d <<= 1) v = fmaxf(v, __shfl_xor(v, d, 64));
        ms[r] = v;
    }
    if (r32 == 0) {
        #pragma unroll
        for (int r = 0; r < 16; r++) {
            int i = (r & 3) + 8 * (r >> 2) + 4 * kg;
            int t = T + i;
            keep[t] = (vld[t] && ms[r] < 0.7f) ? 1 : 0;
        }
    }
}

// ------------------------------------------------- fallback sliding-window (no fnb space)
#define CHUNK 28
#define KROWS 60
__global__ __launch_bounds__(256) void k_sim(const float* img, const float* rnorm,
                                             const unsigned char* vld, int* keep) {
    __shared__ __hip_bfloat16 fnbs[KROWS][D_];
    long c0 = (long)blockIdx.x * CHUNK;
    int tid = threadIdx.x;
    for (int idx = tid; idx < KROWS * (D_ / 8); idx += 256) {
        int rr = idx / (D_ / 8);
        int cc = (idx % (D_ / 8)) * 8;
        long grow = c0 - WIN_ + rr;
        if (grow < 0) grow = 0;
        if (grow >= NTOK_) grow = NTOK_ - 1;
        float rn = rnorm[grow];
        const float* p = img + grow * (long)D_ + cc;
        float4 u = *(const float4*)p, w = *(const float4*)(p + 4);
        fnbs[rr][cc + 0] = __float2bfloat16(u.x * rn);
        fnbs[rr][cc + 1] = __float2bfloat16(u.y * rn);
        fnbs[rr][cc + 2] = __float2bfloat16(u.z * rn);
        fnbs[rr][cc + 3] = __float2bfloat16(u.w * rn);
        fnbs[rr][cc + 4] = __float2bfloat16(w.x * rn);
        fnbs[rr][cc + 5] = __float2bfloat16(w.y * rn);
        fnbs[rr][cc + 6] = __float2bfloat16(w.z * rn);
        fnbs[rr][cc + 7] = __float2bfloat16(w.w * rn);
    }
    __syncthreads();
    int wid = tid >> 6, lane = tid & 63;
    for (int ti = 0; ti < 7; ti++) {
        int tloc = wid * 7 + ti;
        long t = c0 + tloc;
        if (t >= NTOK_) continue;
        int lr = WIN_ + tloc;
        int tl = (int)(t & (N_ - 1));
        float a[8];
        bf8_to_f32(*(const uint4*)&fnbs[lr][lane * 8], a);
        int wmax = tl < WIN_ ? tl : WIN_;
        float msim = -INFINITY;
        for (int w = 1; w <= wmax; w++) {
            if (!vld[t - w]) continue;
            float bvv[8];
            bf8_to_f32(*(const uint4*)&fnbs[lr - w][lane * 8], bvv);
            float p = 0.f;
            #pragma unroll
            for (int i = 0; i < 8; i++) p = fmaf(a[i], bvv[i], p);
            p = wred_sum(p);
            msim = fmaxf(msim, p);
        }
        int kp = (vld[t] && (msim < 0.7f)) ? 1 : 0;
        if (lane == 0) keep[t] = kp;
    }
}

// ------------------------------------------------- per-batch exact top-k (radix select)
static __device__ void scan1024(int* tot, int tid) {
    if (tid < 64) {
        int vals[16], s = 0;
        #pragma unroll
        for (int i = 0; i < 16; i++) vals[i] = tot[tid * 16 + i];
        #pragma unroll
        for (int i = 0; i < 16; i++) { int t = vals[i]; vals[i] = s; s += t; }
        int inc = s;
        #pragma unroll
        for (int d = 1; d < 64; d <<= 1) {
            int v = __shfl_up(inc, d, 64);
            if ((tid & 63) >= d) inc += v;
        }
        int excl = inc - s;
        #pragma unroll
        for (int i = 0; i < 16; i++) tot[tid * 16 + i] = vals[i] + excl;
    }
}

__global__ __launch_bounds__(1024) void k_topk(const float* rel, const int* keep, int* idxo) {
    int b = blockIdx.x, tid = threadIdx.x;
    const float* relb = rel + (long)b * N_;
    const int* keepb  = keep + (long)b * N_;
    __shared__ unsigned int hist[256];
    __shared__ int toti[1024];
    __shared__ unsigned int s_prefix;
    __shared__ int s_rem, s_k;

    unsigned int key[16];
    int base = tid * 16, nk_local = 0;
    #pragma unroll
    for (int j = 0; j < 16; j++) {
        int i = base + j;
        float r = relb[i];
        int kp = keepb[i];
        unsigned int bits = __float_as_uint(r);
        unsigned int kk = (bits & 0x80000000u) ? ~bits : (bits | 0x80000000u);
        key[j] = kp ? kk : 0u;
        nk_local += kp;
    }
    toti[tid] = nk_local; __syncthreads();
    for (int o = 512; o > 0; o >>= 1) { if (tid < o) toti[tid] += toti[tid + o]; __syncthreads(); }
    if (tid == 0) {
        int n_kept = toti[0];
        int k = (int)(0.8f * (float)n_kept);
        if (k < 1) k = 1; if (k > LMAX_) k = LMAX_;
        s_k = k; s_rem = k; s_prefix = 0u;
    }
    __syncthreads();

    for (int pass = 0; pass < 4; pass++) {
        int shift = 24 - pass * 8;
        unsigned int himask = (pass == 0) ? 0u : (0xFFFFFFFFu << (shift + 8));
        if (tid < 256) hist[tid] = 0u;
        __syncthreads();
        unsigned int pfx = s_prefix;
        #pragma unroll
        for (int j = 0; j < 16; j++) {
            unsigned int kk = key[j];
            if ((kk & himask) == (pfx & himask))
                atomicAdd(&hist[(kk >> shift) & 255], 1u);
        }
        __syncthreads();
        if (tid == 0) {
            int rem = s_rem;
            unsigned int cum = 0;
            for (int d = 255; d >= 0; d--) {
                unsigned int h = hist[d];
                if (cum + h >= (unsigned int)rem) {
                    s_rem = rem - (int)cum;
                    s_prefix = pfx | ((unsigned int)d << shift);
                    break;
                }
                cum += h;
            }
        }
        __syncthreads();
    }
    unsigned int T = s_prefix;
    int tie_need = s_rem, k = s_k;

    int eq[16], gt[16], eqpre[16];
    int locEq = 0;
    #pragma unroll
    for (int j = 0; j < 16; j++) {
        eq[j] = (key[j] == T); gt[j] = (key[j] > T);
        eqpre[j] = locEq; locEq += eq[j];
    }
    toti[tid] = locEq; __syncthreads();
    scan1024(toti, tid); __syncthreads();
    int eqoff = toti[tid];

    int sel[16], spre[16];
    int locS = 0;
    #pragma unroll
    for (int j = 0; j < 16; j++) {
        int rank = eqoff + eqpre[j];
        sel[j] = gt[j] || (eq[j] && rank < tie_need);
        spre[j] = locS; locS += sel[j];
    }
    __syncthreads();
    toti[tid] = locS; __syncthreads();
    scan1024(toti, tid); __syncthreads();
    int soff = toti[tid];
    #pragma unroll
    for (int j = 0; j < 16; j++)
        if (sel[j]) idxo[b * LMAX_ + soff + spre[j]] = base + j;
    for (int p = k + tid; p < LMAX_; p += 1024) idxo[b * LMAX_ + p] = N_;
}

// ------------------------------------------------- feat2 gather + pair pooling
__global__ void k_feat3(const float* img, const int* idxo, float* f3) {
    int bm = blockIdx.x;
    int b = bm >> 9, m = bm & 511;
    int i0 = idxo[b * LMAX_ + 2 * m], i1 = idxo[b * LMAX_ + 2 * m + 1];
    int c0 = i0 < N_, c1 = i1 < N_;
    float dn = 1.0f / fmaxf((float)(c0 + c1), 1.0f);
    const float* p0 = img + ((long)b * N_ + (c0 ? i0 : 0)) * D_;
    const float* p1 = img + ((long)b * N_ + (c1 ? i1 : 0)) * D_;
    int d = threadIdx.x * 4;
    float4 v0 = c0 ? *(const float4*)(p0 + d) : make_float4(0.f, 0.f, 0.f, 0.f);
    float4 v1 = c1 ? *(const float4*)(p1 + d) : make_float4(0.f, 0.f, 0.f, 0.f);
    float4 o;
    o.x = (v0.x + v1.x) * dn; o.y = (v0.y + v1.y) * dn;
    o.z = (v0.z + v1.z) * dn; o.w = (v0.w + v1.w) * dn;
    *(float4*)(f3 + (long)bm * D_ + d) = o;
}

// ------------------------------------------------- tiled f32 GEMM (small k/v projections)
#define BM 128
#define BN 64
#define BK 32
#define ASTR 136
__global__ __launch_bounds__(256) void k_gemm(const float* __restrict__ A, int lda,
                                              const float* __restrict__ Bw, int ldb,
                                              const float* __restrict__ bias,
                                              float* __restrict__ C, int ldc, int K) {
    __shared__ float As[BK][ASTR];
    __shared__ float Bsf[BK][BN];
    int bm = blockIdx.x, bn = blockIdx.y;
    int tid = threadIdx.x;
    int trow = tid >> 4, tcol = tid & 15;
    float acc[8][4] = {};
    const float* Ab = A + (long)bm * BM * lda;
    const float* Bb = Bw + bn * BN;
    for (int kt = 0; kt < K; kt += BK) {
        #pragma unroll
        for (int i = 0; i < 4; i++) {
            int f = tid + 256 * i;
            int row = f >> 3, c4 = (f & 7) << 2;
            float4 v = *(const float4*)(Ab + (long)row * lda + kt + c4);
            As[c4 + 0][row] = v.x; As[c4 + 1][row] = v.y;
            As[c4 + 2][row] = v.z; As[c4 + 3][row] = v.w;
        }
        #pragma unroll
        for (int i = 0; i < 2; i++) {
            int f = tid + 256 * i;
            int row = f >> 4, c4 = (f & 15) << 2;
            *(float4*)&Bsf[row][c4] = *(const float4*)(Bb + (long)(kt + row) * ldb + c4);
        }
        __syncthreads();
        #pragma unroll 8
        for (int kk = 0; kk < BK; kk++) {
            float a[8], bv[4];
            #pragma unroll
            for (int i = 0; i < 8; i++) a[i] = As[kk][trow * 8 + i];
            #pragma unroll
            for (int j = 0; j < 4; j++) bv[j] = Bsf[kk][tcol * 4 + j];
            #pragma unroll
            for (int i = 0; i < 8; i++)
                #pragma unroll
                for (int j = 0; j < 4; j++)
                    acc[i][j] = fmaf(a[i], bv[j], acc[i][j]);
        }
        __syncthreads();
    }
    int c = bn * BN + tcol * 4;
    #pragma unroll
    for (int i = 0; i < 8; i++) {
        long r = (long)bm * BM + trow * 8 + i;
        float4 v;
        v.x = acc[i][0] + bias[c + 0]; v.y = acc[i][1] + bias[c + 1];
        v.z = acc[i][2] + bias[c + 2]; v.w = acc[i][3] + bias[c + 3];
        *(float4*)(C + r * ldc + c) = v;
    }
}

// ------------------------------------------------- cross-modal attention
__global__ __launch_bounds__(512) void k_attn(const float* qv, const float* kk,
                                              const float* vv, float* ctx) {
    int bh = blockIdx.x;
    int b = bh >> 3, h = bh & 7;
    __shared__ float qs[DH_];
    __shared__ float sc[M2_];
    __shared__ float red[M2_];
    int m = threadIdx.x;
    if (m < DH_) qs[m] = qv[b * D_ + h * DH_ + m];
    __syncthreads();
    const float* kp = kk + (long)b * M2_ * D_ + h * DH_;
    float acc = 0.f;
    #pragma unroll
    for (int d = 0; d < DH_; d += 4) {
        float4 kv = *(const float4*)(kp + (long)m * D_ + d);
        acc += qs[d] * kv.x + qs[d + 1] * kv.y + qs[d + 2] * kv.z + qs[d + 3] * kv.w;
    }
    acc *= 0.125f;
    red[m] = acc; __syncthreads();
    for (int o = 256; o > 0; o >>= 1) { if (m < o) red[m] = fmaxf(red[m], red[m + o]); __syncthreads(); }
    float mx = red[0]; __syncthreads();
    float e = expf(acc - mx);
    sc[m] = e; red[m] = e; __syncthreads();
    for (int o = 256; o > 0; o >>= 1) { if (m < o) red[m] += red[m + o]; __syncthreads(); }
    float inv = 1.0f / red[0];
    if (m < DH_) {
        float a2 = 0.f;
        const float* vp = vv + (long)b * M2_ * D_ + h * DH_ + m;
        for (int mm = 0; mm < M2_; mm++) a2 = fmaf(sc[mm], vp[(long)mm * D_], a2);
        ctx[b * D_ + h * DH_ + m] = a2 * inv;
    }
}

// ------------------------------------------------- output head (Wo then W_cls), f32 out
__global__ __launch_bounds__(512) void k_head(const float* ctx, const float* Wo, const float* bo,
                                              const float* Wc, const float* bc,
                                              float* out) {
    int b = blockIdx.x, d = threadIdx.x;
    __shared__ float cl[D_], ol[D_];
    cl[d] = ctx[b * D_ + d]; __syncthreads();
    float acc = bo[d];
    for (int e = 0; e < D_; e++) acc = fmaf(cl[e], Wo[(long)e * D_ + d], acc);
    ol[d] = acc; __syncthreads();
    if (d < 4) {
        float a2 = bc[d];
        for (int e = 0; e < D_; e++) a2 = fmaf(ol[e], Wc[e * 4 + d], a2);
        out[b * 4 + d] = a2;
    }
}

// ---------------------------------------------------------------- launcher
extern "C" void kernel_launch(void* const* d_in, const int* in_sizes, int n_in,
                              void* d_out, int out_size, void* d_ws, size_t ws_size,
                              hipStream_t stream) {
    const float* bags = (const float*)d_in[0];
    const void*  kpm  = d_in[1];
    const int*   ids  = (const int*)d_in[2];
    const int*   am   = (const int*)d_in[3];
    const float* emb  = (const float*)d_in[4];
    const float* Wtp  = (const float*)d_in[5];
    const float* btp  = (const float*)d_in[6];
    const float* Wen  = (const float*)d_in[7];
    const float* ben  = (const float*)d_in[8];
    const float* lng  = (const float*)d_in[9];
    const float* lnb  = (const float*)d_in[10];
    const float* Wq   = (const float*)d_in[11];
    const float* bq   = (const float*)d_in[12];
    const float* Wk   = (const float*)d_in[13];
    const float* bk   = (const float*)d_in[14];
    const float* Wv   = (const float*)d_in[15];
    const float* bv   = (const float*)d_in[16];
    const float* Wo   = (const float*)d_in[17];
    const float* bo   = (const float*)d_in[18];
    const float* Wc   = (const float*)d_in[19];
    const float* bc   = (const float*)d_in[20];

    char* ws = (char*)d_ws;
    size_t o = 0;
    auto alloc = [&](size_t bytes) -> void* {
        void* p = ws + o; o += (bytes + 255) & ~(size_t)255; return p;
    };
    float* img  = (float*)alloc((size_t)NTOK_ * D_ * 4);
    float* rno  = (float*)alloc((size_t)NTOK_ * 4);
    float* rel  = (float*)alloc((size_t)NTOK_ * 4);
    int*   keep = (int*)alloc((size_t)NTOK_ * 4);
    unsigned char* vld = (unsigned char*)alloc(NTOK_);
    float* tf   = (float*)alloc(B_ * 768 * 4);
    float* te   = (float*)alloc(B_ * D_ * 4);
    float* qv   = (float*)alloc(B_ * D_ * 4);
    int*   idxo = (int*)alloc(B_ * LMAX_ * 4);
    float* f3   = (float*)alloc((size_t)B_ * M2_ * D_ * 4);
    float* kkb  = (float*)alloc((size_t)B_ * M2_ * D_ * 4);
    float* vvb  = (float*)alloc((size_t)B_ * M2_ * D_ * 4);
    float* ctx  = (float*)alloc(B_ * D_ * 4);
    int*   flag = (int*)alloc(256);
    unsigned short* bth = (unsigned short*)alloc((size_t)D_ * F_ * 2);
    unsigned short* btl = (unsigned short*)alloc((size_t)D_ * F_ * 2);

    // new path: A split planes (512 MiB). fnb aliases a_hi (dead after GEMM).
    size_t aplanes = (size_t)NTOK_ * F_ * 2;       // 256 MiB each
    bool newpath = (ws_size > o) && ((ws_size - o) >= 2 * aplanes + 4096);
    unsigned short* a_hi = nullptr;
    unsigned short* a_lo = nullptr;
    unsigned short* fnb  = nullptr;
    if (newpath) {
        a_hi = (unsigned short*)alloc(aplanes);
        a_lo = (unsigned short*)alloc(aplanes);
        fnb  = a_hi;                               // alias: k_ln runs after k_gemm2
    } else {
        size_t need = (size_t)NTOK_ * D_ * 2 + 1024;
        if (ws_size > o && (ws_size - o) >= need)
            fnb = (unsigned short*)alloc((size_t)NTOK_ * D_ * 2);
    }

    hipMemsetAsync(flag, 0, 4, stream);
    k_detect<<<64, 256, 0, stream>>>((const unsigned char*)kpm, NTOK_, flag);
    k_valid<<<(NTOK_ + 255) / 256, 256, 0, stream>>>(kpm, flag, vld);
    k_text_feat<<<B_, 256, 0, stream>>>(emb, ids, am, tf);
    k_rowmm<<<B_, 512, 0, stream>>>(tf, Wtp, btp, te, 768, 512);
    k_rowmm<<<B_, 512, 0, stream>>>(te, Wq, bq, qv, 512, 512);

    dim3 gsplit(F_ / 32, D_ / 32);
    if (newpath) {
        k_bsplit_sw<<<gsplit, 256, 0, stream>>>(Wen, bth, btl);
        k_asplit<<<4096, 256, 0, stream>>>(bags, a_hi, a_lo);
        k_gemm2<<<4096, 256, 0, stream>>>(a_hi, a_lo, bth, btl, ben, img);
    } else {
        k_bsplit<<<gsplit, 256, 0, stream>>>(Wen, bth, btl);
        dim3 g3(NTOK_ / 64, 2);
        k_gemm_mfma<<<g3, 256, 0, stream>>>(bags, bth, btl, ben, img);
    }

    k_ln<<<NTOK_ / 4, 256, 0, stream>>>(img, lng, lnb, te, rno, rel, fnb);
    if (fnb) k_simg<<<NTOK_ / 128, 256, 0, stream>>>(fnb, vld, keep);
    else     k_sim<<<(NTOK_ + CHUNK - 1) / CHUNK, 256, 0, stream>>>(img, rno, vld, keep);
    k_topk<<<B_, 1024, 0, stream>>>(rel, keep, idxo);
    k_feat3<<<B_ * M2_, 128, 0, stream>>>(img, idxo, f3);

    dim3 g8(B_ * M2_ / BM, D_ / BN);
    k_gemm<<<g8, 256, 0, stream>>>(f3, D_, Wk, D_, bk, kkb, D_, D_);
    k_gemm<<<g8, 256, 0, stream>>>(f3, D_, Wv, D_, bv, vvb, D_, D_);

    k_attn<<<B_ * H_, 512, 0, stream>>>(qv, kkb, vvb, ctx);
    k_head<<<B_, 512, 0, stream>>>(ctx, Wo, bo, Wc, bc, (float*)d_out);
}

// Round 8
// 941.408 us; speedup vs baseline: 3.6277x; 1.3160x over previous
//
#include <hip/hip_runtime.h>
#include <hip/hip_bf16.h>
#include <math.h>
#include <stdint.h>

#define B_    8
#define N_    16384
#define F_    1024
#define D_    512
#define S_    64
#define H_    8
#define DH_   64
#define LMAX_ 1024
#define M2_   512
#define WIN_  32
#define NTOK_ (B_ * N_)   // 131072

typedef __attribute__((ext_vector_type(8)))  short bf16x8;
typedef __attribute__((ext_vector_type(16))) float f32x16;

// quad-swizzle (16B units) keyed by row low bits: B planes use 2-bit, A uses 3-bit
#define S_OF(r) (((r) >> 1) & 3)

// ---------------------------------------------------------------- utilities
static __device__ __forceinline__ float wred_sum(float v) {
    #pragma unroll
    for (int d = 1; d < 64; d <<= 1) v += __shfl_xor(v, d, 64);
    return v;
}

static __device__ __forceinline__ void bf8_to_f32(uint4 q, float* a) {
    a[0] = __uint_as_float(q.x << 16); a[1] = __uint_as_float(q.x & 0xffff0000u);
    a[2] = __uint_as_float(q.y << 16); a[3] = __uint_as_float(q.y & 0xffff0000u);
    a[4] = __uint_as_float(q.z << 16); a[5] = __uint_as_float(q.z & 0xffff0000u);
    a[6] = __uint_as_float(q.w << 16); a[7] = __uint_as_float(q.w & 0xffff0000u);
}

static __device__ __forceinline__ unsigned short bf16r(float x) {   // RNE f32->bf16
    unsigned int b = __float_as_uint(x);
    return (unsigned short)((b + 0x7FFFu + ((b >> 16) & 1u)) >> 16);
}

static __device__ __forceinline__ void split_bf(float x, unsigned short& h, unsigned short& l) {
    unsigned int b = __float_as_uint(x);
    unsigned int hb = (b + 0x7FFFu + ((b >> 16) & 1u)) >> 16;
    h = (unsigned short)hb;
    float r = x - __uint_as_float(hb << 16);
    l = bf16r(r);
}

// cheap truncation split of 8 f32 -> hi/lo bf16x8 (in-register, ~4 VALU/value)
static __device__ __forceinline__ void split8(float4 f0, float4 f1, bf16x8& hi, bf16x8& lo) {
    float xs[8] = { f0.x, f0.y, f0.z, f0.w, f1.x, f1.y, f1.z, f1.w };
    unsigned int hp[4], lp[4];
    #pragma unroll
    for (int i = 0; i < 4; i++) {
        unsigned int b0 = __float_as_uint(xs[2*i]), b1 = __float_as_uint(xs[2*i+1]);
        hp[i] = (b0 >> 16) | (b1 & 0xffff0000u);
        float r0 = xs[2*i]   - __uint_as_float(b0 & 0xffff0000u);
        float r1 = xs[2*i+1] - __uint_as_float(b1 & 0xffff0000u);
        lp[i] = (__float_as_uint(r0) >> 16) | (__float_as_uint(r1) & 0xffff0000u);
    }
    union { uint4 u; bf16x8 v; } a, c;
    a.u = make_uint4(hp[0], hp[1], hp[2], hp[3]);
    c.u = make_uint4(lp[0], lp[1], lp[2], lp[3]);
    hi = a.v; lo = c.v;
}

static __device__ __forceinline__ void gll16(const void* g, void* l) {
    __builtin_amdgcn_global_load_lds(
        (const __attribute__((address_space(1))) unsigned int*)g,
        (__attribute__((address_space(3))) unsigned int*)l, 16, 0, 0);
}

// ------------------------------------------------- mask layout detection
__global__ void k_detect(const unsigned char* mb, int nbytes, int* flag) {
    int found = 0;
    for (int i = blockIdx.x * blockDim.x + threadIdx.x; i < nbytes; i += gridDim.x * blockDim.x)
        if ((i & 3) && mb[i]) found = 1;
    if (found) atomicOr(flag, 1);
}

__global__ void k_valid(const void* maskp, const int* flag, unsigned char* v) {
    int i = blockIdx.x * 256 + threadIdx.x;
    if (i >= NTOK_) return;
    int pad;
    if (*flag) pad = (((const unsigned char*)maskp)[i] != 0);
    else       pad = (((const int*)maskp)[i] != 0);
    v[i] = pad ? 0 : 1;
}

// ------------------------------------------------- text feature (masked mean)
__global__ void k_text_feat(const float* emb, const int* ids, const int* am, float* tf) {
    int b = blockIdx.x;
    __shared__ int   sid[S_];
    __shared__ float sam[S_];
    int t = threadIdx.x;
    if (t < S_) { sid[t] = ids[b * S_ + t]; sam[t] = (float)am[b * S_ + t]; }
    __syncthreads();
    float asum = 0.f;
    for (int s = 0; s < S_; s++) asum += sam[s];
    float denom = fmaxf(asum, 1.0f);
    for (int d = t; d < 768; d += blockDim.x) {
        float acc = 0.f;
        for (int s = 0; s < S_; s++) acc += emb[(long)sid[s] * 768 + d] * sam[s];
        tf[b * 768 + d] = acc / denom;
    }
}

__global__ void k_rowmm(const float* in, const float* W, const float* bias,
                        float* out, int E, int Nn) {
    int b = blockIdx.x, d = threadIdx.x;
    __shared__ float sin[768];
    for (int e = d; e < E; e += blockDim.x) sin[e] = in[b * E + e];
    __syncthreads();
    float acc = bias[d];
    for (int e = 0; e < E; e++) acc = fmaf(sin[e], W[(long)e * Nn + d], acc);
    out[b * Nn + d] = acc;
}

// ------------------------------------------------- W_enc transpose + split, swizzled layout
__global__ __launch_bounds__(256) void k_bsplit_sw(const float* __restrict__ W,
                                                   unsigned short* __restrict__ bh,
                                                   unsigned short* __restrict__ bl) {
    __shared__ float tile[32][33];
    int e0 = blockIdx.x * 32;   // k origin
    int d0 = blockIdx.y * 32;   // out-col origin
    int t = threadIdx.x;
    int r = t >> 3, c4 = (t & 7) * 4;
    float4 v = *(const float4*)(W + (long)(e0 + r) * D_ + d0 + c4);
    tile[r][c4] = v.x; tile[r][c4 + 1] = v.y; tile[r][c4 + 2] = v.z; tile[r][c4 + 3] = v.w;
    __syncthreads();
    if (t < 128) {
        int c = t & 31, kq = t >> 5;           // col-in-tile, quad-in-tile (0..3)
        int col = d0 + c;
        float xs[8];
        #pragma unroll
        for (int i = 0; i < 8; i++) xs[i] = tile[kq * 8 + i][c];
        unsigned short h[8], l[8];
        #pragma unroll
        for (int i = 0; i < 8; i++) split_bf(xs[i], h[i], l[i]);
        uint4 ph, pl;
        ph.x = h[0] | ((unsigned)h[1] << 16); ph.y = h[2] | ((unsigned)h[3] << 16);
        ph.z = h[4] | ((unsigned)h[5] << 16); ph.w = h[6] | ((unsigned)h[7] << 16);
        pl.x = l[0] | ((unsigned)l[1] << 16); pl.y = l[2] | ((unsigned)l[3] << 16);
        pl.z = l[4] | ((unsigned)l[5] << 16); pl.w = l[6] | ((unsigned)l[7] << 16);
        int Q = (e0 >> 3) + kq;
        int Qo = (Q & ~3) | ((Q & 3) ^ S_OF(col & 7));
        *(uint4*)(bh + (long)col * 1024 + Qo * 8) = ph;
        *(uint4*)(bl + (long)col * 1024 + Qo * 8) = pl;
    }
}

// ------------------------------------------------- gll GEMM, A staged raw f32 + in-reg split
// Tile 128x128, BK=32, 4 waves, single 32 KB buffer. Waves 0,1 stage A rows 0-63 /
// 64-127 as f32 (global source per-lane XOR'd by row&7, LDS linear — involution with
// the read-side XOR). Waves 2,3 stage pre-split Bh/Bl. Wave w computes quadrant
// (wr,wc) = (w>>1, w&1). 3-term split MFMA: ah*bh + ah*bl + al*bh.
__global__ __launch_bounds__(256) void k_gemm3(const float* __restrict__ A,
                                               const unsigned short* __restrict__ Bh2,
                                               const unsigned short* __restrict__ Bl2,
                                               const float* __restrict__ bias,
                                               float* __restrict__ C) {
    __shared__ __align__(16) float ldsA[128][32];              // 16 KiB
    __shared__ __align__(16) unsigned short ldsB[2][128][32];  // 16 KiB
    int bid = blockIdx.x;
    int wg = (bid & 7) * 512 + (bid >> 3);    // bijective: nwg=4096 % 8 == 0
    int bn = wg & 3, bm = wg >> 2;
    int tid = threadIdx.x;
    int w = tid >> 6, lane = tid & 63;
    int r32 = lane & 31, kg = lane >> 5;
    int wr = w >> 1, wc = w & 1;
    int s8 = r32 & 7;

    const float* agbase = nullptr;
    const unsigned short* bgbase = nullptr;
    if (w < 2) {
        int rl = lane >> 3, qs = lane & 7;              // rl == row&7 for every j
        agbase = A + (long)(bm * 128 + w * 64 + rl) * 1024 + ((qs ^ rl) * 4);
    } else {
        const unsigned short* plane = (w == 2) ? Bh2 : Bl2;
        int lrow = lane >> 2, lq = lane & 3;
        bgbase = plane + (long)(bn * 128 + lrow) * 1024 + lq * 8;
    }

    f32x16 acc[2][2];
    #pragma unroll
    for (int i = 0; i < 2; i++)
        #pragma unroll
        for (int j = 0; j < 2; j++)
            #pragma unroll
            for (int r = 0; r < 16; r++) acc[i][j][r] = 0.f;

    for (int kt = 0; kt < 1024; kt += 32) {
        if (w < 2) {
            #pragma unroll
            for (int j = 0; j < 8; j++)
                gll16(agbase + (long)j * 8 * 1024 + kt, &ldsA[w * 64 + j * 8][0]);
        } else {
            #pragma unroll
            for (int j = 0; j < 8; j++)
                gll16(bgbase + (long)j * 16 * 1024 + kt, &ldsB[w - 2][j * 16][0]);
        }
        __syncthreads();
        #pragma unroll
        for (int k2 = 0; k2 < 2; k2++) {
            int qA = k2 * 4 + kg * 2;                 // f32 quad index (8 quads/row)
            int qs0 = (qA ^ s8) * 4;                  // float offsets
            int qs1 = ((qA + 1) ^ s8) * 4;
            bf16x8 a_h[2], a_l[2];
            #pragma unroll
            for (int rf = 0; rf < 2; rf++) {
                int ar = wr * 64 + rf * 32 + r32;     // ar&7 == s8
                float4 f0 = *(const float4*)&ldsA[ar][qs0];
                float4 f1 = *(const float4*)&ldsA[ar][qs1];
                split8(f0, f1, a_h[rf], a_l[rf]);
            }
            int qb = k2 * 2 + kg;                     // bf16 quad index (4 quads/row)
            bf16x8 b_h[2], b_l[2];
            #pragma unroll
            for (int cf = 0; cf < 2; cf++) {
                int bc = wc * 64 + cf * 32 + r32;     // bc&7 == s8 (low 2 bits used)
                int q = (qb ^ S_OF(r32)) * 8;
                b_h[cf] = *(const bf16x8*)&ldsB[0][bc][q];
                b_l[cf] = *(const bf16x8*)&ldsB[1][bc][q];
            }
            #pragma unroll
            for (int rf = 0; rf < 2; rf++)
                #pragma unroll
                for (int cf = 0; cf < 2; cf++) {
                    acc[rf][cf] = __builtin_amdgcn_mfma_f32_32x32x16_bf16(a_h[rf], b_h[cf], acc[rf][cf], 0, 0, 0);
                    acc[rf][cf] = __builtin_amdgcn_mfma_f32_32x32x16_bf16(a_h[rf], b_l[cf], acc[rf][cf], 0, 0, 0);
                    acc[rf][cf] = __builtin_amdgcn_mfma_f32_32x32x16_bf16(a_l[rf], b_h[cf], acc[rf][cf], 0, 0, 0);
                }
        }
        __syncthreads();
    }
    #pragma unroll
    for (int rf = 0; rf < 2; rf++)
        #pragma unroll
        for (int cf = 0; cf < 2; cf++) {
            int col = bn * 128 + wc * 64 + cf * 32 + r32;
            float bv = bias[col];
            #pragma unroll
            for (int r = 0; r < 16; r++) {
                int row = bm * 128 + wr * 64 + rf * 32 + (r & 3) + 8 * (r >> 2) + 4 * kg;
                C[(long)row * D_ + col] = acc[rf][cf][r] + bv;
            }
        }
}

// ------------------------------------------------- fallback fused split GEMM (round-4)
#define GPAD 40
__global__ __launch_bounds__(256, 3) void k_gemm_mfma(const float* __restrict__ A,
                                                      const unsigned short* __restrict__ Bth,
                                                      const unsigned short* __restrict__ Btl,
                                                      const float* __restrict__ bias,
                                                      float* __restrict__ C) {
    __shared__ __align__(16) unsigned short As[2][64][GPAD];
    __shared__ __align__(16) unsigned short Bs[2][256][GPAD];
    int bm = blockIdx.x, bn = blockIdx.y;
    int tid = threadIdx.x;
    int w = tid >> 6, lane = tid & 63;
    int r32 = lane & 31, kg = lane >> 5;
    f32x16 acc[2][2];
    #pragma unroll
    for (int i = 0; i < 2; i++)
        #pragma unroll
        for (int j = 0; j < 2; j++)
            #pragma unroll
            for (int r = 0; r < 16; r++) acc[i][j][r] = 0.f;
    int arow = tid >> 2, aq = tid & 3;
    const float* abase = A + (long)(bm * 64 + arow) * 1024 + aq * 8;
    const unsigned short* bhbase = Bth + (long)(bn * 256 + tid) * 1024;
    const unsigned short* blbase = Btl + (long)(bn * 256 + tid) * 1024;
    float4 pa0 = *(const float4*)abase;
    float4 pa1 = *(const float4*)(abase + 4);
    for (int kt = 0; kt < 1024; kt += 32) {
        {
            float xs[8] = { pa0.x, pa0.y, pa0.z, pa0.w, pa1.x, pa1.y, pa1.z, pa1.w };
            unsigned short h[8], l[8];
            #pragma unroll
            for (int i = 0; i < 8; i++) split_bf(xs[i], h[i], l[i]);
            uint4 ph, pl;
            ph.x = h[0] | ((unsigned)h[1] << 16); ph.y = h[2] | ((unsigned)h[3] << 16);
            ph.z = h[4] | ((unsigned)h[5] << 16); ph.w = h[6] | ((unsigned)h[7] << 16);
            pl.x = l[0] | ((unsigned)l[1] << 16); pl.y = l[2] | ((unsigned)l[3] << 16);
            pl.z = l[4] | ((unsigned)l[5] << 16); pl.w = l[6] | ((unsigned)l[7] << 16);
            *(uint4*)&As[0][arow][aq * 8] = ph;
            *(uint4*)&As[1][arow][aq * 8] = pl;
        }
        {
            const uint4* ph = (const uint4*)(bhbase + kt);
            const uint4* pl = (const uint4*)(blbase + kt);
            #pragma unroll
            for (int q = 0; q < 4; q++) {
                *(uint4*)&Bs[0][tid][q * 8] = ph[q];
                *(uint4*)&Bs[1][tid][q * 8] = pl[q];
            }
        }
        __syncthreads();
        if (kt + 32 < 1024) {
            const float* ap = abase + kt + 32;
            pa0 = *(const float4*)ap;
            pa1 = *(const float4*)(ap + 4);
        }
        #pragma unroll
        for (int k2 = 0; k2 < 2; k2++) {
            int ko = k2 * 16 + kg * 8;
            bf16x8 ah[2], al[2], bh[2], blv[2];
            #pragma unroll
            for (int rf = 0; rf < 2; rf++) {
                ah[rf] = *(const bf16x8*)&As[0][rf * 32 + r32][ko];
                al[rf] = *(const bf16x8*)&As[1][rf * 32 + r32][ko];
            }
            #pragma unroll
            for (int cf = 0; cf < 2; cf++) {
                bh[cf]  = *(const bf16x8*)&Bs[0][w * 64 + cf * 32 + r32][ko];
                blv[cf] = *(const bf16x8*)&Bs[1][w * 64 + cf * 32 + r32][ko];
            }
            #pragma unroll
            for (int rf = 0; rf < 2; rf++)
                #pragma unroll
                for (int cf = 0; cf < 2; cf++) {
                    acc[rf][cf] = __builtin_amdgcn_mfma_f32_32x32x16_bf16(ah[rf], bh[cf],  acc[rf][cf], 0, 0, 0);
                    acc[rf][cf] = __builtin_amdgcn_mfma_f32_32x32x16_bf16(ah[rf], blv[cf], acc[rf][cf], 0, 0, 0);
                    acc[rf][cf] = __builtin_amdgcn_mfma_f32_32x32x16_bf16(al[rf], bh[cf],  acc[rf][cf], 0, 0, 0);
                }
        }
        __syncthreads();
    }
    #pragma unroll
    for (int rf = 0; rf < 2; rf++)
        #pragma unroll
        for (int cf = 0; cf < 2; cf++) {
            int col = bn * 256 + w * 64 + cf * 32 + r32;
            float bv = bias[col];
            #pragma unroll
            for (int r = 0; r < 16; r++) {
                int row = bm * 64 + rf * 32 + (r & 3) + 8 * (r >> 2) + 4 * kg;
                C[(long)row * D_ + col] = acc[rf][cf][r] + bv;
            }
        }
}

// old unswizzled bsplit (fallback path)
__global__ __launch_bounds__(256) void k_bsplit(const float* __restrict__ W,
                                                unsigned short* __restrict__ bh,
                                                unsigned short* __restrict__ bl) {
    __shared__ float tile[32][33];
    int e0 = blockIdx.x * 32;
    int d0 = blockIdx.y * 32;
    int t = threadIdx.x;
    int r = t >> 3;
    int c = (t & 7) * 4;
    float4 v = *(const float4*)(W + (long)(e0 + r) * D_ + d0 + c);
    tile[r][c] = v.x; tile[r][c + 1] = v.y; tile[r][c + 2] = v.z; tile[r][c + 3] = v.w;
    __syncthreads();
    ushort4 h4, l4;
    unsigned short hh, ll;
    float x0 = tile[c + 0][r], x1 = tile[c + 1][r], x2 = tile[c + 2][r], x3 = tile[c + 3][r];
    split_bf(x0, hh, ll); h4.x = hh; l4.x = ll;
    split_bf(x1, hh, ll); h4.y = hh; l4.y = ll;
    split_bf(x2, hh, ll); h4.z = hh; l4.z = ll;
    split_bf(x3, hh, ll); h4.w = hh; l4.w = ll;
    *(ushort4*)(bh + (long)(d0 + r) * 1024 + e0 + c) = h4;
    *(ushort4*)(bl + (long)(d0 + r) * 1024 + e0 + c) = l4;
}

// ------------------------------------------------- LayerNorm+ReLU + rnorm + rel (+fnb, +stats)
// write_img=0 (newpath): img stays RAW; per-row {mu,inv} stored for k_feat3 recompute.
__global__ __launch_bounds__(256) void k_ln(float* h, const float* g, const float* bb,
                                            const float* temb, float* rnorm, float* rel,
                                            unsigned short* fnb, float2* stats, int write_img) {
    int wid = threadIdx.x >> 6, lane = threadIdx.x & 63;
    long row = (long)blockIdx.x * 4 + wid;
    int b = (int)(row >> 14);
    float* hp = h + row * (long)D_;
    int c0 = lane * 4, c1 = 256 + lane * 4;
    float4 x0 = *(float4*)(hp + c0);
    float4 x1 = *(float4*)(hp + c1);
    float x[8] = { x0.x, x0.y, x0.z, x0.w, x1.x, x1.y, x1.z, x1.w };
    float s = 0.f;
    #pragma unroll
    for (int i = 0; i < 8; i++) s += x[i];
    s = wred_sum(s);
    float mu = s * (1.0f / 512.0f);
    float var = 0.f;
    #pragma unroll
    for (int i = 0; i < 8; i++) { float d = x[i] - mu; var += d * d; }
    var = wred_sum(var) * (1.0f / 512.0f);
    float inv = 1.0f / sqrtf(var + 1e-5f);
    float4 g0 = *(const float4*)(g + c0), g1 = *(const float4*)(g + c1);
    float4 b0 = *(const float4*)(bb + c0), b1 = *(const float4*)(bb + c1);
    float gg[8] = { g0.x, g0.y, g0.z, g0.w, g1.x, g1.y, g1.z, g1.w };
    float bbv[8] = { b0.x, b0.y, b0.z, b0.w, b1.x, b1.y, b1.z, b1.w };
    float y[8], sq = 0.f;
    #pragma unroll
    for (int i = 0; i < 8; i++) {
        y[i] = fmaxf(gg[i] * (x[i] - mu) * inv + bbv[i], 0.0f);
        sq += y[i] * y[i];
    }
    if (write_img) {
        float4 o0 = { y[0], y[1], y[2], y[3] }, o1 = { y[4], y[5], y[6], y[7] };
        *(float4*)(hp + c0) = o0;
        *(float4*)(hp + c1) = o1;
    }
    sq = wred_sum(sq);
    float rn = 1.0f / (sqrtf(sq) + 1e-8f);
    if (fnb) {
        ushort4 u0, u1;
        u0.x = bf16r(y[0] * rn); u0.y = bf16r(y[1] * rn);
        u0.z = bf16r(y[2] * rn); u0.w = bf16r(y[3] * rn);
        u1.x = bf16r(y[4] * rn); u1.y = bf16r(y[5] * rn);
        u1.z = bf16r(y[6] * rn); u1.w = bf16r(y[7] * rn);
        *(ushort4*)(fnb + row * D_ + c0) = u0;
        *(ushort4*)(fnb + row * D_ + c1) = u1;
    }
    const float* tp = temb + (long)b * D_;
    float4 t0 = *(const float4*)(tp + c0), t1 = *(const float4*)(tp + c1);
    float tt[8] = { t0.x, t0.y, t0.z, t0.w, t1.x, t1.y, t1.z, t1.w };
    float rl = 0.f;
    #pragma unroll
    for (int i = 0; i < 8; i++) rl = fmaf(y[i], tt[i], rl);
    rl = wred_sum(rl);
    if (lane == 0) { rnorm[row] = rn; rel[row] = rl; stats[row] = make_float2(mu, inv); }
}

// ------------------------------------------------- sliding-window cosine pruning via MFMA band
__global__ __launch_bounds__(256) void k_simg(const unsigned short* __restrict__ fnb,
                                              const unsigned char* __restrict__ vld,
                                              int* __restrict__ keep) {
    int wid = threadIdx.x >> 6, lane = threadIdx.x & 63;
    int T = (blockIdx.x * 4 + wid) * 32;
    int r32 = lane & 31, kg = lane >> 5;
    int prevok = (T & (N_ - 1)) != 0;
    const unsigned short* arow  = fnb + (long)(T + r32) * D_ + kg * 8;
    const unsigned short* b0row = fnb + (long)((prevok ? T - 32 : T) + r32) * D_ + kg * 8;

    f32x16 g0, g1;
    #pragma unroll
    for (int r = 0; r < 16; r++) { g0[r] = 0.f; g1[r] = 0.f; }
    #pragma unroll 4
    for (int kt = 0; kt < D_; kt += 16) {
        bf16x8 a  = *(const bf16x8*)(arow + kt);
        bf16x8 b0 = *(const bf16x8*)(b0row + kt);
        g0 = __builtin_amdgcn_mfma_f32_32x32x16_bf16(a, b0, g0, 0, 0, 0);
        g1 = __builtin_amdgcn_mfma_f32_32x32x16_bf16(a, a,  g1, 0, 0, 0);
    }
    int okc0 = prevok ? (int)vld[T - 32 + r32] : 0;
    int okc1 = (int)vld[T + r32];
    float ms[16];
    #pragma unroll
    for (int r = 0; r < 16; r++) {
        int i = (r & 3) + 8 * (r >> 2) + 4 * kg;
        float v = -INFINITY;
        if (okc0 && r32 >= i) v = g0[r];
        if (okc1 && r32 < i)  v = fmaxf(v, g1[r]);
        #pragma unroll
        for (int d = 1; d < 32; d <<= 1) v = fmaxf(v, __shfl_xor(v, d, 64));
        ms[r] = v;
    }
    if (r32 == 0) {
        #pragma unroll
        for (int r = 0; r < 16; r++) {
            int i = (r & 3) + 8 * (r >> 2) + 4 * kg;
            int t = T + i;
            keep[t] = (vld[t] && ms[r] < 0.7f) ? 1 : 0;
        }
    }
}

// ------------------------------------------------- fallback sliding-window (no fnb space)
#define CHUNK 28
#define KROWS 60
__global__ __launch_bounds__(256) void k_sim(const float* img, const float* rnorm,
                                             const unsigned char* vld, int* keep) {
    __shared__ __hip_bfloat16 fnbs[KROWS][D_];
    long c0 = (long)blockIdx.x * CHUNK;
    int tid = threadIdx.x;
    for (int idx = tid; idx < KROWS * (D_ / 8); idx += 256) {
        int rr = idx / (D_ / 8);
        int cc = (idx % (D_ / 8)) * 8;
        long grow = c0 - WIN_ + rr;
        if (grow < 0) grow = 0;
        if (grow >= NTOK_) grow = NTOK_ - 1;
        float rn = rnorm[grow];
        const float* p = img + grow * (long)D_ + cc;
        float4 u = *(const float4*)p, w = *(const float4*)(p + 4);
        fnbs[rr][cc + 0] = __float2bfloat16(u.x * rn);
        fnbs[rr][cc + 1] = __float2bfloat16(u.y * rn);
        fnbs[rr][cc + 2] = __float2bfloat16(u.z * rn);
        fnbs[rr][cc + 3] = __float2bfloat16(u.w * rn);
        fnbs[rr][cc + 4] = __float2bfloat16(w.x * rn);
        fnbs[rr][cc + 5] = __float2bfloat16(w.y * rn);
        fnbs[rr][cc + 6] = __float2bfloat16(w.z * rn);
        fnbs[rr][cc + 7] = __float2bfloat16(w.w * rn);
    }
    __syncthreads();
    int wid = tid >> 6, lane = tid & 63;
    for (int ti = 0; ti < 7; ti++) {
        int tloc = wid * 7 + ti;
        long t = c0 + tloc;
        if (t >= NTOK_) continue;
        int lr = WIN_ + tloc;
        int tl = (int)(t & (N_ - 1));
        float a[8];
        bf8_to_f32(*(const uint4*)&fnbs[lr][lane * 8], a);
        int wmax = tl < WIN_ ? tl : WIN_;
        float msim = -INFINITY;
        for (int w = 1; w <= wmax; w++) {
            if (!vld[t - w]) continue;
            float bvv[8];
            bf8_to_f32(*(const uint4*)&fnbs[lr - w][lane * 8], bvv);
            float p = 0.f;
            #pragma unroll
            for (int i = 0; i < 8; i++) p = fmaf(a[i], bvv[i], p);
            p = wred_sum(p);
            msim = fmaxf(msim, p);
        }
        int kp = (vld[t] && (msim < 0.7f)) ? 1 : 0;
        if (lane == 0) keep[t] = kp;
    }
}

// ------------------------------------------------- per-batch exact top-k (radix select)
static __device__ void scan1024(int* tot, int tid) {
    if (tid < 64) {
        int vals[16], s = 0;
        #pragma unroll
        for (int i = 0; i < 16; i++) vals[i] = tot[tid * 16 + i];
        #pragma unroll
        for (int i = 0; i < 16; i++) { int t = vals[i]; vals[i] = s; s += t; }
        int inc = s;
        #pragma unroll
        for (int d = 1; d < 64; d <<= 1) {
            int v = __shfl_up(inc, d, 64);
            if ((tid & 63) >= d) inc += v;
        }
        int excl = inc - s;
        #pragma unroll
        for (int i = 0; i < 16; i++) tot[tid * 16 + i] = vals[i] + excl;
    }
}

__global__ __launch_bounds__(1024) void k_topk(const float* rel, const int* keep, int* idxo) {
    int b = blockIdx.x, tid = threadIdx.x;
    const float* relb = rel + (long)b * N_;
    const int* keepb  = keep + (long)b * N_;
    __shared__ unsigned int hist[256];
    __shared__ int toti[1024];
    __shared__ unsigned int s_prefix;
    __shared__ int s_rem, s_k;

    unsigned int key[16];
    int base = tid * 16, nk_local = 0;
    #pragma unroll
    for (int j = 0; j < 16; j++) {
        int i = base + j;
        float r = relb[i];
        int kp = keepb[i];
        unsigned int bits = __float_as_uint(r);
        unsigned int kk = (bits & 0x80000000u) ? ~bits : (bits | 0x80000000u);
        key[j] = kp ? kk : 0u;
        nk_local += kp;
    }
    toti[tid] = nk_local; __syncthreads();
    for (int o = 512; o > 0; o >>= 1) { if (tid < o) toti[tid] += toti[tid + o]; __syncthreads(); }
    if (tid == 0) {
        int n_kept = toti[0];
        int k = (int)(0.8f * (float)n_kept);
        if (k < 1) k = 1; if (k > LMAX_) k = LMAX_;
        s_k = k; s_rem = k; s_prefix = 0u;
    }
    __syncthreads();

    for (int pass = 0; pass < 4; pass++) {
        int shift = 24 - pass * 8;
        unsigned int himask = (pass == 0) ? 0u : (0xFFFFFFFFu << (shift + 8));
        if (tid < 256) hist[tid] = 0u;
        __syncthreads();
        unsigned int pfx = s_prefix;
        #pragma unroll
        for (int j = 0; j < 16; j++) {
            unsigned int kk = key[j];
            if ((kk & himask) == (pfx & himask))
                atomicAdd(&hist[(kk >> shift) & 255], 1u);
        }
        __syncthreads();
        if (tid == 0) {
            int rem = s_rem;
            unsigned int cum = 0;
            for (int d = 255; d >= 0; d--) {
                unsigned int h = hist[d];
                if (cum + h >= (unsigned int)rem) {
                    s_rem = rem - (int)cum;
                    s_prefix = pfx | ((unsigned int)d << shift);
                    break;
                }
                cum += h;
            }
        }
        __syncthreads();
    }
    unsigned int T = s_prefix;
    int tie_need = s_rem, k = s_k;

    int eq[16], gt[16], eqpre[16];
    int locEq = 0;
    #pragma unroll
    for (int j = 0; j < 16; j++) {
        eq[j] = (key[j] == T); gt[j] = (key[j] > T);
        eqpre[j] = locEq; locEq += eq[j];
    }
    toti[tid] = locEq; __syncthreads();
    scan1024(toti, tid); __syncthreads();
    int eqoff = toti[tid];

    int sel[16], spre[16];
    int locS = 0;
    #pragma unroll
    for (int j = 0; j < 16; j++) {
        int rank = eqoff + eqpre[j];
        sel[j] = gt[j] || (eq[j] && rank < tie_need);
        spre[j] = locS; locS += sel[j];
    }
    __syncthreads();
    toti[tid] = locS; __syncthreads();
    scan1024(toti, tid); __syncthreads();
    int soff = toti[tid];
    #pragma unroll
    for (int j = 0; j < 16; j++)
        if (sel[j]) idxo[b * LMAX_ + soff + spre[j]] = base + j;
    for (int p = k + tid; p < LMAX_; p += 1024) idxo[b * LMAX_ + p] = N_;
}

// ------------------------------------------------- feat2 gather + pair pooling
// recompute=1: img holds RAW h; apply LN+ReLU on the fly using stats {mu,inv}.
__global__ void k_feat3(const float* img, const float2* stats, const float* lng,
                        const float* lnb, const int* idxo, float* f3, int recompute) {
    int bm = blockIdx.x;
    int b = bm >> 9, m = bm & 511;
    int i0 = idxo[b * LMAX_ + 2 * m], i1 = idxo[b * LMAX_ + 2 * m + 1];
    int c0 = i0 < N_, c1 = i1 < N_;
    float dn = 1.0f / fmaxf((float)(c0 + c1), 1.0f);
    long r0 = (long)b * N_ + (c0 ? i0 : 0);
    long r1 = (long)b * N_ + (c1 ? i1 : 0);
    int d = threadIdx.x * 4;
    float4 v0 = c0 ? *(const float4*)(img + r0 * D_ + d) : make_float4(0.f, 0.f, 0.f, 0.f);
    float4 v1 = c1 ? *(const float4*)(img + r1 * D_ + d) : make_float4(0.f, 0.f, 0.f, 0.f);
    if (recompute) {
        float4 g4 = *(const float4*)(lng + d);
        float4 b4 = *(const float4*)(lnb + d);
        if (c0) {
            float2 st = stats[r0];
            v0.x = fmaxf(g4.x * (v0.x - st.x) * st.y + b4.x, 0.0f);
            v0.y = fmaxf(g4.y * (v0.y - st.x) * st.y + b4.y, 0.0f);
            v0.z = fmaxf(g4.z * (v0.z - st.x) * st.y + b4.z, 0.0f);
            v0.w = fmaxf(g4.w * (v0.w - st.x) * st.y + b4.w, 0.0f);
        }
        if (c1) {
            float2 st = stats[r1];
            v1.x = fmaxf(g4.x * (v1.x - st.x) * st.y + b4.x, 0.0f);
            v1.y = fmaxf(g4.y * (v1.y - st.x) * st.y + b4.y, 0.0f);
            v1.z = fmaxf(g4.z * (v1.z - st.x) * st.y + b4.z, 0.0f);
            v1.w = fmaxf(g4.w * (v1.w - st.x) * st.y + b4.w, 0.0f);
        }
    }
    float4 o;
    o.x = (v0.x + v1.x) * dn; o.y = (v0.y + v1.y) * dn;
    o.z = (v0.z + v1.z) * dn; o.w = (v0.w + v1.w) * dn;
    *(float4*)(f3 + (long)bm * D_ + d) = o;
}

// ------------------------------------------------- fused K+V projection GEMM (f32)
#define BM 128
#define BN 64
#define BK 32
#define ASTR 136
__global__ __launch_bounds__(256) void k_gemmkv(const float* __restrict__ A,
                                                const float* __restrict__ Wk2, const float* __restrict__ bk2, float* __restrict__ Ck,
                                                const float* __restrict__ Wv2, const float* __restrict__ bv2, float* __restrict__ Cv) {
    __shared__ float As[BK][ASTR];
    __shared__ float Bsf[BK][BN];
    int bm = blockIdx.x;
    int which = blockIdx.y >> 3;
    int bn = blockIdx.y & 7;
    const float* Bw  = which ? Wv2 : Wk2;
    const float* bias = which ? bv2 : bk2;
    float* C = which ? Cv : Ck;
    int tid = threadIdx.x;
    int trow = tid >> 4, tcol = tid & 15;
    float acc[8][4] = {};
    const float* Ab = A + (long)bm * BM * D_;
    const float* Bb = Bw + bn * BN;
    for (int kt = 0; kt < D_; kt += BK) {
        #pragma unroll
        for (int i = 0; i < 4; i++) {
            int f = tid + 256 * i;
            int row = f >> 3, c4 = (f & 7) << 2;
            float4 v = *(const float4*)(Ab + (long)row * D_ + kt + c4);
            As[c4 + 0][row] = v.x; As[c4 + 1][row] = v.y;
            As[c4 + 2][row] = v.z; As[c4 + 3][row] = v.w;
        }
        #pragma unroll
        for (int i = 0; i < 2; i++) {
            int f = tid + 256 * i;
            int row = f >> 4, c4 = (f & 15) << 2;
            *(float4*)&Bsf[row][c4] = *(const float4*)(Bb + (long)(kt + row) * D_ + c4);
        }
        __syncthreads();
        #pragma unroll 8
        for (int kk = 0; kk < BK; kk++) {
            float a[8], bv4[4];
            #pragma unroll
            for (int i = 0; i < 8; i++) a[i] = As[kk][trow * 8 + i];
            #pragma unroll
            for (int j = 0; j < 4; j++) bv4[j] = Bsf[kk][tcol * 4 + j];
            #pragma unroll
            for (int i = 0; i < 8; i++)
                #pragma unroll
                for (int j = 0; j < 4; j++)
                    acc[i][j] = fmaf(a[i], bv4[j], acc[i][j]);
        }
        __syncthreads();
    }
    int c = bn * BN + tcol * 4;
    #pragma unroll
    for (int i = 0; i < 8; i++) {
        long r = (long)bm * BM + trow * 8 + i;
        float4 v;
        v.x = acc[i][0] + bias[c + 0]; v.y = acc[i][1] + bias[c + 1];
        v.z = acc[i][2] + bias[c + 2]; v.w = acc[i][3] + bias[c + 3];
        *(float4*)(C + r * D_ + c) = v;
    }
}

// ------------------------------------------------- cross-modal attention (parallel PV)
__global__ __launch_bounds__(512) void k_attn(const float* qv, const float* kk,
                                              const float* vv, float* ctx) {
    int bh = blockIdx.x;
    int b = bh >> 3, h = bh & 7;
    __shared__ float qs[DH_];
    __shared__ float sc[M2_];
    __shared__ float red[M2_];
    __shared__ float part[8][DH_];
    int m = threadIdx.x;
    if (m < DH_) qs[m] = qv[b * D_ + h * DH_ + m];
    __syncthreads();
    const float* kp = kk + (long)b * M2_ * D_ + h * DH_;
    float acc = 0.f;
    #pragma unroll
    for (int d = 0; d < DH_; d += 4) {
        float4 kv = *(const float4*)(kp + (long)m * D_ + d);
        acc += qs[d] * kv.x + qs[d + 1] * kv.y + qs[d + 2] * kv.z + qs[d + 3] * kv.w;
    }
    acc *= 0.125f;
    red[m] = acc; __syncthreads();
    for (int o = 256; o > 0; o >>= 1) { if (m < o) red[m] = fmaxf(red[m], red[m + o]); __syncthreads(); }
    float mx = red[0]; __syncthreads();
    float e = expf(acc - mx);
    sc[m] = e; red[m] = e; __syncthreads();
    for (int o = 256; o > 0; o >>= 1) { if (m < o) red[m] += red[m + o]; __syncthreads(); }
    float inv = 1.0f / red[0];
    // PV: 8 m-groups x 64 d lanes, coalesced V reads
    int g = m >> 6, d = m & 63;
    const float* vp = vv + (long)b * M2_ * D_ + h * DH_ + d;
    float a2 = 0.f;
    #pragma unroll 4
    for (int mm = g * 64; mm < g * 64 + 64; mm++)
        a2 = fmaf(sc[mm], vp[(long)mm * D_], a2);
    part[g][d] = a2; __syncthreads();
    if (m < DH_) {
        float s = 0.f;
        #pragma unroll
        for (int g2 = 0; g2 < 8; g2++) s += part[g2][m];
        ctx[b * D_ + h * DH_ + m] = s * inv;
    }
}

// ------------------------------------------------- output head (Wo then W_cls), f32 out
__global__ __launch_bounds__(512) void k_head(const float* ctx, const float* Wo, const float* bo,
                                              const float* Wc, const float* bc,
                                              float* out) {
    int b = blockIdx.x, d = threadIdx.x;
    __shared__ float cl[D_], ol[D_];
    cl[d] = ctx[b * D_ + d]; __syncthreads();
    float acc = bo[d];
    for (int e = 0; e < D_; e++) acc = fmaf(cl[e], Wo[(long)e * D_ + d], acc);
    ol[d] = acc; __syncthreads();
    if (d < 4) {
        float a2 = bc[d];
        for (int e = 0; e < D_; e++) a2 = fmaf(ol[e], Wc[e * 4 + d], a2);
        out[b * 4 + d] = a2;
    }
}

// ---------------------------------------------------------------- launcher
extern "C" void kernel_launch(void* const* d_in, const int* in_sizes, int n_in,
                              void* d_out, int out_size, void* d_ws, size_t ws_size,
                              hipStream_t stream) {
    const float* bags = (const float*)d_in[0];
    const void*  kpm  = d_in[1];
    const int*   ids  = (const int*)d_in[2];
    const int*   am   = (const int*)d_in[3];
    const float* emb  = (const float*)d_in[4];
    const float* Wtp  = (const float*)d_in[5];
    const float* btp  = (const float*)d_in[6];
    const float* Wen  = (const float*)d_in[7];
    const float* ben  = (const float*)d_in[8];
    const float* lng  = (const float*)d_in[9];
    const float* lnb  = (const float*)d_in[10];
    const float* Wq   = (const float*)d_in[11];
    const float* bq   = (const float*)d_in[12];
    const float* Wk   = (const float*)d_in[13];
    const float* bk   = (const float*)d_in[14];
    const float* Wv   = (const float*)d_in[15];
    const float* bv   = (const float*)d_in[16];
    const float* Wo   = (const float*)d_in[17];
    const float* bo   = (const float*)d_in[18];
    const float* Wc   = (const float*)d_in[19];
    const float* bc   = (const float*)d_in[20];

    char* ws = (char*)d_ws;
    size_t o = 0;
    auto alloc = [&](size_t bytes) -> void* {
        void* p = ws + o; o += (bytes + 255) & ~(size_t)255; return p;
    };
    float* img  = (float*)alloc((size_t)NTOK_ * D_ * 4);
    float* rno  = (float*)alloc((size_t)NTOK_ * 4);
    float* rel  = (float*)alloc((size_t)NTOK_ * 4);
    int*   keep = (int*)alloc((size_t)NTOK_ * 4);
    unsigned char* vld = (unsigned char*)alloc(NTOK_);
    float* tf   = (float*)alloc(B_ * 768 * 4);
    float* te   = (float*)alloc(B_ * D_ * 4);
    float* qv   = (float*)alloc(B_ * D_ * 4);
    int*   idxo = (int*)alloc(B_ * LMAX_ * 4);
    float* f3   = (float*)alloc((size_t)B_ * M2_ * D_ * 4);
    float* kkb  = (float*)alloc((size_t)B_ * M2_ * D_ * 4);
    float* vvb  = (float*)alloc((size_t)B_ * M2_ * D_ * 4);
    float* ctx  = (float*)alloc(B_ * D_ * 4);
    int*   flag = (int*)alloc(256);
    float2* stats = (float2*)alloc((size_t)NTOK_ * 8);
    unsigned short* bth = (unsigned short*)alloc((size_t)D_ * F_ * 2);
    unsigned short* btl = (unsigned short*)alloc((size_t)D_ * F_ * 2);

    size_t fnb_need = (size_t)NTOK_ * D_ * 2 + 4096;
    bool newpath = (ws_size > o) && ((ws_size - o) >= fnb_need);
    unsigned short* fnb = nullptr;
    if (newpath) fnb = (unsigned short*)alloc((size_t)NTOK_ * D_ * 2);

    hipMemsetAsync(flag, 0, 4, stream);
    k_detect<<<64, 256, 0, stream>>>((const unsigned char*)kpm, NTOK_, flag);
    k_valid<<<(NTOK_ + 255) / 256, 256, 0, stream>>>(kpm, flag, vld);
    k_text_feat<<<B_, 256, 0, stream>>>(emb, ids, am, tf);
    k_rowmm<<<B_, 512, 0, stream>>>(tf, Wtp, btp, te, 768, 512);
    k_rowmm<<<B_, 512, 0, stream>>>(te, Wq, bq, qv, 512, 512);

    dim3 gsplit(F_ / 32, D_ / 32);
    if (newpath) {
        k_bsplit_sw<<<gsplit, 256, 0, stream>>>(Wen, bth, btl);
        k_gemm3<<<4096, 256, 0, stream>>>(bags, bth, btl, ben, img);
    } else {
        k_bsplit<<<gsplit, 256, 0, stream>>>(Wen, bth, btl);
        dim3 g3(NTOK_ / 64, 2);
        k_gemm_mfma<<<g3, 256, 0, stream>>>(bags, bth, btl, ben, img);
    }

    int write_img = newpath ? 0 : 1;
    k_ln<<<NTOK_ / 4, 256, 0, stream>>>(img, lng, lnb, te, rno, rel, fnb, stats, write_img);
    if (fnb) k_simg<<<NTOK_ / 128, 256, 0, stream>>>(fnb, vld, keep);
    else     k_sim<<<(NTOK_ + CHUNK - 1) / CHUNK, 256, 0, stream>>>(img, rno, vld, keep);
    k_topk<<<B_, 1024, 0, stream>>>(rel, keep, idxo);
    k_feat3<<<B_ * M2_, 128, 0, stream>>>(img, stats, lng, lnb, idxo, f3, newpath ? 1 : 0);

    dim3 gkv(B_ * M2_ / BM, 16);
    k_gemmkv<<<gkv, 256, 0, stream>>>(f3, Wk, bk, kkb, Wv, bv, vvb);

    k_attn<<<B_ * H_, 512, 0, stream>>>(qv, kkb, vvb, ctx);
    k_head<<<B_, 512, 0, stream>>>(ctx, Wo, bo, Wc, bc, (float*)d_out);
}

// Round 9
// 879.248 us; speedup vs baseline: 3.8841x; 1.0707x over previous
//
#include <hip/hip_runtime.h>
#include <hip/hip_bf16.h>
#include <math.h>
#include <stdint.h>

#define B_    8
#define N_    16384
#define F_    1024
#define D_    512
#define S_    64
#define H_    8
#define DH_   64
#define LMAX_ 1024
#define M2_   512
#define WIN_  32
#define NTOK_ (B_ * N_)   // 131072

typedef __attribute__((ext_vector_type(8)))  short bf16x8;
typedef __attribute__((ext_vector_type(16))) float f32x16;

// quad-swizzle (16B units) keyed by row low bits
#define S_OF(r) (((r) >> 1) & 3)

// ---------------------------------------------------------------- utilities
static __device__ __forceinline__ float wred_sum(float v) {
    #pragma unroll
    for (int d = 1; d < 64; d <<= 1) v += __shfl_xor(v, d, 64);
    return v;
}

static __device__ __forceinline__ void bf8_to_f32(uint4 q, float* a) {
    a[0] = __uint_as_float(q.x << 16); a[1] = __uint_as_float(q.x & 0xffff0000u);
    a[2] = __uint_as_float(q.y << 16); a[3] = __uint_as_float(q.y & 0xffff0000u);
    a[4] = __uint_as_float(q.z << 16); a[5] = __uint_as_float(q.z & 0xffff0000u);
    a[6] = __uint_as_float(q.w << 16); a[7] = __uint_as_float(q.w & 0xffff0000u);
}

static __device__ __forceinline__ unsigned short bf16r(float x) {   // RNE f32->bf16
    unsigned int b = __float_as_uint(x);
    return (unsigned short)((b + 0x7FFFu + ((b >> 16) & 1u)) >> 16);
}

static __device__ __forceinline__ void split_bf(float x, unsigned short& h, unsigned short& l) {
    unsigned int b = __float_as_uint(x);
    unsigned int hb = (b + 0x7FFFu + ((b >> 16) & 1u)) >> 16;
    h = (unsigned short)hb;
    float r = x - __uint_as_float(hb << 16);
    l = bf16r(r);
}

// cheap truncation split of 8 f32 -> hi/lo bf16x8 (in-register)
static __device__ __forceinline__ void split8(float4 f0, float4 f1, bf16x8& hi, bf16x8& lo) {
    float xs[8] = { f0.x, f0.y, f0.z, f0.w, f1.x, f1.y, f1.z, f1.w };
    unsigned int hp[4], lp[4];
    #pragma unroll
    for (int i = 0; i < 4; i++) {
        unsigned int b0 = __float_as_uint(xs[2*i]), b1 = __float_as_uint(xs[2*i+1]);
        hp[i] = (b0 >> 16) | (b1 & 0xffff0000u);
        float r0 = xs[2*i]   - __uint_as_float(b0 & 0xffff0000u);
        float r1 = xs[2*i+1] - __uint_as_float(b1 & 0xffff0000u);
        lp[i] = (__float_as_uint(r0) >> 16) | (__float_as_uint(r1) & 0xffff0000u);
    }
    union { uint4 u; bf16x8 v; } a, c;
    a.u = make_uint4(hp[0], hp[1], hp[2], hp[3]);
    c.u = make_uint4(lp[0], lp[1], lp[2], lp[3]);
    hi = a.v; lo = c.v;
}

static __device__ __forceinline__ void gll16(const void* g, void* l) {
    __builtin_amdgcn_global_load_lds(
        (const __attribute__((address_space(1))) unsigned int*)g,
        (__attribute__((address_space(3))) unsigned int*)l, 16, 0, 0);
}

// ------------------------------------------------- mask layout detection
__global__ void k_detect(const unsigned char* mb, int nbytes, int* flag) {
    int found = 0;
    for (int i = blockIdx.x * blockDim.x + threadIdx.x; i < nbytes; i += gridDim.x * blockDim.x)
        if ((i & 3) && mb[i]) found = 1;
    if (found) atomicOr(flag, 1);
}

__global__ void k_valid(const void* maskp, const int* flag, unsigned char* v) {
    int i = blockIdx.x * 256 + threadIdx.x;
    if (i >= NTOK_) return;
    int pad;
    if (*flag) pad = (((const unsigned char*)maskp)[i] != 0);
    else       pad = (((const int*)maskp)[i] != 0);
    v[i] = pad ? 0 : 1;
}

// ------------------------------------------------- text feature (masked mean)
__global__ void k_text_feat(const float* emb, const int* ids, const int* am, float* tf) {
    int b = blockIdx.x;
    __shared__ int   sid[S_];
    __shared__ float sam[S_];
    int t = threadIdx.x;
    if (t < S_) { sid[t] = ids[b * S_ + t]; sam[t] = (float)am[b * S_ + t]; }
    __syncthreads();
    float asum = 0.f;
    for (int s = 0; s < S_; s++) asum += sam[s];
    float denom = fmaxf(asum, 1.0f);
    for (int d = t; d < 768; d += blockDim.x) {
        float acc = 0.f;
        for (int s = 0; s < S_; s++) acc += emb[(long)sid[s] * 768 + d] * sam[s];
        tf[b * 768 + d] = acc / denom;
    }
}

__global__ void k_rowmm(const float* in, const float* W, const float* bias,
                        float* out, int E, int Nn) {
    int b = blockIdx.x, d = threadIdx.x;
    __shared__ float sin[768];
    for (int e = d; e < E; e += blockDim.x) sin[e] = in[b * E + e];
    __syncthreads();
    float acc = bias[d];
    for (int e = 0; e < E; e++) acc = fmaf(sin[e], W[(long)e * Nn + d], acc);
    out[b * Nn + d] = acc;
}

// ------------------------------------------------- weight transpose + split, swizzled layout
// W [E][512] f32 -> planes [512][E] bf16 hi/lo, 16B-quad XOR'd by S_OF(col&7).
__global__ __launch_bounds__(256) void k_bsplit_sw(const float* __restrict__ W,
                                                   unsigned short* __restrict__ bh,
                                                   unsigned short* __restrict__ bl,
                                                   int E) {
    __shared__ float tile[32][33];
    int e0 = blockIdx.x * 32;   // k origin
    int d0 = blockIdx.y * 32;   // out-col origin
    int t = threadIdx.x;
    int r = t >> 3, c4 = (t & 7) * 4;
    float4 v = *(const float4*)(W + (long)(e0 + r) * D_ + d0 + c4);
    tile[r][c4] = v.x; tile[r][c4 + 1] = v.y; tile[r][c4 + 2] = v.z; tile[r][c4 + 3] = v.w;
    __syncthreads();
    if (t < 128) {
        int c = t & 31, kq = t >> 5;           // col-in-tile, quad-in-tile (0..3)
        int col = d0 + c;
        float xs[8];
        #pragma unroll
        for (int i = 0; i < 8; i++) xs[i] = tile[kq * 8 + i][c];
        unsigned short h[8], l[8];
        #pragma unroll
        for (int i = 0; i < 8; i++) split_bf(xs[i], h[i], l[i]);
        uint4 ph, pl;
        ph.x = h[0] | ((unsigned)h[1] << 16); ph.y = h[2] | ((unsigned)h[3] << 16);
        ph.z = h[4] | ((unsigned)h[5] << 16); ph.w = h[6] | ((unsigned)h[7] << 16);
        pl.x = l[0] | ((unsigned)l[1] << 16); pl.y = l[2] | ((unsigned)l[3] << 16);
        pl.z = l[4] | ((unsigned)l[5] << 16); pl.w = l[6] | ((unsigned)l[7] << 16);
        int Q = (e0 >> 3) + kq;
        int Qo = (Q & ~3) | ((Q & 3) ^ S_OF(col & 7));
        *(uint4*)(bh + (long)col * E + Qo * 8) = ph;
        *(uint4*)(bl + (long)col * E + Qo * 8) = pl;
    }
}

// ------------------------------------------------- gll GEMM body, A raw f32 + in-reg split
// Tile 128x128, BK=32, 4 waves, single 32 KB buffer. C stride fixed 512, 4 bn tiles.
static __device__ __forceinline__ void gemm3_body(const float* __restrict__ A,
                                                  const unsigned short* __restrict__ Bh2,
                                                  const unsigned short* __restrict__ Bl2,
                                                  const float* __restrict__ bias,
                                                  float* __restrict__ C, int K, int wg) {
    __shared__ __align__(16) float ldsA[128][32];              // 16 KiB
    __shared__ __align__(16) unsigned short ldsB[2][128][32];  // 16 KiB
    int bn = wg & 3, bm = wg >> 2;
    int tid = threadIdx.x;
    int w = tid >> 6, lane = tid & 63;
    int r32 = lane & 31, kg = lane >> 5;
    int wr = w >> 1, wc = w & 1;
    int s8 = r32 & 7;

    const float* agbase = nullptr;
    const unsigned short* bgbase = nullptr;
    if (w < 2) {
        int rl = lane >> 3, qs = lane & 7;
        agbase = A + (long)(bm * 128 + w * 64 + rl) * K + ((qs ^ rl) * 4);
    } else {
        const unsigned short* plane = (w == 2) ? Bh2 : Bl2;
        int lrow = lane >> 2, lq = lane & 3;
        bgbase = plane + (long)(bn * 128 + lrow) * K + lq * 8;
    }

    f32x16 acc[2][2];
    #pragma unroll
    for (int i = 0; i < 2; i++)
        #pragma unroll
        for (int j = 0; j < 2; j++)
            #pragma unroll
            for (int r = 0; r < 16; r++) acc[i][j][r] = 0.f;

    for (int kt = 0; kt < K; kt += 32) {
        if (w < 2) {
            #pragma unroll
            for (int j = 0; j < 8; j++)
                gll16(agbase + (long)j * 8 * K + kt, &ldsA[w * 64 + j * 8][0]);
        } else {
            #pragma unroll
            for (int j = 0; j < 8; j++)
                gll16(bgbase + (long)j * 16 * K + kt, &ldsB[w - 2][j * 16][0]);
        }
        __syncthreads();
        #pragma unroll
        for (int k2 = 0; k2 < 2; k2++) {
            int qA = k2 * 4 + kg * 2;
            int qs0 = (qA ^ s8) * 4;
            int qs1 = ((qA + 1) ^ s8) * 4;
            bf16x8 a_h[2], a_l[2];
            #pragma unroll
            for (int rf = 0; rf < 2; rf++) {
                int ar = wr * 64 + rf * 32 + r32;
                float4 f0 = *(const float4*)&ldsA[ar][qs0];
                float4 f1 = *(const float4*)&ldsA[ar][qs1];
                split8(f0, f1, a_h[rf], a_l[rf]);
            }
            int qb = k2 * 2 + kg;
            bf16x8 b_h[2], b_l[2];
            #pragma unroll
            for (int cf = 0; cf < 2; cf++) {
                int bc = wc * 64 + cf * 32 + r32;
                int q = (qb ^ S_OF(r32)) * 8;
                b_h[cf] = *(const bf16x8*)&ldsB[0][bc][q];
                b_l[cf] = *(const bf16x8*)&ldsB[1][bc][q];
            }
            #pragma unroll
            for (int rf = 0; rf < 2; rf++)
                #pragma unroll
                for (int cf = 0; cf < 2; cf++) {
                    acc[rf][cf] = __builtin_amdgcn_mfma_f32_32x32x16_bf16(a_h[rf], b_h[cf], acc[rf][cf], 0, 0, 0);
                    acc[rf][cf] = __builtin_amdgcn_mfma_f32_32x32x16_bf16(a_h[rf], b_l[cf], acc[rf][cf], 0, 0, 0);
                    acc[rf][cf] = __builtin_amdgcn_mfma_f32_32x32x16_bf16(a_l[rf], b_h[cf], acc[rf][cf], 0, 0, 0);
                }
        }
        __syncthreads();
    }
    #pragma unroll
    for (int rf = 0; rf < 2; rf++)
        #pragma unroll
        for (int cf = 0; cf < 2; cf++) {
            int col = bn * 128 + wc * 64 + cf * 32 + r32;
            float bv = bias[col];
            #pragma unroll
            for (int r = 0; r < 16; r++) {
                int row = bm * 128 + wr * 64 + rf * 32 + (r & 3) + 8 * (r >> 2) + 4 * kg;
                C[(long)row * D_ + col] = acc[rf][cf][r] + bv;
            }
        }
}

__global__ __launch_bounds__(256) void k_gemm3p(const float* __restrict__ A,
                                                const unsigned short* __restrict__ Bh2,
                                                const unsigned short* __restrict__ Bl2,
                                                const float* __restrict__ bias,
                                                float* __restrict__ C, int K) {
    int bid = blockIdx.x;
    int cpx = gridDim.x >> 3;                 // gridDim.x % 8 == 0 (4096)
    int wg = (bid & 7) * cpx + (bid >> 3);    // bijective XCD chunking
    gemm3_body(A, Bh2, Bl2, bias, C, K, wg);
}

// K and V projections in one launch: 256 blocks, which = bid&1
__global__ __launch_bounds__(256) void k_gemmkv2(const float* __restrict__ A,
                                                 const unsigned short* __restrict__ Kh, const unsigned short* __restrict__ Kl,
                                                 const float* __restrict__ bk2, float* __restrict__ Ck,
                                                 const unsigned short* __restrict__ Vh, const unsigned short* __restrict__ Vl,
                                                 const float* __restrict__ bv2, float* __restrict__ Cv) {
    int which = blockIdx.x & 1;
    int wg = blockIdx.x >> 1;                 // 0..127 -> bm 0..31, bn 0..3
    if (which)
        gemm3_body(A, Vh, Vl, bv2, Cv, 512, wg);
    else
        gemm3_body(A, Kh, Kl, bk2, Ck, 512, wg);
}

// ------------------------------------------------- fallback fused split GEMM (round-4)
#define GPAD 40
__global__ __launch_bounds__(256, 3) void k_gemm_mfma(const float* __restrict__ A,
                                                      const unsigned short* __restrict__ Bth,
                                                      const unsigned short* __restrict__ Btl,
                                                      const float* __restrict__ bias,
                                                      float* __restrict__ C) {
    __shared__ __align__(16) unsigned short As[2][64][GPAD];
    __shared__ __align__(16) unsigned short Bs[2][256][GPAD];
    int bm = blockIdx.x, bn = blockIdx.y;
    int tid = threadIdx.x;
    int w = tid >> 6, lane = tid & 63;
    int r32 = lane & 31, kg = lane >> 5;
    f32x16 acc[2][2];
    #pragma unroll
    for (int i = 0; i < 2; i++)
        #pragma unroll
        for (int j = 0; j < 2; j++)
            #pragma unroll
            for (int r = 0; r < 16; r++) acc[i][j][r] = 0.f;
    int arow = tid >> 2, aq = tid & 3;
    const float* abase = A + (long)(bm * 64 + arow) * 1024 + aq * 8;
    const unsigned short* bhbase = Bth + (long)(bn * 256 + tid) * 1024;
    const unsigned short* blbase = Btl + (long)(bn * 256 + tid) * 1024;
    float4 pa0 = *(const float4*)abase;
    float4 pa1 = *(const float4*)(abase + 4);
    for (int kt = 0; kt < 1024; kt += 32) {
        {
            float xs[8] = { pa0.x, pa0.y, pa0.z, pa0.w, pa1.x, pa1.y, pa1.z, pa1.w };
            unsigned short h[8], l[8];
            #pragma unroll
            for (int i = 0; i < 8; i++) split_bf(xs[i], h[i], l[i]);
            uint4 ph, pl;
            ph.x = h[0] | ((unsigned)h[1] << 16); ph.y = h[2] | ((unsigned)h[3] << 16);
            ph.z = h[4] | ((unsigned)h[5] << 16); ph.w = h[6] | ((unsigned)h[7] << 16);
            pl.x = l[0] | ((unsigned)l[1] << 16); pl.y = l[2] | ((unsigned)l[3] << 16);
            pl.z = l[4] | ((unsigned)l[5] << 16); pl.w = l[6] | ((unsigned)l[7] << 16);
            *(uint4*)&As[0][arow][aq * 8] = ph;
            *(uint4*)&As[1][arow][aq * 8] = pl;
        }
        {
            const uint4* ph = (const uint4*)(bhbase + kt);
            const uint4* pl = (const uint4*)(blbase + kt);
            #pragma unroll
            for (int q = 0; q < 4; q++) {
                *(uint4*)&Bs[0][tid][q * 8] = ph[q];
                *(uint4*)&Bs[1][tid][q * 8] = pl[q];
            }
        }
        __syncthreads();
        if (kt + 32 < 1024) {
            const float* ap = abase + kt + 32;
            pa0 = *(const float4*)ap;
            pa1 = *(const float4*)(ap + 4);
        }
        #pragma unroll
        for (int k2 = 0; k2 < 2; k2++) {
            int ko = k2 * 16 + kg * 8;
            bf16x8 ah[2], al[2], bh[2], blv[2];
            #pragma unroll
            for (int rf = 0; rf < 2; rf++) {
                ah[rf] = *(const bf16x8*)&As[0][rf * 32 + r32][ko];
                al[rf] = *(const bf16x8*)&As[1][rf * 32 + r32][ko];
            }
            #pragma unroll
            for (int cf = 0; cf < 2; cf++) {
                bh[cf]  = *(const bf16x8*)&Bs[0][w * 64 + cf * 32 + r32][ko];
                blv[cf] = *(const bf16x8*)&Bs[1][w * 64 + cf * 32 + r32][ko];
            }
            #pragma unroll
            for (int rf = 0; rf < 2; rf++)
                #pragma unroll
                for (int cf = 0; cf < 2; cf++) {
                    acc[rf][cf] = __builtin_amdgcn_mfma_f32_32x32x16_bf16(ah[rf], bh[cf],  acc[rf][cf], 0, 0, 0);
                    acc[rf][cf] = __builtin_amdgcn_mfma_f32_32x32x16_bf16(ah[rf], blv[cf], acc[rf][cf], 0, 0, 0);
                    acc[rf][cf] = __builtin_amdgcn_mfma_f32_32x32x16_bf16(al[rf], bh[cf],  acc[rf][cf], 0, 0, 0);
                }
        }
        __syncthreads();
    }
    #pragma unroll
    for (int rf = 0; rf < 2; rf++)
        #pragma unroll
        for (int cf = 0; cf < 2; cf++) {
            int col = bn * 256 + w * 64 + cf * 32 + r32;
            float bv = bias[col];
            #pragma unroll
            for (int r = 0; r < 16; r++) {
                int row = bm * 64 + rf * 32 + (r & 3) + 8 * (r >> 2) + 4 * kg;
                C[(long)row * D_ + col] = acc[rf][cf][r] + bv;
            }
        }
}

// old unswizzled bsplit (fallback path)
__global__ __launch_bounds__(256) void k_bsplit(const float* __restrict__ W,
                                                unsigned short* __restrict__ bh,
                                                unsigned short* __restrict__ bl) {
    __shared__ float tile[32][33];
    int e0 = blockIdx.x * 32;
    int d0 = blockIdx.y * 32;
    int t = threadIdx.x;
    int r = t >> 3;
    int c = (t & 7) * 4;
    float4 v = *(const float4*)(W + (long)(e0 + r) * D_ + d0 + c);
    tile[r][c] = v.x; tile[r][c + 1] = v.y; tile[r][c + 2] = v.z; tile[r][c + 3] = v.w;
    __syncthreads();
    ushort4 h4, l4;
    unsigned short hh, ll;
    float x0 = tile[c + 0][r], x1 = tile[c + 1][r], x2 = tile[c + 2][r], x3 = tile[c + 3][r];
    split_bf(x0, hh, ll); h4.x = hh; l4.x = ll;
    split_bf(x1, hh, ll); h4.y = hh; l4.y = ll;
    split_bf(x2, hh, ll); h4.z = hh; l4.z = ll;
    split_bf(x3, hh, ll); h4.w = hh; l4.w = ll;
    *(ushort4*)(bh + (long)(d0 + r) * 1024 + e0 + c) = h4;
    *(ushort4*)(bl + (long)(d0 + r) * 1024 + e0 + c) = l4;
}

// ------------------------------------------------- LayerNorm+ReLU + rnorm + rel (+fnb, +stats)
__global__ __launch_bounds__(256) void k_ln(float* h, const float* g, const float* bb,
                                            const float* temb, float* rnorm, float* rel,
                                            unsigned short* fnb, float2* stats, int write_img) {
    int wid = threadIdx.x >> 6, lane = threadIdx.x & 63;
    long row = (long)blockIdx.x * 4 + wid;
    int b = (int)(row >> 14);
    float* hp = h + row * (long)D_;
    int c0 = lane * 4, c1 = 256 + lane * 4;
    float4 x0 = *(float4*)(hp + c0);
    float4 x1 = *(float4*)(hp + c1);
    float x[8] = { x0.x, x0.y, x0.z, x0.w, x1.x, x1.y, x1.z, x1.w };
    float s = 0.f;
    #pragma unroll
    for (int i = 0; i < 8; i++) s += x[i];
    s = wred_sum(s);
    float mu = s * (1.0f / 512.0f);
    float var = 0.f;
    #pragma unroll
    for (int i = 0; i < 8; i++) { float d = x[i] - mu; var += d * d; }
    var = wred_sum(var) * (1.0f / 512.0f);
    float inv = 1.0f / sqrtf(var + 1e-5f);
    float4 g0 = *(const float4*)(g + c0), g1 = *(const float4*)(g + c1);
    float4 b0 = *(const float4*)(bb + c0), b1 = *(const float4*)(bb + c1);
    float gg[8] = { g0.x, g0.y, g0.z, g0.w, g1.x, g1.y, g1.z, g1.w };
    float bbv[8] = { b0.x, b0.y, b0.z, b0.w, b1.x, b1.y, b1.z, b1.w };
    float y[8], sq = 0.f;
    #pragma unroll
    for (int i = 0; i < 8; i++) {
        y[i] = fmaxf(gg[i] * (x[i] - mu) * inv + bbv[i], 0.0f);
        sq += y[i] * y[i];
    }
    if (write_img) {
        float4 o0 = { y[0], y[1], y[2], y[3] }, o1 = { y[4], y[5], y[6], y[7] };
        *(float4*)(hp + c0) = o0;
        *(float4*)(hp + c1) = o1;
    }
    sq = wred_sum(sq);
    float rn = 1.0f / (sqrtf(sq) + 1e-8f);
    if (fnb) {
        ushort4 u0, u1;
        u0.x = bf16r(y[0] * rn); u0.y = bf16r(y[1] * rn);
        u0.z = bf16r(y[2] * rn); u0.w = bf16r(y[3] * rn);
        u1.x = bf16r(y[4] * rn); u1.y = bf16r(y[5] * rn);
        u1.z = bf16r(y[6] * rn); u1.w = bf16r(y[7] * rn);
        *(ushort4*)(fnb + row * D_ + c0) = u0;
        *(ushort4*)(fnb + row * D_ + c1) = u1;
    }
    const float* tp = temb + (long)b * D_;
    float4 t0 = *(const float4*)(tp + c0), t1 = *(const float4*)(tp + c1);
    float tt[8] = { t0.x, t0.y, t0.z, t0.w, t1.x, t1.y, t1.z, t1.w };
    float rl = 0.f;
    #pragma unroll
    for (int i = 0; i < 8; i++) rl = fmaf(y[i], tt[i], rl);
    rl = wred_sum(rl);
    if (lane == 0) { rnorm[row] = rn; rel[row] = rl; stats[row] = make_float2(mu, inv); }
}

// ------------------------------------------------- sliding-window cosine pruning via MFMA band
__global__ __launch_bounds__(256) void k_simg(const unsigned short* __restrict__ fnb,
                                              const unsigned char* __restrict__ vld,
                                              int* __restrict__ keep) {
    int wid = threadIdx.x >> 6, lane = threadIdx.x & 63;
    int T = (blockIdx.x * 4 + wid) * 32;
    int r32 = lane & 31, kg = lane >> 5;
    int prevok = (T & (N_ - 1)) != 0;
    const unsigned short* arow  = fnb + (long)(T + r32) * D_ + kg * 8;
    const unsigned short* b0row = fnb + (long)((prevok ? T - 32 : T) + r32) * D_ + kg * 8;

    f32x16 g0, g1;
    #pragma unroll
    for (int r = 0; r < 16; r++) { g0[r] = 0.f; g1[r] = 0.f; }
    #pragma unroll 4
    for (int kt = 0; kt < D_; kt += 16) {
        bf16x8 a  = *(const bf16x8*)(arow + kt);
        bf16x8 b0 = *(const bf16x8*)(b0row + kt);
        g0 = __builtin_amdgcn_mfma_f32_32x32x16_bf16(a, b0, g0, 0, 0, 0);
        g1 = __builtin_amdgcn_mfma_f32_32x32x16_bf16(a, a,  g1, 0, 0, 0);
    }
    int okc0 = prevok ? (int)vld[T - 32 + r32] : 0;
    int okc1 = (int)vld[T + r32];
    float ms[16];
    #pragma unroll
    for (int r = 0; r < 16; r++) {
        int i = (r & 3) + 8 * (r >> 2) + 4 * kg;
        float v = -INFINITY;
        if (okc0 && r32 >= i) v = g0[r];
        if (okc1 && r32 < i)  v = fmaxf(v, g1[r]);
        #pragma unroll
        for (int d = 1; d < 32; d <<= 1) v = fmaxf(v, __shfl_xor(v, d, 64));
        ms[r] = v;
    }
    if (r32 == 0) {
        #pragma unroll
        for (int r = 0; r < 16; r++) {
            int i = (r & 3) + 8 * (r >> 2) + 4 * kg;
            int t = T + i;
            keep[t] = (vld[t] && ms[r] < 0.7f) ? 1 : 0;
        }
    }
}

// ------------------------------------------------- fallback sliding-window (no fnb space)
#define CHUNK 28
#define KROWS 60
__global__ __launch_bounds__(256) void k_sim(const float* img, const float* rnorm,
                                             const unsigned char* vld, int* keep) {
    __shared__ __hip_bfloat16 fnbs[KROWS][D_];
    long c0 = (long)blockIdx.x * CHUNK;
    int tid = threadIdx.x;
    for (int idx = tid; idx < KROWS * (D_ / 8); idx += 256) {
        int rr = idx / (D_ / 8);
        int cc = (idx % (D_ / 8)) * 8;
        long grow = c0 - WIN_ + rr;
        if (grow < 0) grow = 0;
        if (grow >= NTOK_) grow = NTOK_ - 1;
        float rn = rnorm[grow];
        const float* p = img + grow * (long)D_ + cc;
        float4 u = *(const float4*)p, w = *(const float4*)(p + 4);
        fnbs[rr][cc + 0] = __float2bfloat16(u.x * rn);
        fnbs[rr][cc + 1] = __float2bfloat16(u.y * rn);
        fnbs[rr][cc + 2] = __float2bfloat16(u.z * rn);
        fnbs[rr][cc + 3] = __float2bfloat16(u.w * rn);
        fnbs[rr][cc + 4] = __float2bfloat16(w.x * rn);
        fnbs[rr][cc + 5] = __float2bfloat16(w.y * rn);
        fnbs[rr][cc + 6] = __float2bfloat16(w.z * rn);
        fnbs[rr][cc + 7] = __float2bfloat16(w.w * rn);
    }
    __syncthreads();
    int wid = tid >> 6, lane = tid & 63;
    for (int ti = 0; ti < 7; ti++) {
        int tloc = wid * 7 + ti;
        long t = c0 + tloc;
        if (t >= NTOK_) continue;
        int lr = WIN_ + tloc;
        int tl = (int)(t & (N_ - 1));
        float a[8];
        bf8_to_f32(*(const uint4*)&fnbs[lr][lane * 8], a);
        int wmax = tl < WIN_ ? tl : WIN_;
        float msim = -INFINITY;
        for (int w = 1; w <= wmax; w++) {
            if (!vld[t - w]) continue;
            float bvv[8];
            bf8_to_f32(*(const uint4*)&fnbs[lr - w][lane * 8], bvv);
            float p = 0.f;
            #pragma unroll
            for (int i = 0; i < 8; i++) p = fmaf(a[i], bvv[i], p);
            p = wred_sum(p);
            msim = fmaxf(msim, p);
        }
        int kp = (vld[t] && (msim < 0.7f)) ? 1 : 0;
        if (lane == 0) keep[t] = kp;
    }
}

// ------------------------------------------------- per-batch exact top-k (radix select)
static __device__ void scan1024(int* tot, int tid) {
    if (tid < 64) {
        int vals[16], s = 0;
        #pragma unroll
        for (int i = 0; i < 16; i++) vals[i] = tot[tid * 16 + i];
        #pragma unroll
        for (int i = 0; i < 16; i++) { int t = vals[i]; vals[i] = s; s += t; }
        int inc = s;
        #pragma unroll
        for (int d = 1; d < 64; d <<= 1) {
            int v = __shfl_up(inc, d, 64);
            if ((tid & 63) >= d) inc += v;
        }
        int excl = inc - s;
        #pragma unroll
        for (int i = 0; i < 16; i++) tot[tid * 16 + i] = vals[i] + excl;
    }
}

__global__ __launch_bounds__(1024) void k_topk(const float* rel, const int* keep, int* idxo) {
    int b = blockIdx.x, tid = threadIdx.x;
    const float* relb = rel + (long)b * N_;
    const int* keepb  = keep + (long)b * N_;
    __shared__ unsigned int hist[256];
    __shared__ unsigned int suf[256];
    __shared__ int toti[1024];
    __shared__ int wsum[16];
    __shared__ unsigned int s_prefix;
    __shared__ int s_rem, s_k;

    unsigned int key[16];
    int base = tid * 16, nk_local = 0;
    #pragma unroll
    for (int j = 0; j < 16; j++) {
        int i = base + j;
        float r = relb[i];
        int kp = keepb[i];
        unsigned int bits = __float_as_uint(r);
        unsigned int kk = (bits & 0x80000000u) ? ~bits : (bits | 0x80000000u);
        key[j] = kp ? kk : 0u;
        nk_local += kp;
    }
    // n_kept: wave reduce + 16-entry sum
    int nk = nk_local;
    #pragma unroll
    for (int d = 1; d < 64; d <<= 1) nk += __shfl_xor(nk, d, 64);
    if ((tid & 63) == 0) wsum[tid >> 6] = nk;
    __syncthreads();
    if (tid == 0) {
        int n_kept = 0;
        #pragma unroll
        for (int i = 0; i < 16; i++) n_kept += wsum[i];
        int k = (int)(0.8f * (float)n_kept);
        if (k < 1) k = 1; if (k > LMAX_) k = LMAX_;
        s_k = k; s_rem = k; s_prefix = 0u;
    }
    __syncthreads();

    for (int pass = 0; pass < 4; pass++) {
        int shift = 24 - pass * 8;
        unsigned int himask = (pass == 0) ? 0u : (0xFFFFFFFFu << (shift + 8));
        if (tid < 256) hist[tid] = 0u;
        __syncthreads();
        unsigned int pfx = s_prefix;
        int rem = s_rem;
        #pragma unroll
        for (int j = 0; j < 16; j++) {
            unsigned int kk = key[j];
            if ((kk & himask) == (pfx & himask))
                atomicAdd(&hist[(kk >> shift) & 255], 1u);
        }
        __syncthreads();
        // parallel suffix-sum digit select: largest d with suffix[d] >= rem
        if (tid < 256) suf[tid] = hist[tid];
        __syncthreads();
        for (int o = 1; o < 256; o <<= 1) {
            unsigned int v = 0;
            if (tid < 256 && tid + o < 256) v = suf[tid + o];
            __syncthreads();
            if (tid < 256) suf[tid] += v;
            __syncthreads();
        }
        if (tid < 256) {
            unsigned int sv = suf[tid];
            unsigned int nxt = (tid == 255) ? 0u : suf[tid + 1];
            if (sv >= (unsigned int)rem && nxt < (unsigned int)rem) {
                s_prefix = pfx | ((unsigned int)tid << shift);
                s_rem = rem - (int)nxt;
            }
        }
        __syncthreads();
    }
    unsigned int T = s_prefix;
    int tie_need = s_rem, k = s_k;

    int eq[16], gt[16], eqpre[16];
    int locEq = 0;
    #pragma unroll
    for (int j = 0; j < 16; j++) {
        eq[j] = (key[j] == T); gt[j] = (key[j] > T);
        eqpre[j] = locEq; locEq += eq[j];
    }
    toti[tid] = locEq; __syncthreads();
    scan1024(toti, tid); __syncthreads();
    int eqoff = toti[tid];

    int sel[16], spre[16];
    int locS = 0;
    #pragma unroll
    for (int j = 0; j < 16; j++) {
        int rank = eqoff + eqpre[j];
        sel[j] = gt[j] || (eq[j] && rank < tie_need);
        spre[j] = locS; locS += sel[j];
    }
    __syncthreads();
    toti[tid] = locS; __syncthreads();
    scan1024(toti, tid); __syncthreads();
    int soff = toti[tid];
    #pragma unroll
    for (int j = 0; j < 16; j++)
        if (sel[j]) idxo[b * LMAX_ + soff + spre[j]] = base + j;
    for (int p = k + tid; p < LMAX_; p += 1024) idxo[b * LMAX_ + p] = N_;
}

// ------------------------------------------------- feat2 gather + pair pooling
__global__ void k_feat3(const float* img, const float2* stats, const float* lng,
                        const float* lnb, const int* idxo, float* f3, int recompute) {
    int bm = blockIdx.x;
    int b = bm >> 9, m = bm & 511;
    int i0 = idxo[b * LMAX_ + 2 * m], i1 = idxo[b * LMAX_ + 2 * m + 1];
    int c0 = i0 < N_, c1 = i1 < N_;
    float dn = 1.0f / fmaxf((float)(c0 + c1), 1.0f);
    long r0 = (long)b * N_ + (c0 ? i0 : 0);
    long r1 = (long)b * N_ + (c1 ? i1 : 0);
    int d = threadIdx.x * 4;
    float4 v0 = c0 ? *(const float4*)(img + r0 * D_ + d) : make_float4(0.f, 0.f, 0.f, 0.f);
    float4 v1 = c1 ? *(const float4*)(img + r1 * D_ + d) : make_float4(0.f, 0.f, 0.f, 0.f);
    if (recompute) {
        float4 g4 = *(const float4*)(lng + d);
        float4 b4 = *(const float4*)(lnb + d);
        if (c0) {
            float2 st = stats[r0];
            v0.x = fmaxf(g4.x * (v0.x - st.x) * st.y + b4.x, 0.0f);
            v0.y = fmaxf(g4.y * (v0.y - st.x) * st.y + b4.y, 0.0f);
            v0.z = fmaxf(g4.z * (v0.z - st.x) * st.y + b4.z, 0.0f);
            v0.w = fmaxf(g4.w * (v0.w - st.x) * st.y + b4.w, 0.0f);
        }
        if (c1) {
            float2 st = stats[r1];
            v1.x = fmaxf(g4.x * (v1.x - st.x) * st.y + b4.x, 0.0f);
            v1.y = fmaxf(g4.y * (v1.y - st.x) * st.y + b4.y, 0.0f);
            v1.z = fmaxf(g4.z * (v1.z - st.x) * st.y + b4.z, 0.0f);
            v1.w = fmaxf(g4.w * (v1.w - st.x) * st.y + b4.w, 0.0f);
        }
    }
    float4 o;
    o.x = (v0.x + v1.x) * dn; o.y = (v0.y + v1.y) * dn;
    o.z = (v0.z + v1.z) * dn; o.w = (v0.w + v1.w) * dn;
    *(float4*)(f3 + (long)bm * D_ + d) = o;
}

// ------------------------------------------------- cross-modal attention (parallel PV)
__global__ __launch_bounds__(512) void k_attn(const float* qv, const float* kk,
                                              const float* vv, float* ctx) {
    int bh = blockIdx.x;
    int b = bh >> 3, h = bh & 7;
    __shared__ float qs[DH_];
    __shared__ float sc[M2_];
    __shared__ float red[M2_];
    __shared__ float part[8][DH_];
    int m = threadIdx.x;
    if (m < DH_) qs[m] = qv[b * D_ + h * DH_ + m];
    __syncthreads();
    const float* kp = kk + (long)b * M2_ * D_ + h * DH_;
    float acc = 0.f;
    #pragma unroll
    for (int d = 0; d < DH_; d += 4) {
        float4 kv = *(const float4*)(kp + (long)m * D_ + d);
        acc += qs[d] * kv.x + qs[d + 1] * kv.y + qs[d + 2] * kv.z + qs[d + 3] * kv.w;
    }
    acc *= 0.125f;
    red[m] = acc; __syncthreads();
    for (int o = 256; o > 0; o >>= 1) { if (m < o) red[m] = fmaxf(red[m], red[m + o]); __syncthreads(); }
    float mx = red[0]; __syncthreads();
    float e = expf(acc - mx);
    sc[m] = e; red[m] = e; __syncthreads();
    for (int o = 256; o > 0; o >>= 1) { if (m < o) red[m] += red[m + o]; __syncthreads(); }
    float inv = 1.0f / red[0];
    int g = m >> 6, d = m & 63;
    const float* vp = vv + (long)b * M2_ * D_ + h * DH_ + d;
    float a2 = 0.f;
    #pragma unroll 4
    for (int mm = g * 64; mm < g * 64 + 64; mm++)
        a2 = fmaf(sc[mm], vp[(long)mm * D_], a2);
    part[g][d] = a2; __syncthreads();
    if (m < DH_) {
        float s = 0.f;
        #pragma unroll
        for (int g2 = 0; g2 < 8; g2++) s += part[g2][m];
        ctx[b * D_ + h * DH_ + m] = s * inv;
    }
}

// ------------------------------------------------- output head (Wo then W_cls), f32 out
__global__ __launch_bounds__(512) void k_head(const float* ctx, const float* Wo, const float* bo,
                                              const float* Wc, const float* bc,
                                              float* out) {
    int b = blockIdx.x, d = threadIdx.x;
    __shared__ float cl[D_], ol[D_];
    cl[d] = ctx[b * D_ + d]; __syncthreads();
    float acc = bo[d];
    for (int e = 0; e < D_; e++) acc = fmaf(cl[e], Wo[(long)e * D_ + d], acc);
    ol[d] = acc; __syncthreads();
    if (d < 4) {
        float a2 = bc[d];
        for (int e = 0; e < D_; e++) a2 = fmaf(ol[e], Wc[e * 4 + d], a2);
        out[b * 4 + d] = a2;
    }
}

// ---------------------------------------------------------------- launcher
extern "C" void kernel_launch(void* const* d_in, const int* in_sizes, int n_in,
                              void* d_out, int out_size, void* d_ws, size_t ws_size,
                              hipStream_t stream) {
    const float* bags = (const float*)d_in[0];
    const void*  kpm  = d_in[1];
    const int*   ids  = (const int*)d_in[2];
    const int*   am   = (const int*)d_in[3];
    const float* emb  = (const float*)d_in[4];
    const float* Wtp  = (const float*)d_in[5];
    const float* btp  = (const float*)d_in[6];
    const float* Wen  = (const float*)d_in[7];
    const float* ben  = (const float*)d_in[8];
    const float* lng  = (const float*)d_in[9];
    const float* lnb  = (const float*)d_in[10];
    const float* Wq   = (const float*)d_in[11];
    const float* bq   = (const float*)d_in[12];
    const float* Wk   = (const float*)d_in[13];
    const float* bk   = (const float*)d_in[14];
    const float* Wv   = (const float*)d_in[15];
    const float* bv   = (const float*)d_in[16];
    const float* Wo   = (const float*)d_in[17];
    const float* bo   = (const float*)d_in[18];
    const float* Wc   = (const float*)d_in[19];
    const float* bc   = (const float*)d_in[20];

    char* ws = (char*)d_ws;
    size_t o = 0;
    auto alloc = [&](size_t bytes) -> void* {
        void* p = ws + o; o += (bytes + 255) & ~(size_t)255; return p;
    };
    float* img  = (float*)alloc((size_t)NTOK_ * D_ * 4);
    float* rno  = (float*)alloc((size_t)NTOK_ * 4);
    float* rel  = (float*)alloc((size_t)NTOK_ * 4);
    int*   keep = (int*)alloc((size_t)NTOK_ * 4);
    unsigned char* vld = (unsigned char*)alloc(NTOK_);
    float* tf   = (float*)alloc(B_ * 768 * 4);
    float* te   = (float*)alloc(B_ * D_ * 4);
    float* qv   = (float*)alloc(B_ * D_ * 4);
    int*   idxo = (int*)alloc(B_ * LMAX_ * 4);
    float* f3   = (float*)alloc((size_t)B_ * M2_ * D_ * 4);
    float* kkb  = (float*)alloc((size_t)B_ * M2_ * D_ * 4);
    float* vvb  = (float*)alloc((size_t)B_ * M2_ * D_ * 4);
    float* ctx  = (float*)alloc(B_ * D_ * 4);
    int*   flag = (int*)alloc(256);
    float2* stats = (float2*)alloc((size_t)NTOK_ * 8);
    unsigned short* bth = (unsigned short*)alloc((size_t)D_ * F_ * 2);
    unsigned short* btl = (unsigned short*)alloc((size_t)D_ * F_ * 2);
    unsigned short* wkh = (unsigned short*)alloc((size_t)D_ * D_ * 2);
    unsigned short* wkl = (unsigned short*)alloc((size_t)D_ * D_ * 2);
    unsigned short* wvh = (unsigned short*)alloc((size_t)D_ * D_ * 2);
    unsigned short* wvl = (unsigned short*)alloc((size_t)D_ * D_ * 2);

    size_t fnb_need = (size_t)NTOK_ * D_ * 2 + 4096;
    bool newpath = (ws_size > o) && ((ws_size - o) >= fnb_need);
    unsigned short* fnb = nullptr;
    if (newpath) fnb = (unsigned short*)alloc((size_t)NTOK_ * D_ * 2);

    hipMemsetAsync(flag, 0, 4, stream);
    k_detect<<<64, 256, 0, stream>>>((const unsigned char*)kpm, NTOK_, flag);
    k_valid<<<(NTOK_ + 255) / 256, 256, 0, stream>>>(kpm, flag, vld);
    k_text_feat<<<B_, 256, 0, stream>>>(emb, ids, am, tf);
    k_rowmm<<<B_, 512, 0, stream>>>(tf, Wtp, btp, te, 768, 512);
    k_rowmm<<<B_, 512, 0, stream>>>(te, Wq, bq, qv, 512, 512);

    // weight prepasses (swizzled split): W_enc (E=1024), Wk/Wv (E=512)
    dim3 gw512(D_ / 32, D_ / 32);
    k_bsplit_sw<<<gw512, 256, 0, stream>>>(Wk, wkh, wkl, D_);
    k_bsplit_sw<<<gw512, 256, 0, stream>>>(Wv, wvh, wvl, D_);

    if (newpath) {
        dim3 gw1024(F_ / 32, D_ / 32);
        k_bsplit_sw<<<gw1024, 256, 0, stream>>>(Wen, bth, btl, F_);
        k_gemm3p<<<4096, 256, 0, stream>>>(bags, bth, btl, ben, img, F_);
    } else {
        dim3 gsplit(F_ / 32, D_ / 32);
        k_bsplit<<<gsplit, 256, 0, stream>>>(Wen, bth, btl);
        dim3 g3(NTOK_ / 64, 2);
        k_gemm_mfma<<<g3, 256, 0, stream>>>(bags, bth, btl, ben, img);
    }

    int write_img = newpath ? 0 : 1;
    k_ln<<<NTOK_ / 4, 256, 0, stream>>>(img, lng, lnb, te, rno, rel, fnb, stats, write_img);
    if (fnb) k_simg<<<NTOK_ / 128, 256, 0, stream>>>(fnb, vld, keep);
    else     k_sim<<<(NTOK_ + CHUNK - 1) / CHUNK, 256, 0, stream>>>(img, rno, vld, keep);
    k_topk<<<B_, 1024, 0, stream>>>(rel, keep, idxo);
    k_feat3<<<B_ * M2_, 128, 0, stream>>>(img, stats, lng, lnb, idxo, f3, newpath ? 1 : 0);

    k_gemmkv2<<<256, 256, 0, stream>>>(f3, wkh, wkl, bk, kkb, wvh, wvl, bv, vvb);

    k_attn<<<B_ * H_, 512, 0, stream>>>(qv, kkb, vvb, ctx);
    k_head<<<B_, 512, 0, stream>>>(ctx, Wo, bo, Wc, bc, (float*)d_out);
}

// Round 10
// 776.306 us; speedup vs baseline: 4.3992x; 1.1326x over previous
//
#include <hip/hip_runtime.h>
#include <hip/hip_bf16.h>
#include <math.h>
#include <stdint.h>

#define B_    8
#define N_    16384
#define F_    1024
#define D_    512
#define S_    64
#define H_    8
#define DH_   64
#define LMAX_ 1024
#define M2_   512
#define WIN_  32
#define NTOK_ (B_ * N_)   // 131072

typedef __attribute__((ext_vector_type(8)))  short bf16x8;
typedef __attribute__((ext_vector_type(16))) float f32x16;

// quad-swizzle (16B units) keyed by row low bits
#define S_OF(r) (((r) >> 1) & 3)

// ---------------------------------------------------------------- utilities
static __device__ __forceinline__ float wred_sum(float v) {
    #pragma unroll
    for (int d = 1; d < 64; d <<= 1) v += __shfl_xor(v, d, 64);
    return v;
}

static __device__ __forceinline__ void bf8_to_f32(uint4 q, float* a) {
    a[0] = __uint_as_float(q.x << 16); a[1] = __uint_as_float(q.x & 0xffff0000u);
    a[2] = __uint_as_float(q.y << 16); a[3] = __uint_as_float(q.y & 0xffff0000u);
    a[4] = __uint_as_float(q.z << 16); a[5] = __uint_as_float(q.z & 0xffff0000u);
    a[6] = __uint_as_float(q.w << 16); a[7] = __uint_as_float(q.w & 0xffff0000u);
}

static __device__ __forceinline__ unsigned short bf16r(float x) {   // RNE f32->bf16
    unsigned int b = __float_as_uint(x);
    return (unsigned short)((b + 0x7FFFu + ((b >> 16) & 1u)) >> 16);
}

static __device__ __forceinline__ void split_bf(float x, unsigned short& h, unsigned short& l) {
    unsigned int b = __float_as_uint(x);
    unsigned int hb = (b + 0x7FFFu + ((b >> 16) & 1u)) >> 16;
    h = (unsigned short)hb;
    float r = x - __uint_as_float(hb << 16);
    l = bf16r(r);
}

// cheap truncation split of 8 f32 -> hi/lo bf16x8 (in-register)
static __device__ __forceinline__ void split8(float4 f0, float4 f1, bf16x8& hi, bf16x8& lo) {
    float xs[8] = { f0.x, f0.y, f0.z, f0.w, f1.x, f1.y, f1.z, f1.w };
    unsigned int hp[4], lp[4];
    #pragma unroll
    for (int i = 0; i < 4; i++) {
        unsigned int b0 = __float_as_uint(xs[2*i]), b1 = __float_as_uint(xs[2*i+1]);
        hp[i] = (b0 >> 16) | (b1 & 0xffff0000u);
        float r0 = xs[2*i]   - __uint_as_float(b0 & 0xffff0000u);
        float r1 = xs[2*i+1] - __uint_as_float(b1 & 0xffff0000u);
        lp[i] = (__float_as_uint(r0) >> 16) | (__float_as_uint(r1) & 0xffff0000u);
    }
    union { uint4 u; bf16x8 v; } a, c;
    a.u = make_uint4(hp[0], hp[1], hp[2], hp[3]);
    c.u = make_uint4(lp[0], lp[1], lp[2], lp[3]);
    hi = a.v; lo = c.v;
}

static __device__ __forceinline__ void gll16(const void* g, void* l) {
    __builtin_amdgcn_global_load_lds(
        (const __attribute__((address_space(1))) unsigned int*)g,
        (__attribute__((address_space(3))) unsigned int*)l, 16, 0, 0);
}

// ------------------------------------------------- mask layout detection
__global__ void k_detect(const unsigned char* mb, int nbytes, int* flag) {
    int found = 0;
    for (int i = blockIdx.x * blockDim.x + threadIdx.x; i < nbytes; i += gridDim.x * blockDim.x)
        if ((i & 3) && mb[i]) found = 1;
    if (found) atomicOr(flag, 1);
}

__global__ void k_valid(const void* maskp, const int* flag, unsigned char* v) {
    int i = blockIdx.x * 256 + threadIdx.x;
    if (i >= NTOK_) return;
    int pad;
    if (*flag) pad = (((const unsigned char*)maskp)[i] != 0);
    else       pad = (((const int*)maskp)[i] != 0);
    v[i] = pad ? 0 : 1;
}

// ------------------------------------------------- fused text chain: feat -> te -> qv
__global__ __launch_bounds__(512) void k_text(const float* emb, const int* ids, const int* am,
                                              const float* Wtp, const float* btp,
                                              const float* Wq, const float* bq,
                                              float* te, float* qv) {
    int b = blockIdx.x, t = threadIdx.x;
    __shared__ int   sid[S_];
    __shared__ float sam[S_];
    __shared__ float tfl[768];
    __shared__ float tel[D_];
    if (t < S_) { sid[t] = ids[b * S_ + t]; sam[t] = (float)am[b * S_ + t]; }
    __syncthreads();
    float asum = 0.f;
    for (int s = 0; s < S_; s++) asum += sam[s];
    float denom = fmaxf(asum, 1.0f);
    for (int d = t; d < 768; d += 512) {
        float acc = 0.f;
        for (int s = 0; s < S_; s++) acc += emb[(long)sid[s] * 768 + d] * sam[s];
        tfl[d] = acc / denom;
    }
    __syncthreads();
    {
        float acc = btp[t];
        for (int e = 0; e < 768; e++) acc = fmaf(tfl[e], Wtp[(long)e * D_ + t], acc);
        tel[t] = acc;
        te[b * D_ + t] = acc;
    }
    __syncthreads();
    {
        float acc = bq[t];
        for (int e = 0; e < D_; e++) acc = fmaf(tel[e], Wq[(long)e * D_ + t], acc);
        qv[b * D_ + t] = acc;
    }
}

// ------------------------------------------------- weight transpose + split (swizzled) body
static __device__ __forceinline__ void wsplit_body(const float* __restrict__ W,
                                                   unsigned short* __restrict__ bh,
                                                   unsigned short* __restrict__ bl,
                                                   int E, int e0, int d0) {
    __shared__ float tile[32][33];
    int t = threadIdx.x;
    int r = t >> 3, c4 = (t & 7) * 4;
    float4 v = *(const float4*)(W + (long)(e0 + r) * D_ + d0 + c4);
    tile[r][c4] = v.x; tile[r][c4 + 1] = v.y; tile[r][c4 + 2] = v.z; tile[r][c4 + 3] = v.w;
    __syncthreads();
    if (t < 128) {
        int c = t & 31, kq = t >> 5;
        int col = d0 + c;
        float xs[8];
        #pragma unroll
        for (int i = 0; i < 8; i++) xs[i] = tile[kq * 8 + i][c];
        unsigned short h[8], l[8];
        #pragma unroll
        for (int i = 0; i < 8; i++) split_bf(xs[i], h[i], l[i]);
        uint4 ph, pl;
        ph.x = h[0] | ((unsigned)h[1] << 16); ph.y = h[2] | ((unsigned)h[3] << 16);
        ph.z = h[4] | ((unsigned)h[5] << 16); ph.w = h[6] | ((unsigned)h[7] << 16);
        pl.x = l[0] | ((unsigned)l[1] << 16); pl.y = l[2] | ((unsigned)l[3] << 16);
        pl.z = l[4] | ((unsigned)l[5] << 16); pl.w = l[6] | ((unsigned)l[7] << 16);
        int Q = (e0 >> 3) + kq;
        int Qo = (Q & ~3) | ((Q & 3) ^ S_OF(col & 7));
        *(uint4*)(bh + (long)col * E + Qo * 8) = ph;
        *(uint4*)(bl + (long)col * E + Qo * 8) = pl;
    }
}

__global__ __launch_bounds__(256) void k_bsplit_sw(const float* __restrict__ W,
                                                   unsigned short* __restrict__ bh,
                                                   unsigned short* __restrict__ bl,
                                                   int E) {
    wsplit_body(W, bh, bl, E, blockIdx.x * 32, blockIdx.y * 32);
}

// one launch for all three weight splits: Wen (512 blocks), Wk (256), Wv (256)
__global__ __launch_bounds__(256) void k_wsplit(const float* Wen, unsigned short* eh, unsigned short* el,
                                                const float* Wk2, unsigned short* kh, unsigned short* kl,
                                                const float* Wv2, unsigned short* vh, unsigned short* vl) {
    int bid = blockIdx.x;
    if (bid < 512) {
        wsplit_body(Wen, eh, el, 1024, (bid >> 4) * 32, (bid & 15) * 32);
    } else if (bid < 768) {
        int i = bid - 512;
        wsplit_body(Wk2, kh, kl, 512, (i >> 4) * 32, (i & 15) * 32);
    } else {
        int i = bid - 768;
        wsplit_body(Wv2, vh, vl, 512, (i >> 4) * 32, (i & 15) * 32);
    }
}

// ------------------------------------------------- gll GEMM body, A raw f32 + in-reg split
// Tile 128x128, BK=32, 4 waves, single 32 KB buffer. Wave w computes ROW-STRIPE
// w*32 (all 128 cols): each A fragment split by exactly ONE wave (no duplicate
// split VALU). C stride fixed 512, 4 bn tiles.
static __device__ __forceinline__ void gemm3_body(const float* __restrict__ A,
                                                  const unsigned short* __restrict__ Bh2,
                                                  const unsigned short* __restrict__ Bl2,
                                                  const float* __restrict__ bias,
                                                  float* __restrict__ C, int K, int wg) {
    __shared__ __align__(16) float ldsA[128][32];              // 16 KiB
    __shared__ __align__(16) unsigned short ldsB[2][128][32];  // 16 KiB
    int bn = wg & 3, bm = wg >> 2;
    int tid = threadIdx.x;
    int w = tid >> 6, lane = tid & 63;
    int r32 = lane & 31, kg = lane >> 5;
    int s8 = r32 & 7;

    const float* agbase = nullptr;
    const unsigned short* bgbase = nullptr;
    if (w < 2) {
        int rl = lane >> 3, qs = lane & 7;
        agbase = A + (long)(bm * 128 + w * 64 + rl) * K + ((qs ^ rl) * 4);
    } else {
        const unsigned short* plane = (w == 2) ? Bh2 : Bl2;
        int lrow = lane >> 2, lq = lane & 3;
        bgbase = plane + (long)(bn * 128 + lrow) * K + lq * 8;
    }

    f32x16 acc[4];
    #pragma unroll
    for (int j = 0; j < 4; j++)
        #pragma unroll
        for (int r = 0; r < 16; r++) acc[j][r] = 0.f;

    int ar = w * 32 + r32;                    // this wave's A row; ar&7 == s8

    for (int kt = 0; kt < K; kt += 32) {
        if (w < 2) {
            #pragma unroll
            for (int j = 0; j < 8; j++)
                gll16(agbase + (long)j * 8 * K + kt, &ldsA[w * 64 + j * 8][0]);
        } else {
            #pragma unroll
            for (int j = 0; j < 8; j++)
                gll16(bgbase + (long)j * 16 * K + kt, &ldsB[w - 2][j * 16][0]);
        }
        __syncthreads();
        #pragma unroll
        for (int k2 = 0; k2 < 2; k2++) {
            int qA = k2 * 4 + kg * 2;
            int qs0 = (qA ^ s8) * 4;
            int qs1 = ((qA + 1) ^ s8) * 4;
            bf16x8 a_h, a_l;
            {
                float4 f0 = *(const float4*)&ldsA[ar][qs0];
                float4 f1 = *(const float4*)&ldsA[ar][qs1];
                split8(f0, f1, a_h, a_l);
            }
            int qb = k2 * 2 + kg;
            int q = (qb ^ S_OF(r32)) * 8;
            bf16x8 b_h[4], b_l[4];
            #pragma unroll
            for (int cf = 0; cf < 4; cf++) {
                int bc = cf * 32 + r32;
                b_h[cf] = *(const bf16x8*)&ldsB[0][bc][q];
                b_l[cf] = *(const bf16x8*)&ldsB[1][bc][q];
            }
            #pragma unroll
            for (int cf = 0; cf < 4; cf++) {
                acc[cf] = __builtin_amdgcn_mfma_f32_32x32x16_bf16(a_h, b_h[cf], acc[cf], 0, 0, 0);
                acc[cf] = __builtin_amdgcn_mfma_f32_32x32x16_bf16(a_h, b_l[cf], acc[cf], 0, 0, 0);
                acc[cf] = __builtin_amdgcn_mfma_f32_32x32x16_bf16(a_l, b_h[cf], acc[cf], 0, 0, 0);
            }
        }
        __syncthreads();
    }
    #pragma unroll
    for (int cf = 0; cf < 4; cf++) {
        int col = bn * 128 + cf * 32 + r32;
        float bv = bias[col];
        #pragma unroll
        for (int r = 0; r < 16; r++) {
            int row = bm * 128 + w * 32 + (r & 3) + 8 * (r >> 2) + 4 * kg;
            C[(long)row * D_ + col] = acc[cf][r] + bv;
        }
    }
}

__global__ __launch_bounds__(256) void k_gemm3p(const float* __restrict__ A,
                                                const unsigned short* __restrict__ Bh2,
                                                const unsigned short* __restrict__ Bl2,
                                                const float* __restrict__ bias,
                                                float* __restrict__ C, int K) {
    int bid = blockIdx.x;
    int cpx = gridDim.x >> 3;                 // gridDim.x % 8 == 0 (4096)
    int wg = (bid & 7) * cpx + (bid >> 3);    // bijective XCD chunking
    gemm3_body(A, Bh2, Bl2, bias, C, K, wg);
}

// K and V projections in one launch: 256 blocks, which = bid&1
__global__ __launch_bounds__(256) void k_gemmkv2(const float* __restrict__ A,
                                                 const unsigned short* __restrict__ Kh, const unsigned short* __restrict__ Kl,
                                                 const float* __restrict__ bk2, float* __restrict__ Ck,
                                                 const unsigned short* __restrict__ Vh, const unsigned short* __restrict__ Vl,
                                                 const float* __restrict__ bv2, float* __restrict__ Cv) {
    int which = blockIdx.x & 1;
    int wg = blockIdx.x >> 1;                 // 0..127 -> bm 0..31, bn 0..3
    if (which)
        gemm3_body(A, Vh, Vl, bv2, Cv, 512, wg);
    else
        gemm3_body(A, Kh, Kl, bk2, Ck, 512, wg);
}

// ------------------------------------------------- fallback fused split GEMM (round-4)
#define GPAD 40
__global__ __launch_bounds__(256, 3) void k_gemm_mfma(const float* __restrict__ A,
                                                      const unsigned short* __restrict__ Bth,
                                                      const unsigned short* __restrict__ Btl,
                                                      const float* __restrict__ bias,
                                                      float* __restrict__ C) {
    __shared__ __align__(16) unsigned short As[2][64][GPAD];
    __shared__ __align__(16) unsigned short Bs[2][256][GPAD];
    int bm = blockIdx.x, bn = blockIdx.y;
    int tid = threadIdx.x;
    int w = tid >> 6, lane = tid & 63;
    int r32 = lane & 31, kg = lane >> 5;
    f32x16 acc[2][2];
    #pragma unroll
    for (int i = 0; i < 2; i++)
        #pragma unroll
        for (int j = 0; j < 2; j++)
            #pragma unroll
            for (int r = 0; r < 16; r++) acc[i][j][r] = 0.f;
    int arow = tid >> 2, aq = tid & 3;
    const float* abase = A + (long)(bm * 64 + arow) * 1024 + aq * 8;
    const unsigned short* bhbase = Bth + (long)(bn * 256 + tid) * 1024;
    const unsigned short* blbase = Btl + (long)(bn * 256 + tid) * 1024;
    float4 pa0 = *(const float4*)abase;
    float4 pa1 = *(const float4*)(abase + 4);
    for (int kt = 0; kt < 1024; kt += 32) {
        {
            float xs[8] = { pa0.x, pa0.y, pa0.z, pa0.w, pa1.x, pa1.y, pa1.z, pa1.w };
            unsigned short h[8], l[8];
            #pragma unroll
            for (int i = 0; i < 8; i++) split_bf(xs[i], h[i], l[i]);
            uint4 ph, pl;
            ph.x = h[0] | ((unsigned)h[1] << 16); ph.y = h[2] | ((unsigned)h[3] << 16);
            ph.z = h[4] | ((unsigned)h[5] << 16); ph.w = h[6] | ((unsigned)h[7] << 16);
            pl.x = l[0] | ((unsigned)l[1] << 16); pl.y = l[2] | ((unsigned)l[3] << 16);
            pl.z = l[4] | ((unsigned)l[5] << 16); pl.w = l[6] | ((unsigned)l[7] << 16);
            *(uint4*)&As[0][arow][aq * 8] = ph;
            *(uint4*)&As[1][arow][aq * 8] = pl;
        }
        {
            const uint4* ph = (const uint4*)(bhbase + kt);
            const uint4* pl = (const uint4*)(blbase + kt);
            #pragma unroll
            for (int q = 0; q < 4; q++) {
                *(uint4*)&Bs[0][tid][q * 8] = ph[q];
                *(uint4*)&Bs[1][tid][q * 8] = pl[q];
            }
        }
        __syncthreads();
        if (kt + 32 < 1024) {
            const float* ap = abase + kt + 32;
            pa0 = *(const float4*)ap;
            pa1 = *(const float4*)(ap + 4);
        }
        #pragma unroll
        for (int k2 = 0; k2 < 2; k2++) {
            int ko = k2 * 16 + kg * 8;
            bf16x8 ah[2], al[2], bh[2], blv[2];
            #pragma unroll
            for (int rf = 0; rf < 2; rf++) {
                ah[rf] = *(const bf16x8*)&As[0][rf * 32 + r32][ko];
                al[rf] = *(const bf16x8*)&As[1][rf * 32 + r32][ko];
            }
            #pragma unroll
            for (int cf = 0; cf < 2; cf++) {
                bh[cf]  = *(const bf16x8*)&Bs[0][w * 64 + cf * 32 + r32][ko];
                blv[cf] = *(const bf16x8*)&Bs[1][w * 64 + cf * 32 + r32][ko];
            }
            #pragma unroll
            for (int rf = 0; rf < 2; rf++)
                #pragma unroll
                for (int cf = 0; cf < 2; cf++) {
                    acc[rf][cf] = __builtin_amdgcn_mfma_f32_32x32x16_bf16(ah[rf], bh[cf],  acc[rf][cf], 0, 0, 0);
                    acc[rf][cf] = __builtin_amdgcn_mfma_f32_32x32x16_bf16(ah[rf], blv[cf], acc[rf][cf], 0, 0, 0);
                    acc[rf][cf] = __builtin_amdgcn_mfma_f32_32x32x16_bf16(al[rf], bh[cf],  acc[rf][cf], 0, 0, 0);
                }
        }
        __syncthreads();
    }
    #pragma unroll
    for (int rf = 0; rf < 2; rf++)
        #pragma unroll
        for (int cf = 0; cf < 2; cf++) {
            int col = bn * 256 + w * 64 + cf * 32 + r32;
            float bv = bias[col];
            #pragma unroll
            for (int r = 0; r < 16; r++) {
                int row = bm * 64 + rf * 32 + (r & 3) + 8 * (r >> 2) + 4 * kg;
                C[(long)row * D_ + col] = acc[rf][cf][r] + bv;
            }
        }
}

// old unswizzled bsplit (fallback path)
__global__ __launch_bounds__(256) void k_bsplit(const float* __restrict__ W,
                                                unsigned short* __restrict__ bh,
                                                unsigned short* __restrict__ bl) {
    __shared__ float tile[32][33];
    int e0 = blockIdx.x * 32;
    int d0 = blockIdx.y * 32;
    int t = threadIdx.x;
    int r = t >> 3;
    int c = (t & 7) * 4;
    float4 v = *(const float4*)(W + (long)(e0 + r) * D_ + d0 + c);
    tile[r][c] = v.x; tile[r][c + 1] = v.y; tile[r][c + 2] = v.z; tile[r][c + 3] = v.w;
    __syncthreads();
    ushort4 h4, l4;
    unsigned short hh, ll;
    float x0 = tile[c + 0][r], x1 = tile[c + 1][r], x2 = tile[c + 2][r], x3 = tile[c + 3][r];
    split_bf(x0, hh, ll); h4.x = hh; l4.x = ll;
    split_bf(x1, hh, ll); h4.y = hh; l4.y = ll;
    split_bf(x2, hh, ll); h4.z = hh; l4.z = ll;
    split_bf(x3, hh, ll); h4.w = hh; l4.w = ll;
    *(ushort4*)(bh + (long)(d0 + r) * 1024 + e0 + c) = h4;
    *(ushort4*)(bl + (long)(d0 + r) * 1024 + e0 + c) = l4;
}

// ------------------------------------------------- LayerNorm+ReLU + rnorm + rel (+fnb, +stats)
__global__ __launch_bounds__(256) void k_ln(float* h, const float* g, const float* bb,
                                            const float* temb, float* rnorm, float* rel,
                                            unsigned short* fnb, float2* stats, int write_img) {
    int wid = threadIdx.x >> 6, lane = threadIdx.x & 63;
    long row = (long)blockIdx.x * 4 + wid;
    int b = (int)(row >> 14);
    float* hp = h + row * (long)D_;
    int c0 = lane * 4, c1 = 256 + lane * 4;
    float4 x0 = *(float4*)(hp + c0);
    float4 x1 = *(float4*)(hp + c1);
    float x[8] = { x0.x, x0.y, x0.z, x0.w, x1.x, x1.y, x1.z, x1.w };
    float s = 0.f;
    #pragma unroll
    for (int i = 0; i < 8; i++) s += x[i];
    s = wred_sum(s);
    float mu = s * (1.0f / 512.0f);
    float var = 0.f;
    #pragma unroll
    for (int i = 0; i < 8; i++) { float d = x[i] - mu; var += d * d; }
    var = wred_sum(var) * (1.0f / 512.0f);
    float inv = 1.0f / sqrtf(var + 1e-5f);
    float4 g0 = *(const float4*)(g + c0), g1 = *(const float4*)(g + c1);
    float4 b0 = *(const float4*)(bb + c0), b1 = *(const float4*)(bb + c1);
    float gg[8] = { g0.x, g0.y, g0.z, g0.w, g1.x, g1.y, g1.z, g1.w };
    float bbv[8] = { b0.x, b0.y, b0.z, b0.w, b1.x, b1.y, b1.z, b1.w };
    float y[8], sq = 0.f;
    #pragma unroll
    for (int i = 0; i < 8; i++) {
        y[i] = fmaxf(gg[i] * (x[i] - mu) * inv + bbv[i], 0.0f);
        sq += y[i] * y[i];
    }
    if (write_img) {
        float4 o0 = { y[0], y[1], y[2], y[3] }, o1 = { y[4], y[5], y[6], y[7] };
        *(float4*)(hp + c0) = o0;
        *(float4*)(hp + c1) = o1;
    }
    sq = wred_sum(sq);
    float rn = 1.0f / (sqrtf(sq) + 1e-8f);
    if (fnb) {
        ushort4 u0, u1;
        u0.x = bf16r(y[0] * rn); u0.y = bf16r(y[1] * rn);
        u0.z = bf16r(y[2] * rn); u0.w = bf16r(y[3] * rn);
        u1.x = bf16r(y[4] * rn); u1.y = bf16r(y[5] * rn);
        u1.z = bf16r(y[6] * rn); u1.w = bf16r(y[7] * rn);
        *(ushort4*)(fnb + row * D_ + c0) = u0;
        *(ushort4*)(fnb + row * D_ + c1) = u1;
    }
    const float* tp = temb + (long)b * D_;
    float4 t0 = *(const float4*)(tp + c0), t1 = *(const float4*)(tp + c1);
    float tt[8] = { t0.x, t0.y, t0.z, t0.w, t1.x, t1.y, t1.z, t1.w };
    float rl = 0.f;
    #pragma unroll
    for (int i = 0; i < 8; i++) rl = fmaf(y[i], tt[i], rl);
    rl = wred_sum(rl);
    if (lane == 0) { rnorm[row] = rn; rel[row] = rl; stats[row] = make_float2(mu, inv); }
}

// ------------------------------------------------- sliding-window cosine pruning via MFMA band
__global__ __launch_bounds__(256) void k_simg(const unsigned short* __restrict__ fnb,
                                              const unsigned char* __restrict__ vld,
                                              int* __restrict__ keep) {
    int wid = threadIdx.x >> 6, lane = threadIdx.x & 63;
    int T = (blockIdx.x * 4 + wid) * 32;
    int r32 = lane & 31, kg = lane >> 5;
    int prevok = (T & (N_ - 1)) != 0;
    const unsigned short* arow  = fnb + (long)(T + r32) * D_ + kg * 8;
    const unsigned short* b0row = fnb + (long)((prevok ? T - 32 : T) + r32) * D_ + kg * 8;

    f32x16 g0, g1;
    #pragma unroll
    for (int r = 0; r < 16; r++) { g0[r] = 0.f; g1[r] = 0.f; }
    #pragma unroll 4
    for (int kt = 0; kt < D_; kt += 16) {
        bf16x8 a  = *(const bf16x8*)(arow + kt);
        bf16x8 b0 = *(const bf16x8*)(b0row + kt);
        g0 = __builtin_amdgcn_mfma_f32_32x32x16_bf16(a, b0, g0, 0, 0, 0);
        g1 = __builtin_amdgcn_mfma_f32_32x32x16_bf16(a, a,  g1, 0, 0, 0);
    }
    int okc0 = prevok ? (int)vld[T - 32 + r32] : 0;
    int okc1 = (int)vld[T + r32];
    float ms[16];
    #pragma unroll
    for (int r = 0; r < 16; r++) {
        int i = (r & 3) + 8 * (r >> 2) + 4 * kg;
        float v = -INFINITY;
        if (okc0 && r32 >= i) v = g0[r];
        if (okc1 && r32 < i)  v = fmaxf(v, g1[r]);
        #pragma unroll
        for (int d = 1; d < 32; d <<= 1) v = fmaxf(v, __shfl_xor(v, d, 64));
        ms[r] = v;
    }
    if (r32 == 0) {
        #pragma unroll
        for (int r = 0; r < 16; r++) {
            int i = (r & 3) + 8 * (r >> 2) + 4 * kg;
            int t = T + i;
            keep[t] = (vld[t] && ms[r] < 0.7f) ? 1 : 0;
        }
    }
}

// ------------------------------------------------- fallback sliding-window (no fnb space)
#define CHUNK 28
#define KROWS 60
__global__ __launch_bounds__(256) void k_sim(const float* img, const float* rnorm,
                                             const unsigned char* vld, int* keep) {
    __shared__ __hip_bfloat16 fnbs[KROWS][D_];
    long c0 = (long)blockIdx.x * CHUNK;
    int tid = threadIdx.x;
    for (int idx = tid; idx < KROWS * (D_ / 8); idx += 256) {
        int rr = idx / (D_ / 8);
        int cc = (idx % (D_ / 8)) * 8;
        long grow = c0 - WIN_ + rr;
        if (grow < 0) grow = 0;
        if (grow >= NTOK_) grow = NTOK_ - 1;
        float rn = rnorm[grow];
        const float* p = img + grow * (long)D_ + cc;
        float4 u = *(const float4*)p, w = *(const float4*)(p + 4);
        fnbs[rr][cc + 0] = __float2bfloat16(u.x * rn);
        fnbs[rr][cc + 1] = __float2bfloat16(u.y * rn);
        fnbs[rr][cc + 2] = __float2bfloat16(u.z * rn);
        fnbs[rr][cc + 3] = __float2bfloat16(u.w * rn);
        fnbs[rr][cc + 4] = __float2bfloat16(w.x * rn);
        fnbs[rr][cc + 5] = __float2bfloat16(w.y * rn);
        fnbs[rr][cc + 6] = __float2bfloat16(w.z * rn);
        fnbs[rr][cc + 7] = __float2bfloat16(w.w * rn);
    }
    __syncthreads();
    int wid = tid >> 6, lane = tid & 63;
    for (int ti = 0; ti < 7; ti++) {
        int tloc = wid * 7 + ti;
        long t = c0 + tloc;
        if (t >= NTOK_) continue;
        int lr = WIN_ + tloc;
        int tl = (int)(t & (N_ - 1));
        float a[8];
        bf8_to_f32(*(const uint4*)&fnbs[lr][lane * 8], a);
        int wmax = tl < WIN_ ? tl : WIN_;
        float msim = -INFINITY;
        for (int w = 1; w <= wmax; w++) {
            if (!vld[t - w]) continue;
            float bvv[8];
            bf8_to_f32(*(const uint4*)&fnbs[lr - w][lane * 8], bvv);
            float p = 0.f;
            #pragma unroll
            for (int i = 0; i < 8; i++) p = fmaf(a[i], bvv[i], p);
            p = wred_sum(p);
            msim = fmaxf(msim, p);
        }
        int kp = (vld[t] && (msim < 0.7f)) ? 1 : 0;
        if (lane == 0) keep[t] = kp;
    }
}

// ------------------------------------------------- per-batch exact top-k (radix select)
static __device__ void scan1024(int* tot, int tid) {
    if (tid < 64) {
        int vals[16], s = 0;
        #pragma unroll
        for (int i = 0; i < 16; i++) vals[i] = tot[tid * 16 + i];
        #pragma unroll
        for (int i = 0; i < 16; i++) { int t = vals[i]; vals[i] = s; s += t; }
        int inc = s;
        #pragma unroll
        for (int d = 1; d < 64; d <<= 1) {
            int v = __shfl_up(inc, d, 64);
            if ((tid & 63) >= d) inc += v;
        }
        int excl = inc - s;
        #pragma unroll
        for (int i = 0; i < 16; i++) tot[tid * 16 + i] = vals[i] + excl;
    }
}

__global__ __launch_bounds__(1024) void k_topk(const float* rel, const int* keep, int* idxo) {
    int b = blockIdx.x, tid = threadIdx.x;
    const float* relb = rel + (long)b * N_;
    const int* keepb  = keep + (long)b * N_;
    __shared__ unsigned int hist[256];
    __shared__ unsigned int suf[256];
    __shared__ int toti[1024];
    __shared__ int wsum[16];
    __shared__ unsigned int s_prefix;
    __shared__ int s_rem, s_k;

    unsigned int key[16];
    int base = tid * 16, nk_local = 0;
    #pragma unroll
    for (int j = 0; j < 16; j++) {
        int i = base + j;
        float r = relb[i];
        int kp = keepb[i];
        unsigned int bits = __float_as_uint(r);
        unsigned int kk = (bits & 0x80000000u) ? ~bits : (bits | 0x80000000u);
        key[j] = kp ? kk : 0u;
        nk_local += kp;
    }
    int nk = nk_local;
    #pragma unroll
    for (int d = 1; d < 64; d <<= 1) nk += __shfl_xor(nk, d, 64);
    if ((tid & 63) == 0) wsum[tid >> 6] = nk;
    __syncthreads();
    if (tid == 0) {
        int n_kept = 0;
        #pragma unroll
        for (int i = 0; i < 16; i++) n_kept += wsum[i];
        int k = (int)(0.8f * (float)n_kept);
        if (k < 1) k = 1; if (k > LMAX_) k = LMAX_;
        s_k = k; s_rem = k; s_prefix = 0u;
    }
    __syncthreads();

    for (int pass = 0; pass < 4; pass++) {
        int shift = 24 - pass * 8;
        unsigned int himask = (pass == 0) ? 0u : (0xFFFFFFFFu << (shift + 8));
        if (tid < 256) hist[tid] = 0u;
        __syncthreads();
        unsigned int pfx = s_prefix;
        int rem = s_rem;
        #pragma unroll
        for (int j = 0; j < 16; j++) {
            unsigned int kk = key[j];
            if ((kk & himask) == (pfx & himask))
                atomicAdd(&hist[(kk >> shift) & 255], 1u);
        }
        __syncthreads();
        if (tid < 256) suf[tid] = hist[tid];
        __syncthreads();
        for (int o = 1; o < 256; o <<= 1) {
            unsigned int v = 0;
            if (tid < 256 && tid + o < 256) v = suf[tid + o];
            __syncthreads();
            if (tid < 256) suf[tid] += v;
            __syncthreads();
        }
        if (tid < 256) {
            unsigned int sv = suf[tid];
            unsigned int nxt = (tid == 255) ? 0u : suf[tid + 1];
            if (sv >= (unsigned int)rem && nxt < (unsigned int)rem) {
                s_prefix = pfx | ((unsigned int)tid << shift);
                s_rem = rem - (int)nxt;
            }
        }
        __syncthreads();
    }
    unsigned int T = s_prefix;
    int tie_need = s_rem, k = s_k;

    int eq[16], gt[16], eqpre[16];
    int locEq = 0;
    #pragma unroll
    for (int j = 0; j < 16; j++) {
        eq[j] = (key[j] == T); gt[j] = (key[j] > T);
        eqpre[j] = locEq; locEq += eq[j];
    }
    toti[tid] = locEq; __syncthreads();
    scan1024(toti, tid); __syncthreads();
    int eqoff = toti[tid];

    int sel[16], spre[16];
    int locS = 0;
    #pragma unroll
    for (int j = 0; j < 16; j++) {
        int rank = eqoff + eqpre[j];
        sel[j] = gt[j] || (eq[j] && rank < tie_need);
        spre[j] = locS; locS += sel[j];
    }
    __syncthreads();
    toti[tid] = locS; __syncthreads();
    scan1024(toti, tid); __syncthreads();
    int soff = toti[tid];
    #pragma unroll
    for (int j = 0; j < 16; j++)
        if (sel[j]) idxo[b * LMAX_ + soff + spre[j]] = base + j;
    for (int p = k + tid; p < LMAX_; p += 1024) idxo[b * LMAX_ + p] = N_;
}

// ------------------------------------------------- feat2 gather + pair pooling
__global__ void k_feat3(const float* img, const float2* stats, const float* lng,
                        const float* lnb, const int* idxo, float* f3, int recompute) {
    int bm = blockIdx.x;
    int b = bm >> 9, m = bm & 511;
    int i0 = idxo[b * LMAX_ + 2 * m], i1 = idxo[b * LMAX_ + 2 * m + 1];
    int c0 = i0 < N_, c1 = i1 < N_;
    float dn = 1.0f / fmaxf((float)(c0 + c1), 1.0f);
    long r0 = (long)b * N_ + (c0 ? i0 : 0);
    long r1 = (long)b * N_ + (c1 ? i1 : 0);
    int d = threadIdx.x * 4;
    float4 v0 = c0 ? *(const float4*)(img + r0 * D_ + d) : make_float4(0.f, 0.f, 0.f, 0.f);
    float4 v1 = c1 ? *(const float4*)(img + r1 * D_ + d) : make_float4(0.f, 0.f, 0.f, 0.f);
    if (recompute) {
        float4 g4 = *(const float4*)(lng + d);
        float4 b4 = *(const float4*)(lnb + d);
        if (c0) {
            float2 st = stats[r0];
            v0.x = fmaxf(g4.x * (v0.x - st.x) * st.y + b4.x, 0.0f);
            v0.y = fmaxf(g4.y * (v0.y - st.x) * st.y + b4.y, 0.0f);
            v0.z = fmaxf(g4.z * (v0.z - st.x) * st.y + b4.z, 0.0f);
            v0.w = fmaxf(g4.w * (v0.w - st.x) * st.y + b4.w, 0.0f);
        }
        if (c1) {
            float2 st = stats[r1];
            v1.x = fmaxf(g4.x * (v1.x - st.x) * st.y + b4.x, 0.0f);
            v1.y = fmaxf(g4.y * (v1.y - st.x) * st.y + b4.y, 0.0f);
            v1.z = fmaxf(g4.z * (v1.z - st.x) * st.y + b4.z, 0.0f);
            v1.w = fmaxf(g4.w * (v1.w - st.x) * st.y + b4.w, 0.0f);
        }
    }
    float4 o;
    o.x = (v0.x + v1.x) * dn; o.y = (v0.y + v1.y) * dn;
    o.z = (v0.z + v1.z) * dn; o.w = (v0.w + v1.w) * dn;
    *(float4*)(f3 + (long)bm * D_ + d) = o;
}

// ------------------------------------------------- cross-modal attention (parallel PV)
__global__ __launch_bounds__(512) void k_attn(const float* qv, const float* kk,
                                              const float* vv, float* ctx) {
    int bh = blockIdx.x;
    int b = bh >> 3, h = bh & 7;
    __shared__ float qs[DH_];
    __shared__ float sc[M2_];
    __shared__ float red[M2_];
    __shared__ float part[8][DH_];
    int m = threadIdx.x;
    if (m < DH_) qs[m] = qv[b * D_ + h * DH_ + m];
    __syncthreads();
    const float* kp = kk + (long)b * M2_ * D_ + h * DH_;
    float acc = 0.f;
    #pragma unroll
    for (int d = 0; d < DH_; d += 4) {
        float4 kv = *(const float4*)(kp + (long)m * D_ + d);
        acc += qs[d] * kv.x + qs[d + 1] * kv.y + qs[d + 2] * kv.z + qs[d + 3] * kv.w;
    }
    acc *= 0.125f;
    red[m] = acc; __syncthreads();
    for (int o = 256; o > 0; o >>= 1) { if (m < o) red[m] = fmaxf(red[m], red[m + o]); __syncthreads(); }
    float mx = red[0]; __syncthreads();
    float e = expf(acc - mx);
    sc[m] = e; red[m] = e; __syncthreads();
    for (int o = 256; o > 0; o >>= 1) { if (m < o) red[m] += red[m + o]; __syncthreads(); }
    float inv = 1.0f / red[0];
    int g = m >> 6, d = m & 63;
    const float* vp = vv + (long)b * M2_ * D_ + h * DH_ + d;
    float a2 = 0.f;
    #pragma unroll 4
    for (int mm = g * 64; mm < g * 64 + 64; mm++)
        a2 = fmaf(sc[mm], vp[(long)mm * D_], a2);
    part[g][d] = a2; __syncthreads();
    if (m < DH_) {
        float s = 0.f;
        #pragma unroll
        for (int g2 = 0; g2 < 8; g2++) s += part[g2][m];
        ctx[b * D_ + h * DH_ + m] = s * inv;
    }
}

// ------------------------------------------------- output head (Wo then W_cls), f32 out
__global__ __launch_bounds__(512) void k_head(const float* ctx, const float* Wo, const float* bo,
                                              const float* Wc, const float* bc,
                                              float* out) {
    int b = blockIdx.x, d = threadIdx.x;
    __shared__ float cl[D_], ol[D_];
    cl[d] = ctx[b * D_ + d]; __syncthreads();
    float acc = bo[d];
    for (int e = 0; e < D_; e++) acc = fmaf(cl[e], Wo[(long)e * D_ + d], acc);
    ol[d] = acc; __syncthreads();
    if (d < 4) {
        float a2 = bc[d];
        for (int e = 0; e < D_; e++) a2 = fmaf(ol[e], Wc[e * 4 + d], a2);
        out[b * 4 + d] = a2;
    }
}

// ---------------------------------------------------------------- launcher
extern "C" void kernel_launch(void* const* d_in, const int* in_sizes, int n_in,
                              void* d_out, int out_size, void* d_ws, size_t ws_size,
                              hipStream_t stream) {
    const float* bags = (const float*)d_in[0];
    const void*  kpm  = d_in[1];
    const int*   ids  = (const int*)d_in[2];
    const int*   am   = (const int*)d_in[3];
    const float* emb  = (const float*)d_in[4];
    const float* Wtp  = (const float*)d_in[5];
    const float* btp  = (const float*)d_in[6];
    const float* Wen  = (const float*)d_in[7];
    const float* ben  = (const float*)d_in[8];
    const float* lng  = (const float*)d_in[9];
    const float* lnb  = (const float*)d_in[10];
    const float* Wq   = (const float*)d_in[11];
    const float* bq   = (const float*)d_in[12];
    const float* Wk   = (const float*)d_in[13];
    const float* bk   = (const float*)d_in[14];
    const float* Wv   = (const float*)d_in[15];
    const float* bv   = (const float*)d_in[16];
    const float* Wo   = (const float*)d_in[17];
    const float* bo   = (const float*)d_in[18];
    const float* Wc   = (const float*)d_in[19];
    const float* bc   = (const float*)d_in[20];

    char* ws = (char*)d_ws;
    size_t o = 0;
    auto alloc = [&](size_t bytes) -> void* {
        void* p = ws + o; o += (bytes + 255) & ~(size_t)255; return p;
    };
    float* img  = (float*)alloc((size_t)NTOK_ * D_ * 4);
    float* rno  = (float*)alloc((size_t)NTOK_ * 4);
    float* rel  = (float*)alloc((size_t)NTOK_ * 4);
    int*   keep = (int*)alloc((size_t)NTOK_ * 4);
    unsigned char* vld = (unsigned char*)alloc(NTOK_);
    float* te   = (float*)alloc(B_ * D_ * 4);
    float* qv   = (float*)alloc(B_ * D_ * 4);
    int*   idxo = (int*)alloc(B_ * LMAX_ * 4);
    float* f3   = (float*)alloc((size_t)B_ * M2_ * D_ * 4);
    float* kkb  = (float*)alloc((size_t)B_ * M2_ * D_ * 4);
    float* vvb  = (float*)alloc((size_t)B_ * M2_ * D_ * 4);
    float* ctx  = (float*)alloc(B_ * D_ * 4);
    int*   flag = (int*)alloc(256);
    float2* stats = (float2*)alloc((size_t)NTOK_ * 8);
    unsigned short* bth = (unsigned short*)alloc((size_t)D_ * F_ * 2);
    unsigned short* btl = (unsigned short*)alloc((size_t)D_ * F_ * 2);
    unsigned short* wkh = (unsigned short*)alloc((size_t)D_ * D_ * 2);
    unsigned short* wkl = (unsigned short*)alloc((size_t)D_ * D_ * 2);
    unsigned short* wvh = (unsigned short*)alloc((size_t)D_ * D_ * 2);
    unsigned short* wvl = (unsigned short*)alloc((size_t)D_ * D_ * 2);

    size_t fnb_need = (size_t)NTOK_ * D_ * 2 + 4096;
    bool newpath = (ws_size > o) && ((ws_size - o) >= fnb_need);
    unsigned short* fnb = nullptr;
    if (newpath) fnb = (unsigned short*)alloc((size_t)NTOK_ * D_ * 2);

    hipMemsetAsync(flag, 0, 4, stream);
    k_detect<<<64, 256, 0, stream>>>((const unsigned char*)kpm, NTOK_, flag);
    k_valid<<<(NTOK_ + 255) / 256, 256, 0, stream>>>(kpm, flag, vld);
    k_text<<<B_, 512, 0, stream>>>(emb, ids, am, Wtp, btp, Wq, bq, te, qv);

    if (newpath) {
        k_wsplit<<<1024, 256, 0, stream>>>(Wen, bth, btl, Wk, wkh, wkl, Wv, wvh, wvl);
        k_gemm3p<<<4096, 256, 0, stream>>>(bags, bth, btl, ben, img, F_);
    } else {
        dim3 gw512(D_ / 32, D_ / 32);
        k_bsplit_sw<<<gw512, 256, 0, stream>>>(Wk, wkh, wkl, D_);
        k_bsplit_sw<<<gw512, 256, 0, stream>>>(Wv, wvh, wvl, D_);
        dim3 gsplit(F_ / 32, D_ / 32);
        k_bsplit<<<gsplit, 256, 0, stream>>>(Wen, bth, btl);
        dim3 g3(NTOK_ / 64, 2);
        k_gemm_mfma<<<g3, 256, 0, stream>>>(bags, bth, btl, ben, img);
    }

    int write_img = newpath ? 0 : 1;
    k_ln<<<NTOK_ / 4, 256, 0, stream>>>(img, lng, lnb, te, rno, rel, fnb, stats, write_img);
    if (fnb) k_simg<<<NTOK_ / 128, 256, 0, stream>>>(fnb, vld, keep);
    else     k_sim<<<(NTOK_ + CHUNK - 1) / CHUNK, 256, 0, stream>>>(img, rno, vld, keep);
    k_topk<<<B_, 1024, 0, stream>>>(rel, keep, idxo);
    k_feat3<<<B_ * M2_, 128, 0, stream>>>(img, stats, lng, lnb, idxo, f3, newpath ? 1 : 0);

    k_gemmkv2<<<256, 256, 0, stream>>>(f3, wkh, wkl, bk, kkb, wvh, wvl, bv, vvb);

    k_attn<<<B_ * H_, 512, 0, stream>>>(qv, kkb, vvb, ctx);
    k_head<<<B_, 512, 0, stream>>>(ctx, Wo, bo, Wc, bc, (float*)d_out);
}